// Round 16
// baseline (403.246 us; speedup 1.0000x reference)
//
#include <hip/hip_runtime.h>
#include <math.h>

// DenoiseEncoder forward, MI355X. B=256,N=100,D=128,H=2.
// v12 = v10 (round-14, 298us) + weight-converts folded into k_prep_a grid.
// f32 GNN intermediates (f16 stores regressed: partial-cacheline RMW).
constexpr int cB = 256, cN = 100, cD = 128, cH = 2, cG = 10, cNCH = cN / cG;
constexpr int N_ITER_RUN = 12;

typedef __fp16 h2 __attribute__((ext_vector_type(2)));
typedef __fp16 f16x8 __attribute__((ext_vector_type(8)));
typedef float f32x4 __attribute__((ext_vector_type(4)));
typedef unsigned short ushort_t;
typedef unsigned char uchar_t;

// ---------------- helpers ----------------
__device__ __forceinline__ float wsum(float v) {
#pragma unroll
    for (int o = 32; o; o >>= 1) v += __shfl_xor(v, o, 64);
    return v;
}
__device__ __forceinline__ float sigm(float x) { return 1.f / (1.f + __expf(-x)); }
__device__ __forceinline__ float ex2(float x) {
#if __has_builtin(__builtin_amdgcn_exp2f)
    return __builtin_amdgcn_exp2f(x);
#else
    return exp2f(x);
#endif
}
__device__ __forceinline__ float lg2(float x) {
#if __has_builtin(__builtin_amdgcn_logf)
    return __builtin_amdgcn_logf(x);       // v_log_f32; lg2(0) = -inf
#else
    return __log2f(x);
#endif
}
__device__ __forceinline__ unsigned pkh2(float a, float b) {
#if __has_builtin(__builtin_amdgcn_cvt_pkrtz)
    h2 r = __builtin_amdgcn_cvt_pkrtz(a, b);
#else
    h2 r; r.x = (__fp16)a; r.y = (__fp16)b;
#endif
    unsigned u; __builtin_memcpy(&u, &r, 4); return u;
}
__device__ __forceinline__ ushort_t f2hbits(float v) {
    __fp16 h = (__fp16)v;
    ushort_t u; __builtin_memcpy(&u, &h, 2); return u;
}
__device__ __forceinline__ float h2f(ushort_t u) {
    __fp16 h; __builtin_memcpy(&h, &u, 2); return (float)h;
}
__device__ __forceinline__ f16x8 ldf(const ushort_t* p) {   // 16B-aligned load
    uint4 u = *(const uint4*)p;
    f16x8 a; __builtin_memcpy(&a, &u, 16); return a;
}
__device__ __forceinline__ f32x4 mm(f16x8 a, f16x8 b, f32x4 c) {
    return __builtin_amdgcn_mfma_f32_16x16x32_f16(a, b, c, 0, 0, 0);
}

// ---------------- kernel 1a: avgdot[b] (bx<256) + weight converts (bx>=256) ----------------
__global__ __launch_bounds__(256) void k_prep_a(
    const float* __restrict__ gnn, const void* __restrict__ m0,
    const float* __restrict__ fnw, float* __restrict__ avgdot,
    const float* __restrict__ LWL, const float* __restrict__ LWG,
    const float* __restrict__ W1, const float* __restrict__ G1w,
    const float* __restrict__ GW, const float* __restrict__ pos,
    ushort_t* __restrict__ LWT, ushort_t* __restrict__ W1bT, ushort_t* __restrict__ G1T,
    ushort_t* __restrict__ W0T, ushort_t* __restrict__ W1gT, float* __restrict__ posW1)
{
    const int bx = blockIdx.x, tid = threadIdx.x;
    if (bx >= cB) {
        const int bz = bx - cB;
        if (bz < 4) {
            const int gzc = bz >> 1, h = bz & 1;
            const float* src = (gzc ? LWG : LWL) + (size_t)h * 2 * cD * cD;
            for (int idx = tid; idx < 256 * cD; idx += 256) {
                int c = idx >> 7, d = idx & 127;
                LWT[((size_t)bz * cD + d) * 256 + c] = f2hbits(src[c * cD + d]);
            }
        } else if (bz < 8) {
            const float* src = (bz == 4) ? (W1 + cD * cD) : (bz == 5) ? G1w
                             : (bz == 6) ? GW : (GW + cD * cD);
            ushort_t* dst = (bz == 4) ? W1bT : (bz == 5) ? G1T : (bz == 6) ? W0T : W1gT;
            for (int idx = tid; idx < cD * cD; idx += 256) {
                int c = idx >> 7, d = idx & 127;
                dst[(size_t)d * cD + c] = f2hbits(src[c * cD + d]);
            }
        } else {
            for (int idx = tid; idx < cN * cD; idx += 256) {
                int n = idx >> 7, d = idx & 127;
                float acc = 0.f;
                for (int c = 0; c < cD; c++) acc += pos[n * cD + c] * W1[c * cD + d];
                posW1[n * cD + d] = acc;
            }
        }
        return;
    }

    const int b = bx;
    const int w = tid >> 6, l = tid & 63;
    const int d0 = l, d1 = l + 64;
    __shared__ int fmt_s;
    __shared__ float mrow[cN];
    __shared__ float part[4][cD];
    __shared__ float red2[2];
    if (tid < 64) {
        unsigned u = ((const unsigned*)m0)[tid];
        int c = ((u & 0xffu) != 0) + ((u & 0xff00u) != 0) + ((u & 0xff0000u) != 0) + ((u >> 24) != 0);
        float cf = wsum((float)c);
        if (tid == 0) fmt_s = (cf > 128.f);
    }
    __syncthreads();
    if (tid < cN) {
        int idx = b * cN + tid;
        float m;
        if (fmt_s) m = ((const unsigned char*)m0)[idx] ? 1.f : 0.f;
        else       m = ((const int*)m0)[idx] ? 1.f : 0.f;
        mrow[tid] = m;
    }
    __syncthreads();
    float s0 = 0.f, s1 = 0.f;
    for (int n = w; n < cN; n += 4) {
        size_t o = ((size_t)b * cN + n) * cD;
        float m = mrow[n];
        s0 += gnn[o + d0] * m;
        s1 += gnn[o + d1] * m;
    }
    part[w][d0] = s0; part[w][d1] = s1;
    __syncthreads();
    const float rcnt = 1.f / (100.f + 1e-7f);
    if (tid < cD) {
        float avg = (part[0][tid] + part[1][tid] + part[2][tid] + part[3][tid]) * rcnt;
        float v = wsum(avg * fnw[tid]);
        if ((tid & 63) == 0) red2[tid >> 6] = v;
    }
    __syncthreads();
    if (tid == 0) avgdot[b] = red2[0] + red2[1];
}

// ---------------- kernel 1b: per-(b,n) wave: gi, pi, aL, aG ----------------
__global__ __launch_bounds__(512) void k_prep_b(
    const float* __restrict__ gnn, const float* __restrict__ drop, const float* __restrict__ proto,
    const void* __restrict__ m0, const float* __restrict__ avgdot,
    const float* __restrict__ fnw, const float* __restrict__ fnb,
    const float* __restrict__ ssLw, const float* __restrict__ ssLb,
    const float* __restrict__ ssGw, const float* __restrict__ ssGb,
    float* __restrict__ gi, float* __restrict__ pi,
    float* __restrict__ aL, float* __restrict__ aG)
{
    const int b = blockIdx.x, tid = threadIdx.x;
    const int wid = tid >> 6, l = tid & 63;
    const int n = blockIdx.y * 8 + wid;
    __shared__ int fmt_s;
    if (tid < 64) {
        unsigned u = ((const unsigned*)m0)[tid];
        int c = ((u & 0xffu) != 0) + ((u & 0xff00u) != 0) + ((u & 0xff0000u) != 0) + ((u >> 24) != 0);
        float cf = wsum((float)c);
        if (tid == 0) fmt_s = (cf > 128.f);
    }
    __syncthreads();
    if (n >= cN) return;
    float m;
    {
        int idx = b * cN + n;
        if (fmt_s) m = ((const unsigned char*)m0)[idx] ? 1.f : 0.f;
        else       m = ((const int*)m0)[idx] ? 1.f : 0.f;
    }
    const float dm = 1.f - m;
    const int d0 = l, d1 = l + 64;
    const size_t o = ((size_t)b * cN + n) * cD;
    float dr0 = drop[o + d0] * dm, dr1 = drop[o + d1] * dm;
    float p0 = proto[o + d0] * m,  p1 = proto[o + d1] * m;
    pi[o + d0] = p0; pi[o + d1] = p1;
    float r1 = wsum(dr0 * fnw[cD + d0] + dr1 * fnw[cD + d1]);
    float r2 = wsum(p0 * ssGw[d0] + p1 * ssGw[d1]);
    float alpha = r1 + avgdot[b] + fnb[0];
    float g0 = gnn[o + d0] * m + alpha * dr0;
    float g1 = gnn[o + d1] * m + alpha * dr1;
    gi[o + d0] = g0; gi[o + d1] = g1;
    float r3 = wsum(g0 * ssLw[d0] + g1 * ssLw[d1]);
    if (l == 0) {
        aL[b * cN + n] = 1.f + sigm(r3 + ssLb[0]);
        aG[b * cN + n] = 1.f + sigm(r2 + ssGb[0]);
    }
}

// ---------------- kernel 2: GNN via MFMA. 512 threads, G=10 rows ----------------
// 1D grid 5120 with XCD-affinity decode (wgid%8 == b%8). LDS 39288 B -> 4 blocks/CU.
__global__ __launch_bounds__(512, 8) void k_gnn(
    const float* __restrict__ xL, const float* __restrict__ xG,
    const int* __restrict__ adj,
    const float* __restrict__ alpL, const float* __restrict__ alpG,
    const float* __restrict__ AL, const float* __restrict__ AG,
    const ushort_t* __restrict__ LWT,
    const float* __restrict__ LBL, const float* __restrict__ LBG,
    float* __restrict__ outLp, float* __restrict__ outGp)
{
    const int wg = blockIdx.x;
    const int xcd = wg & 7;
    const int q = wg >> 3;
    const int b = (q / 20) * 8 + xcd;
    const int c20 = q % 20;
    const int gz = c20 & 1;
    const int r0 = (c20 >> 1) * cG;

    const float* __restrict__ x   = gz ? xG : xL;
    const float* __restrict__ alp = gz ? alpG : alpL;
    const float* __restrict__ A   = gz ? AG : AL;
    const float* __restrict__ LB  = gz ? LBG : LBL;
    float* __restrict__ out       = gz ? outGp : outLp;

    const int tid = threadIdx.x, wid = tid >> 6, l = tid & 63;
    const int la = l & 15, lg = l >> 4;

    __shared__ __align__(16) uchar_t lds[39288];
    ushort_t* x16   = (ushort_t*)(lds);           // [100][136]
    ushort_t* xT    = (ushort_t*)(lds);           // [128][104], after gating-p1
    ushort_t* sc    = (ushort_t*)(lds + 27200);   // [2][16][104]
    ushort_t* A16   = (ushort_t*)(lds + 33856);   // [8][128], scores phase only
    ushort_t* out16 = (ushort_t*)(lds + 33856);   // [16][136], PV phase (A16 dead)
    uchar_t*  adjb  = lds + 38208;                // [10][104]
    float*    alps  = (float*)(lds + 39248);

    // ---- S1: stage x16 (paired dwords), A16, adjb, sc zero, alps
    for (int idx = tid; idx < 100 * 64; idx += 512) {
        int j = idx >> 6, d2 = idx & 63;
        const float* xp = x + ((size_t)b * cN + j) * cD + 2 * d2;
        *(unsigned*)&x16[j * 136 + 2 * d2] = pkh2(xp[0], xp[1]);
    }
    {   // 8 rows x 64 dwords
        int row = tid >> 6, d2 = tid & 63;
        const float* ap = A + row * cD + 2 * d2;
        *(unsigned*)&A16[row * 128 + 2 * d2] = pkh2(ap[0], ap[1]);
    }
    for (int idx = tid; idx < cG * cN; idx += 512) {
        int i = idx / cN, j = idx % cN;
        adjb[i * 104 + j] = (uchar_t)adj[((size_t)b * cN + r0 + i) * cN + j];
    }
    for (int idx = tid; idx < 1664; idx += 512) ((unsigned*)sc)[idx] = 0u;
    if (tid < cG) alps[tid] = alp[b * cN + r0 + tid];
    __syncthreads();

    // ---- scores, both h: C[j][(ik)] = sum_d x16[j][d] * (x16[r0+i][d]*A16[h*4+k][d])
    for (int h = 0; h < 2; h++) {
        f16x8 afr[4];
        const int krow = (h * 4 + (la & 3)) * 128;
#pragma unroll
        for (int kc = 0; kc < 4; kc++) afr[kc] = ldf(&A16[krow + kc * 32 + lg * 8]);
        for (int job = wid; job < 21; job += 8) {
            int mt = job / 3, nt = job % 3;
            int arow = mt * 16 + la; if (arow > 99) arow = 99;
            int brow = nt * 16 + la; if (brow > 39) brow = 39;
            int xrow = r0 + (brow >> 2);
            f32x4 c = {0.f, 0.f, 0.f, 0.f};
#pragma unroll
            for (int kc = 0; kc < 4; kc++) {
                f16x8 a  = ldf(&x16[arow * 136 + kc * 32 + lg * 8]);
                f16x8 xb = ldf(&x16[xrow * 136 + kc * 32 + lg * 8]);
                c = mm(a, xb * afr[kc], c);
            }
            int col = nt * 16 + la, i = col >> 2, k = col & 3;
            if (i < cG) {
#pragma unroll
                for (int r = 0; r < 4; r++) {
                    int j = mt * 16 + lg * 4 + r;
                    if (j < cN && (int)adjb[i * 104 + j] == k + 1) {
                        float v = c[r];
                        v = (v >= 0.f) ? v : 0.2f * v;     // leaky
                        sc[(h * 16 + i) * 104 + j] = f2hbits(v);
                    }
                }
            }
        }
    }
    __syncthreads();

    // ---- entmax: waves 0-3 rows {wid, 8+wid, 16+wid}; waves 4-7 rows {wid, 8+wid}
    {
        const bool w3 = (wid < 4);
        const float log2_rn = -6.6438561897747395f;
        float X0[3], X1[3], INV[3], TLO[3], DM[3], FLO[3], TM[3], S[3];
        int RI[3], RH[3];
#pragma unroll
        for (int q2 = 0; q2 < 3; q2++) {
            if (q2 < 2 || w3) {
                int r = (q2 < 2) ? (wid + 8 * q2) : (16 + wid);
                RI[q2] = r >> 1; RH[q2] = r & 1;
                float am1 = alps[RI[q2]] - 1.f;
                INV[q2] = 1.f / am1;
                X0[q2] = h2f(sc[(RH[q2] * 16 + RI[q2]) * 104 + l]) * am1;
                X1[q2] = (l + 64 < cN) ? h2f(sc[(RH[q2] * 16 + RI[q2]) * 104 + l + 64]) * am1 : -INFINITY;
                TM[q2] = ex2(am1 * log2_rn);
            }
        }
        float MX[3];
#pragma unroll
        for (int q2 = 0; q2 < 3; q2++) if (q2 < 2 || w3) MX[q2] = fmaxf(X0[q2], X1[q2]);
#pragma unroll
        for (int o = 32; o; o >>= 1) {
#pragma unroll
            for (int q2 = 0; q2 < 3; q2++) if (q2 < 2 || w3) MX[q2] = fmaxf(MX[q2], __shfl_xor(MX[q2], o, 64));
        }
#pragma unroll
        for (int q2 = 0; q2 < 3; q2++) if (q2 < 2 || w3) { TLO[q2] = MX[q2] - 1.f; DM[q2] = 1.f - TM[q2]; }
#pragma unroll
        for (int q2 = 0; q2 < 3; q2++) if (q2 < 2 || w3) {
            float z0 = fmaxf(X0[q2] - TLO[q2], 0.f);
            float z1 = fmaxf(X1[q2] - TLO[q2], 0.f);
            S[q2] = ex2(INV[q2] * lg2(z0)) + ex2(INV[q2] * lg2(z1));
        }
#pragma unroll
        for (int o = 32; o; o >>= 1) {
#pragma unroll
            for (int q2 = 0; q2 < 3; q2++) if (q2 < 2 || w3) S[q2] += __shfl_xor(S[q2], o, 64);
        }
#pragma unroll
        for (int q2 = 0; q2 < 3; q2++) if (q2 < 2 || w3) FLO[q2] = S[q2] - 1.f;

#pragma unroll 1
        for (int it = 0; it < N_ITER_RUN - 1; ++it) {
#pragma unroll
            for (int q2 = 0; q2 < 3; q2++) if (q2 < 2 || w3) { DM[q2] *= 0.5f; TM[q2] = TLO[q2] + DM[q2]; }
#pragma unroll
            for (int q2 = 0; q2 < 3; q2++) if (q2 < 2 || w3) {
                float z0 = fmaxf(X0[q2] - TM[q2], 0.f);
                float z1 = fmaxf(X1[q2] - TM[q2], 0.f);
                S[q2] = ex2(INV[q2] * lg2(z0)) + ex2(INV[q2] * lg2(z1));
            }
#pragma unroll
            for (int o = 32; o; o >>= 1) {
#pragma unroll
                for (int q2 = 0; q2 < 3; q2++) if (q2 < 2 || w3) S[q2] += __shfl_xor(S[q2], o, 64);
            }
#pragma unroll
            for (int q2 = 0; q2 < 3; q2++) if (q2 < 2 || w3)
                if ((S[q2] - 1.f) * FLO[q2] >= 0.f) TLO[q2] = TM[q2];
        }
        float P0[3], P1[3];
#pragma unroll
        for (int q2 = 0; q2 < 3; q2++) if (q2 < 2 || w3) {
            DM[q2] *= 0.5f; TM[q2] = TLO[q2] + DM[q2];
            float z0 = fmaxf(X0[q2] - TM[q2], 0.f);
            float z1 = fmaxf(X1[q2] - TM[q2], 0.f);
            P0[q2] = ex2(INV[q2] * lg2(z0));
            P1[q2] = ex2(INV[q2] * lg2(z1));
            S[q2] = P0[q2] + P1[q2];
        }
#pragma unroll
        for (int o = 32; o; o >>= 1) {
#pragma unroll
            for (int q2 = 0; q2 < 3; q2++) if (q2 < 2 || w3) S[q2] += __shfl_xor(S[q2], o, 64);
        }
        __syncthreads();
#pragma unroll
        for (int q2 = 0; q2 < 3; q2++) {
            if (q2 < 2 || w3) {
                float invs = 1.f / S[q2];
                sc[(RH[q2] * 16 + RI[q2]) * 104 + l] = f2hbits(P0[q2] * invs);
                if (l + 64 < cN) sc[(RH[q2] * 16 + RI[q2]) * 104 + l + 64] = f2hbits(P1[q2] * invs);
            }
        }
    }

    // ---- gating part 1 (x16 still intact): cg[h] = xi @ LW_top
    f32x4 cg0 = {0.f, 0.f, 0.f, 0.f}, cg1 = {0.f, 0.f, 0.f, 0.f};
    {
        const int d = wid * 16 + la;
        int arow = r0 + la; if (arow > 99) arow = 99;
#pragma unroll
        for (int h = 0; h < 2; h++) {
            const ushort_t* lwbase = LWT + ((size_t)(gz * 2 + h) * cD + d) * 256;
            f32x4 c = {0.f, 0.f, 0.f, 0.f};
#pragma unroll
            for (int kc = 0; kc < 4; kc++) {
                f16x8 a = ldf(&x16[arow * 136 + kc * 32 + lg * 8]);
                uint4 u = *(const uint4*)(lwbase + kc * 32 + lg * 8);
                f16x8 bb; __builtin_memcpy(&bb, &u, 16);
                c = mm(a, bb, c);
            }
            if (h) cg1 = c; else cg0 = c;
        }
    }
    __syncthreads();

    // ---- xT build from GLOBAL x (L2-hot), b128 writes, into dead x16 region
    for (int job = tid; job < 13 * 128; job += 512) {
        int d2 = job & 127, jc = job >> 7;
        f16x8 v;
#pragma unroll
        for (int t = 0; t < 8; t++) {
            int j = jc * 8 + t;
            float f = (j < cN) ? x[((size_t)b * cN + j) * cD + d2] : 0.f;
            v[t] = (__fp16)f;
        }
        uint4 u; __builtin_memcpy(&u, &v, 16);
        *(uint4*)(&xT[d2 * 104 + jc * 8]) = u;
    }
    __syncthreads();

    // ---- PV + gating part 2, per h ----
    float res[4] = {0.f, 0.f, 0.f, 0.f};
    const int dt = wid;
    const int d = dt * 16 + la;
    for (int h = 0; h < 2; h++) {
        if (h) __syncthreads();
        {
            f32x4 c = {0.f, 0.f, 0.f, 0.f};
#pragma unroll
            for (int kc = 0; kc < 3; kc++) {
                f16x8 a  = ldf(&sc[(h * 16 + la) * 104 + kc * 32 + lg * 8]);
                f16x8 bb = ldf(&xT[(dt * 16 + la) * 104 + kc * 32 + lg * 8]);
                c = mm(a, bb, c);
            }
#pragma unroll
            for (int r = 0; r < 4; r++) {
                int i = lg * 4 + r;
                float acc = c[r];
#pragma unroll
                for (int j = 96; j < 100; j++)
                    acc += h2f(sc[(h * 16 + i) * 104 + j]) * h2f(xT[d * 104 + j]);
                if (i < cG) out16[i * 136 + d] = f2hbits(acc);
            }
        }
        __syncthreads();
        {
            f32x4 c = h ? cg1 : cg0;
            const ushort_t* lwbase = LWT + ((size_t)(gz * 2 + h) * cD + d) * 256 + 128;
#pragma unroll
            for (int kc = 0; kc < 4; kc++) {
                f16x8 a = ldf(&out16[la * 136 + kc * 32 + lg * 8]);
                uint4 u = *(const uint4*)(lwbase + kc * 32 + lg * 8);
                f16x8 bb; __builtin_memcpy(&bb, &u, 16);
                c = mm(a, bb, c);
            }
            float lb = LB[h * cD + d];
#pragma unroll
            for (int r = 0; r < 4; r++) {
                int i = lg * 4 + r;
                float g = sigm(c[r] + lb);
                float o = h2f(out16[i * 136 + d]);
                float xi = h2f(xT[d * 104 + r0 + i]);
                res[r] += g * o + (1.f - g) * xi;
            }
        }
    }
#pragma unroll
    for (int r = 0; r < 4; r++) {
        int i = lg * 4 + r;
        if (i < cG) out[((size_t)b * cN + r0 + i) * cD + d] = res[r];
    }
}

// ---------------- kernel 3: fused tail (one block per b, 512 threads) ----------------
__global__ __launch_bounds__(512) void k_tail(
    const float* __restrict__ S, const float* __restrict__ T,
    const int* __restrict__ iidx, const float* __restrict__ g2w,
    const float* __restrict__ G1b, const float* __restrict__ W2,
    const ushort_t* __restrict__ W0T, const ushort_t* __restrict__ W1gT,
    const ushort_t* __restrict__ W1bT, const ushort_t* __restrict__ G1T,
    const float* __restrict__ posW1, float* __restrict__ outp)
{
    const int b = blockIdx.x;
    const int tid = threadIdx.x, wid = tid >> 6, l = tid & 63;
    const int la = l & 15, lg = l >> 4;
    const float scale = 0.088388347648318447f;   // 1/sqrt(128)

    __shared__ __align__(16) ushort_t s16[100 * 136];   // s, then snew, then nh
    __shared__ __align__(16) ushort_t t16[100 * 136];   // t, then hid
    __shared__ float a_sh[cN];
    __shared__ float part[4][cD];
    __shared__ float hs_s[cD];
    __shared__ float hsg_s[cD];
    __shared__ float beta_s[cN];
    __shared__ int   idx_s[cN];

    for (int idx = tid; idx < 100 * 64; idx += 512) {
        int n = idx >> 6, d2 = idx & 63;
        const float* sp = S + ((size_t)b * cN + n) * cD + 2 * d2;
        const float* tp = T + ((size_t)b * cN + n) * cD + 2 * d2;
        *(unsigned*)&s16[n * 136 + 2 * d2] = pkh2(sp[0], sp[1]);
        *(unsigned*)&t16[n * 136 + 2 * d2] = pkh2(tp[0], tp[1]);
    }
    if (tid < cN) idx_s[tid] = iidx[b * cN + tid];
    __syncthreads();

    if (wid < 7) {
        int arow = wid * 16 + la; if (arow > 99) arow = 99;
        float asum[4] = {0.f, 0.f, 0.f, 0.f};
        for (int nt = 0; nt < 8; nt++) {
            f32x4 cs = {0.f, 0.f, 0.f, 0.f}, ct = {0.f, 0.f, 0.f, 0.f};
            const ushort_t* b0 = W0T + (size_t)(nt * 16 + la) * cD;
            const ushort_t* b1 = W1gT + (size_t)(nt * 16 + la) * cD;
#pragma unroll
            for (int kc = 0; kc < 4; kc++) {
                f16x8 as = ldf(&s16[arow * 136 + kc * 32 + lg * 8]);
                f16x8 at = ldf(&t16[arow * 136 + kc * 32 + lg * 8]);
                uint4 u0 = *(const uint4*)(b0 + kc * 32 + lg * 8);
                uint4 u1 = *(const uint4*)(b1 + kc * 32 + lg * 8);
                f16x8 w0v, w1v; __builtin_memcpy(&w0v, &u0, 16); __builtin_memcpy(&w1v, &u1, 16);
                cs = mm(as, w0v, cs);
                ct = mm(at, w1v, ct);
            }
#pragma unroll
            for (int r = 0; r < 4; r++) asum[r] += cs[r] * ct[r];
        }
#pragma unroll
        for (int o = 8; o; o >>= 1) {
#pragma unroll
            for (int r = 0; r < 4; r++) asum[r] += __shfl_xor(asum[r], o, 64);
        }
        if (la == 0) {
#pragma unroll
            for (int r = 0; r < 4; r++) {
                int n = wid * 16 + lg * 4 + r;
                if (n < cN) a_sh[n] = asum[r] * scale;
            }
        }
    }
    __syncthreads();

    for (int idx = tid; idx < 100 * 64; idx += 512) {
        int n = idx >> 6, d2 = idx & 63;
        unsigned su = *(unsigned*)&s16[n * 136 + 2 * d2];
        unsigned tu = *(unsigned*)&t16[n * 136 + 2 * d2];
        float a = a_sh[n];
        float s0 = h2f((ushort_t)(su & 0xffffu)), s1 = h2f((ushort_t)(su >> 16));
        float t0 = h2f((ushort_t)(tu & 0xffffu)), t1 = h2f((ushort_t)(tu >> 16));
        *(unsigned*)&s16[n * 136 + 2 * d2] = pkh2(s0 + a * (t0 - s0), s1 + a * (t1 - s1));
    }
    __syncthreads();

    for (int idx = tid; idx < 100 * 64; idx += 512) {
        int n = idx >> 6, d2 = idx & 63;
        int rsrc = idx_s[n];
        *(unsigned*)&t16[n * 136 + 2 * d2] = *(unsigned*)&s16[rsrc * 136 + 2 * d2];
    }
    __syncthreads();

    {
        int g = tid >> 7, d = tid & 127;
        float sum = 0.f;
        for (int n = g * 25; n < g * 25 + 25; n++) sum += h2f(t16[n * 136 + d]);
        part[g][d] = sum;
    }
    __syncthreads();
    if (tid < cD) hs_s[tid] = (part[0][tid] + part[1][tid] + part[2][tid] + part[3][tid]) * (1.f / (100.f + 1e-7f));
    __syncthreads();
    if (tid < cD) {
        float acc = 0.f;
        for (int c = 0; c < cD; c++) acc += hs_s[c] * g2w[c * cD + tid];
        hsg_s[tid] = acc;
    }
    __syncthreads();

    if (wid < 7) {
        int arow = wid * 16 + la; if (arow > 99) arow = 99;
        for (int nt = 0; nt < 8; nt++) {
            f32x4 c = {0.f, 0.f, 0.f, 0.f};
            const ushort_t* bb = W1bT + (size_t)(nt * 16 + la) * cD;
#pragma unroll
            for (int kc = 0; kc < 4; kc++) {
                f16x8 a = ldf(&t16[arow * 136 + kc * 32 + lg * 8]);
                uint4 u = *(const uint4*)(bb + kc * 32 + lg * 8);
                f16x8 wv; __builtin_memcpy(&wv, &u, 16);
                c = mm(a, wv, c);
            }
            int d = nt * 16 + la;
#pragma unroll
            for (int r = 0; r < 4; r++) {
                int n = wid * 16 + lg * 4 + r;
                if (n < cN) s16[n * 136 + d] = f2hbits(tanhf(c[r] + posW1[n * cD + d]));
            }
        }
    }
    __syncthreads();

    if (wid < 7) {
        int arow = wid * 16 + la; if (arow > 99) arow = 99;
        float bsum[4] = {0.f, 0.f, 0.f, 0.f};
        for (int nt = 0; nt < 8; nt++) {
            f32x4 c = {0.f, 0.f, 0.f, 0.f};
            const ushort_t* bb = G1T + (size_t)(nt * 16 + la) * cD;
#pragma unroll
            for (int kc = 0; kc < 4; kc++) {
                f16x8 a = ldf(&s16[arow * 136 + kc * 32 + lg * 8]);
                uint4 u = *(const uint4*)(bb + kc * 32 + lg * 8);
                f16x8 wv; __builtin_memcpy(&wv, &u, 16);
                c = mm(a, wv, c);
            }
            int d = nt * 16 + la;
            float add = G1b[d] + hsg_s[d];
            float w2v = W2[d];
#pragma unroll
            for (int r = 0; r < 4; r++) bsum[r] += sigm(c[r] + add) * w2v;
        }
#pragma unroll
        for (int o = 8; o; o >>= 1) {
#pragma unroll
            for (int r = 0; r < 4; r++) bsum[r] += __shfl_xor(bsum[r], o, 64);
        }
        if (la == 0) {
#pragma unroll
            for (int r = 0; r < 4; r++) {
                int n = wid * 16 + lg * 4 + r;
                if (n < cN) beta_s[n] = bsum[r];
            }
        }
    }
    __syncthreads();

    {
        int g = tid >> 7, d = tid & 127;
        float sum = 0.f;
        for (int n = g * 25; n < g * 25 + 25; n++) sum += beta_s[n] * h2f(t16[n * 136 + d]);
        part[g][d] = sum;
    }
    __syncthreads();
    if (tid < cD) outp[b * cD + tid] = part[0][tid] + part[1][tid] + part[2][tid] + part[3][tid];
}

extern "C" void kernel_launch(void* const* d_in, const int* in_sizes, int n_in,
                              void* d_out, int out_size, void* d_ws, size_t ws_size,
                              hipStream_t stream) {
    const float* gnn   = (const float*)d_in[0];
    const float* drop  = (const float*)d_in[1];
    const float* proto = (const float*)d_in[2];
    const float* pos   = (const float*)d_in[3];
    const float* laL_a = (const float*)d_in[4];
    const float* laL_w = (const float*)d_in[5];
    const float* laL_b = (const float*)d_in[6];
    const float* ssL_w = (const float*)d_in[7];
    const float* ssL_b = (const float*)d_in[8];
    const float* laG_a = (const float*)d_in[9];
    const float* laG_w = (const float*)d_in[10];
    const float* laG_b = (const float*)d_in[11];
    const float* ssG_w = (const float*)d_in[12];
    const float* ssG_b = (const float*)d_in[13];
    const float* gem_w = (const float*)d_in[14];
    const float* fn_w  = (const float*)d_in[15];
    const float* fn_b  = (const float*)d_in[16];
    const float* w_1   = (const float*)d_in[17];
    const float* w_2   = (const float*)d_in[18];
    const float* glu1w = (const float*)d_in[19];
    const float* glu1b = (const float*)d_in[20];
    const float* glu2w = (const float*)d_in[21];
    const int*   adj   = (const int*)d_in[22];
    const int*   iidx  = (const int*)d_in[23];
    const void*  m0    = d_in[24];
    float* out = (float*)d_out;

    const size_t BND = (size_t)cB * cN * cD;
    float* w = (float*)d_ws;
    float* bufA = w;               // gi
    float* bufB = bufA + BND;      // pi
    float* locS = bufB + BND;
    float* gloS = locS + BND;
    float* aL   = gloS + BND;
    float* aG   = aL + (size_t)cB * cN;
    float* avgdot = aG + (size_t)cB * cN;
    ushort_t* LWT  = (ushort_t*)(avgdot + cB);
    ushort_t* W1bT = LWT + (size_t)4 * cD * 256;
    ushort_t* G1T  = W1bT + (size_t)cD * cD;
    ushort_t* W0T  = G1T + (size_t)cD * cD;
    ushort_t* W1gT = W0T + (size_t)cD * cD;
    float* posW1   = (float*)(W1gT + (size_t)cD * cD);

    k_prep_a<<<dim3(cB + 9), dim3(256), 0, stream>>>(gnn, m0, fn_w, avgdot,
                                                     laL_w, laG_w, w_1, glu1w, gem_w, pos,
                                                     LWT, W1bT, G1T, W0T, W1gT, posW1);
    k_prep_b<<<dim3(cB, 13), dim3(512), 0, stream>>>(gnn, drop, proto, m0, avgdot,
                                                     fn_w, fn_b, ssL_w, ssL_b, ssG_w, ssG_b,
                                                     bufA, bufB, aL, aG);
    k_gnn<<<dim3(cNCH * cB * 2), dim3(512), 0, stream>>>(
        bufA, bufB, adj, aL, aG, laL_a, laG_a, LWT, laL_b, laG_b, locS, gloS);
    k_tail<<<dim3(cB), dim3(512), 0, stream>>>(locS, gloS, iidx, glu2w, glu1b, w_2,
                                               W0T, W1gT, W1bT, G1T, posW1, out);
}

// Round 17
// 299.271 us; speedup vs baseline: 1.3474x; 1.3474x over previous
//
#include <hip/hip_runtime.h>
#include <math.h>

// DenoiseEncoder forward, MI355X. B=256,N=100,D=128,H=2.
// v13 == v10 (round-14, measured 298us): k_cvtw(9,8) + k_prep_a + k_prep_b +
// k_gnn (XCD-affinity swizzle, 39.3KB LDS, 4 blocks/CU) + fused k_tail.
constexpr int cB = 256, cN = 100, cD = 128, cH = 2, cG = 10, cNCH = cN / cG;
constexpr int N_ITER_RUN = 12;

typedef __fp16 h2 __attribute__((ext_vector_type(2)));
typedef __fp16 f16x8 __attribute__((ext_vector_type(8)));
typedef float f32x4 __attribute__((ext_vector_type(4)));
typedef unsigned short ushort_t;
typedef unsigned char uchar_t;

// ---------------- helpers ----------------
__device__ __forceinline__ float wsum(float v) {
#pragma unroll
    for (int o = 32; o; o >>= 1) v += __shfl_xor(v, o, 64);
    return v;
}
__device__ __forceinline__ float sigm(float x) { return 1.f / (1.f + __expf(-x)); }
__device__ __forceinline__ float ex2(float x) {
#if __has_builtin(__builtin_amdgcn_exp2f)
    return __builtin_amdgcn_exp2f(x);
#else
    return exp2f(x);
#endif
}
__device__ __forceinline__ float lg2(float x) {
#if __has_builtin(__builtin_amdgcn_logf)
    return __builtin_amdgcn_logf(x);       // v_log_f32; lg2(0) = -inf
#else
    return __log2f(x);
#endif
}
__device__ __forceinline__ unsigned pkh2(float a, float b) {
#if __has_builtin(__builtin_amdgcn_cvt_pkrtz)
    h2 r = __builtin_amdgcn_cvt_pkrtz(a, b);
#else
    h2 r; r.x = (__fp16)a; r.y = (__fp16)b;
#endif
    unsigned u; __builtin_memcpy(&u, &r, 4); return u;
}
__device__ __forceinline__ ushort_t f2hbits(float v) {
    __fp16 h = (__fp16)v;
    ushort_t u; __builtin_memcpy(&u, &h, 2); return u;
}
__device__ __forceinline__ float h2f(ushort_t u) {
    __fp16 h; __builtin_memcpy(&h, &u, 2); return (float)h;
}
__device__ __forceinline__ f16x8 ldf(const ushort_t* p) {   // 16B-aligned load
    uint4 u = *(const uint4*)p;
    f16x8 a; __builtin_memcpy(&a, &u, 16); return a;
}
__device__ __forceinline__ f32x4 mm(f16x8 a, f16x8 b, f32x4 c) {
    return __builtin_amdgcn_mfma_f32_16x16x32_f16(a, b, c, 0, 0, 0);
}

// ---------------- kernel 0: weight converts + posW1 (grid (9,8)) ----------------
__global__ __launch_bounds__(256) void k_cvtw(
    const float* __restrict__ LWL, const float* __restrict__ LWG,
    const float* __restrict__ W1, const float* __restrict__ G1w,
    const float* __restrict__ GW, const float* __restrict__ pos,
    ushort_t* __restrict__ LWT, ushort_t* __restrict__ W1bT, ushort_t* __restrict__ G1T,
    ushort_t* __restrict__ W0T, ushort_t* __restrict__ W1gT, float* __restrict__ posW1)
{
    const int bz = blockIdx.x;
    if (bz < 4) {
        const int gz = bz >> 1, h = bz & 1;
        const int cseg = blockIdx.y * 32;
        const float* src = (gz ? LWG : LWL) + (size_t)h * 2 * cD * cD;
        for (int idx = threadIdx.x; idx < 32 * cD; idx += 256) {
            int c = cseg + (idx >> 7), d = idx & 127;
            LWT[((size_t)bz * cD + d) * 256 + c] = f2hbits(src[c * cD + d]);
        }
    } else if (bz < 8) {
        const float* src = (bz == 4) ? (W1 + cD * cD) : (bz == 5) ? G1w
                         : (bz == 6) ? GW : (GW + cD * cD);
        ushort_t* dst = (bz == 4) ? W1bT : (bz == 5) ? G1T : (bz == 6) ? W0T : W1gT;
        const int cseg = blockIdx.y * 16;
        for (int idx = threadIdx.x; idx < 16 * cD; idx += 256) {
            int c = cseg + (idx >> 7), d = idx & 127;
            dst[(size_t)d * cD + c] = f2hbits(src[c * cD + d]);
        }
    } else {
        int n0 = blockIdx.y * 13;
        int cnt = (n0 + 13 <= cN) ? 13 : (cN - n0);
        for (int idx = threadIdx.x; idx < cnt * cD; idx += 256) {
            int n = n0 + (idx >> 7), d = idx & 127;
            float acc = 0.f;
            for (int c = 0; c < cD; c++) acc += pos[n * cD + c] * W1[c * cD + d];
            posW1[n * cD + d] = acc;
        }
    }
}

// ---------------- kernel 1a: avgdot[b] ----------------
__global__ __launch_bounds__(256) void k_prep_a(
    const float* __restrict__ gnn, const void* __restrict__ m0,
    const float* __restrict__ fnw, float* __restrict__ avgdot)
{
    const int b = blockIdx.x, tid = threadIdx.x;
    const int w = tid >> 6, l = tid & 63;
    const int d0 = l, d1 = l + 64;
    __shared__ int fmt_s;
    __shared__ float mrow[cN];
    __shared__ float part[4][cD];
    __shared__ float red2[2];
    if (tid < 64) {
        unsigned u = ((const unsigned*)m0)[tid];
        int c = ((u & 0xffu) != 0) + ((u & 0xff00u) != 0) + ((u & 0xff0000u) != 0) + ((u >> 24) != 0);
        float cf = wsum((float)c);
        if (tid == 0) fmt_s = (cf > 128.f);
    }
    __syncthreads();
    if (tid < cN) {
        int idx = b * cN + tid;
        float m;
        if (fmt_s) m = ((const unsigned char*)m0)[idx] ? 1.f : 0.f;
        else       m = ((const int*)m0)[idx] ? 1.f : 0.f;
        mrow[tid] = m;
    }
    __syncthreads();
    float s0 = 0.f, s1 = 0.f;
    for (int n = w; n < cN; n += 4) {
        size_t o = ((size_t)b * cN + n) * cD;
        float m = mrow[n];
        s0 += gnn[o + d0] * m;
        s1 += gnn[o + d1] * m;
    }
    part[w][d0] = s0; part[w][d1] = s1;
    __syncthreads();
    const float rcnt = 1.f / (100.f + 1e-7f);
    if (tid < cD) {
        float avg = (part[0][tid] + part[1][tid] + part[2][tid] + part[3][tid]) * rcnt;
        float v = wsum(avg * fnw[tid]);
        if ((tid & 63) == 0) red2[tid >> 6] = v;
    }
    __syncthreads();
    if (tid == 0) avgdot[b] = red2[0] + red2[1];
}

// ---------------- kernel 1b: per-(b,n) wave: gi, pi, aL, aG ----------------
__global__ __launch_bounds__(512) void k_prep_b(
    const float* __restrict__ gnn, const float* __restrict__ drop, const float* __restrict__ proto,
    const void* __restrict__ m0, const float* __restrict__ avgdot,
    const float* __restrict__ fnw, const float* __restrict__ fnb,
    const float* __restrict__ ssLw, const float* __restrict__ ssLb,
    const float* __restrict__ ssGw, const float* __restrict__ ssGb,
    float* __restrict__ gi, float* __restrict__ pi,
    float* __restrict__ aL, float* __restrict__ aG)
{
    const int b = blockIdx.x, tid = threadIdx.x;
    const int wid = tid >> 6, l = tid & 63;
    const int n = blockIdx.y * 8 + wid;
    __shared__ int fmt_s;
    if (tid < 64) {
        unsigned u = ((const unsigned*)m0)[tid];
        int c = ((u & 0xffu) != 0) + ((u & 0xff00u) != 0) + ((u & 0xff0000u) != 0) + ((u >> 24) != 0);
        float cf = wsum((float)c);
        if (tid == 0) fmt_s = (cf > 128.f);
    }
    __syncthreads();
    if (n >= cN) return;
    float m;
    {
        int idx = b * cN + n;
        if (fmt_s) m = ((const unsigned char*)m0)[idx] ? 1.f : 0.f;
        else       m = ((const int*)m0)[idx] ? 1.f : 0.f;
    }
    const float dm = 1.f - m;
    const int d0 = l, d1 = l + 64;
    const size_t o = ((size_t)b * cN + n) * cD;
    float dr0 = drop[o + d0] * dm, dr1 = drop[o + d1] * dm;
    float p0 = proto[o + d0] * m,  p1 = proto[o + d1] * m;
    pi[o + d0] = p0; pi[o + d1] = p1;
    float r1 = wsum(dr0 * fnw[cD + d0] + dr1 * fnw[cD + d1]);
    float r2 = wsum(p0 * ssGw[d0] + p1 * ssGw[d1]);
    float alpha = r1 + avgdot[b] + fnb[0];
    float g0 = gnn[o + d0] * m + alpha * dr0;
    float g1 = gnn[o + d1] * m + alpha * dr1;
    gi[o + d0] = g0; gi[o + d1] = g1;
    float r3 = wsum(g0 * ssLw[d0] + g1 * ssLw[d1]);
    if (l == 0) {
        aL[b * cN + n] = 1.f + sigm(r3 + ssLb[0]);
        aG[b * cN + n] = 1.f + sigm(r2 + ssGb[0]);
    }
}

// ---------------- kernel 2: GNN via MFMA. 512 threads, G=10 rows ----------------
// 1D grid 5120 with XCD-affinity decode (wgid%8 == b%8). LDS 39288 B -> 4 blocks/CU.
__global__ __launch_bounds__(512, 8) void k_gnn(
    const float* __restrict__ xL, const float* __restrict__ xG,
    const int* __restrict__ adj,
    const float* __restrict__ alpL, const float* __restrict__ alpG,
    const float* __restrict__ AL, const float* __restrict__ AG,
    const ushort_t* __restrict__ LWT,
    const float* __restrict__ LBL, const float* __restrict__ LBG,
    float* __restrict__ outLp, float* __restrict__ outGp)
{
    const int wg = blockIdx.x;
    const int xcd = wg & 7;
    const int q = wg >> 3;
    const int b = (q / 20) * 8 + xcd;
    const int c20 = q % 20;
    const int gz = c20 & 1;
    const int r0 = (c20 >> 1) * cG;

    const float* __restrict__ x   = gz ? xG : xL;
    const float* __restrict__ alp = gz ? alpG : alpL;
    const float* __restrict__ A   = gz ? AG : AL;
    const float* __restrict__ LB  = gz ? LBG : LBL;
    float* __restrict__ out       = gz ? outGp : outLp;

    const int tid = threadIdx.x, wid = tid >> 6, l = tid & 63;
    const int la = l & 15, lg = l >> 4;

    __shared__ __align__(16) uchar_t lds[39288];
    ushort_t* x16   = (ushort_t*)(lds);           // [100][136]
    ushort_t* xT    = (ushort_t*)(lds);           // [128][104], after gating-p1
    ushort_t* sc    = (ushort_t*)(lds + 27200);   // [2][16][104]
    ushort_t* A16   = (ushort_t*)(lds + 33856);   // [8][128], scores phase only
    ushort_t* out16 = (ushort_t*)(lds + 33856);   // [16][136], PV phase (A16 dead)
    uchar_t*  adjb  = lds + 38208;                // [10][104]
    float*    alps  = (float*)(lds + 39248);

    // ---- S1: stage x16 (paired dwords), A16, adjb, sc zero, alps
    for (int idx = tid; idx < 100 * 64; idx += 512) {
        int j = idx >> 6, d2 = idx & 63;
        const float* xp = x + ((size_t)b * cN + j) * cD + 2 * d2;
        *(unsigned*)&x16[j * 136 + 2 * d2] = pkh2(xp[0], xp[1]);
    }
    {   // 8 rows x 64 dwords
        int row = tid >> 6, d2 = tid & 63;
        const float* ap = A + row * cD + 2 * d2;
        *(unsigned*)&A16[row * 128 + 2 * d2] = pkh2(ap[0], ap[1]);
    }
    for (int idx = tid; idx < cG * cN; idx += 512) {
        int i = idx / cN, j = idx % cN;
        adjb[i * 104 + j] = (uchar_t)adj[((size_t)b * cN + r0 + i) * cN + j];
    }
    for (int idx = tid; idx < 1664; idx += 512) ((unsigned*)sc)[idx] = 0u;
    if (tid < cG) alps[tid] = alp[b * cN + r0 + tid];
    __syncthreads();

    // ---- scores, both h: C[j][(ik)] = sum_d x16[j][d] * (x16[r0+i][d]*A16[h*4+k][d])
    for (int h = 0; h < 2; h++) {
        f16x8 afr[4];
        const int krow = (h * 4 + (la & 3)) * 128;
#pragma unroll
        for (int kc = 0; kc < 4; kc++) afr[kc] = ldf(&A16[krow + kc * 32 + lg * 8]);
        for (int job = wid; job < 21; job += 8) {
            int mt = job / 3, nt = job % 3;
            int arow = mt * 16 + la; if (arow > 99) arow = 99;
            int brow = nt * 16 + la; if (brow > 39) brow = 39;
            int xrow = r0 + (brow >> 2);
            f32x4 c = {0.f, 0.f, 0.f, 0.f};
#pragma unroll
            for (int kc = 0; kc < 4; kc++) {
                f16x8 a  = ldf(&x16[arow * 136 + kc * 32 + lg * 8]);
                f16x8 xb = ldf(&x16[xrow * 136 + kc * 32 + lg * 8]);
                c = mm(a, xb * afr[kc], c);
            }
            int col = nt * 16 + la, i = col >> 2, k = col & 3;
            if (i < cG) {
#pragma unroll
                for (int r = 0; r < 4; r++) {
                    int j = mt * 16 + lg * 4 + r;
                    if (j < cN && (int)adjb[i * 104 + j] == k + 1) {
                        float v = c[r];
                        v = (v >= 0.f) ? v : 0.2f * v;     // leaky
                        sc[(h * 16 + i) * 104 + j] = f2hbits(v);
                    }
                }
            }
        }
    }
    __syncthreads();

    // ---- entmax: waves 0-3 rows {wid, 8+wid, 16+wid}; waves 4-7 rows {wid, 8+wid}
    {
        const bool w3 = (wid < 4);
        const float log2_rn = -6.6438561897747395f;
        float X0[3], X1[3], INV[3], TLO[3], DM[3], FLO[3], TM[3], S[3];
        int RI[3], RH[3];
#pragma unroll
        for (int q2 = 0; q2 < 3; q2++) {
            if (q2 < 2 || w3) {
                int r = (q2 < 2) ? (wid + 8 * q2) : (16 + wid);
                RI[q2] = r >> 1; RH[q2] = r & 1;
                float am1 = alps[RI[q2]] - 1.f;
                INV[q2] = 1.f / am1;
                X0[q2] = h2f(sc[(RH[q2] * 16 + RI[q2]) * 104 + l]) * am1;
                X1[q2] = (l + 64 < cN) ? h2f(sc[(RH[q2] * 16 + RI[q2]) * 104 + l + 64]) * am1 : -INFINITY;
                TM[q2] = ex2(am1 * log2_rn);
            }
        }
        float MX[3];
#pragma unroll
        for (int q2 = 0; q2 < 3; q2++) if (q2 < 2 || w3) MX[q2] = fmaxf(X0[q2], X1[q2]);
#pragma unroll
        for (int o = 32; o; o >>= 1) {
#pragma unroll
            for (int q2 = 0; q2 < 3; q2++) if (q2 < 2 || w3) MX[q2] = fmaxf(MX[q2], __shfl_xor(MX[q2], o, 64));
        }
#pragma unroll
        for (int q2 = 0; q2 < 3; q2++) if (q2 < 2 || w3) { TLO[q2] = MX[q2] - 1.f; DM[q2] = 1.f - TM[q2]; }
#pragma unroll
        for (int q2 = 0; q2 < 3; q2++) if (q2 < 2 || w3) {
            float z0 = fmaxf(X0[q2] - TLO[q2], 0.f);
            float z1 = fmaxf(X1[q2] - TLO[q2], 0.f);
            S[q2] = ex2(INV[q2] * lg2(z0)) + ex2(INV[q2] * lg2(z1));
        }
#pragma unroll
        for (int o = 32; o; o >>= 1) {
#pragma unroll
            for (int q2 = 0; q2 < 3; q2++) if (q2 < 2 || w3) S[q2] += __shfl_xor(S[q2], o, 64);
        }
#pragma unroll
        for (int q2 = 0; q2 < 3; q2++) if (q2 < 2 || w3) FLO[q2] = S[q2] - 1.f;

#pragma unroll 1
        for (int it = 0; it < N_ITER_RUN - 1; ++it) {
#pragma unroll
            for (int q2 = 0; q2 < 3; q2++) if (q2 < 2 || w3) { DM[q2] *= 0.5f; TM[q2] = TLO[q2] + DM[q2]; }
#pragma unroll
            for (int q2 = 0; q2 < 3; q2++) if (q2 < 2 || w3) {
                float z0 = fmaxf(X0[q2] - TM[q2], 0.f);
                float z1 = fmaxf(X1[q2] - TM[q2], 0.f);
                S[q2] = ex2(INV[q2] * lg2(z0)) + ex2(INV[q2] * lg2(z1));
            }
#pragma unroll
            for (int o = 32; o; o >>= 1) {
#pragma unroll
                for (int q2 = 0; q2 < 3; q2++) if (q2 < 2 || w3) S[q2] += __shfl_xor(S[q2], o, 64);
            }
#pragma unroll
            for (int q2 = 0; q2 < 3; q2++) if (q2 < 2 || w3)
                if ((S[q2] - 1.f) * FLO[q2] >= 0.f) TLO[q2] = TM[q2];
        }
        float P0[3], P1[3];
#pragma unroll
        for (int q2 = 0; q2 < 3; q2++) if (q2 < 2 || w3) {
            DM[q2] *= 0.5f; TM[q2] = TLO[q2] + DM[q2];
            float z0 = fmaxf(X0[q2] - TM[q2], 0.f);
            float z1 = fmaxf(X1[q2] - TM[q2], 0.f);
            P0[q2] = ex2(INV[q2] * lg2(z0));
            P1[q2] = ex2(INV[q2] * lg2(z1));
            S[q2] = P0[q2] + P1[q2];
        }
#pragma unroll
        for (int o = 32; o; o >>= 1) {
#pragma unroll
            for (int q2 = 0; q2 < 3; q2++) if (q2 < 2 || w3) S[q2] += __shfl_xor(S[q2], o, 64);
        }
        __syncthreads();
#pragma unroll
        for (int q2 = 0; q2 < 3; q2++) {
            if (q2 < 2 || w3) {
                float invs = 1.f / S[q2];
                sc[(RH[q2] * 16 + RI[q2]) * 104 + l] = f2hbits(P0[q2] * invs);
                if (l + 64 < cN) sc[(RH[q2] * 16 + RI[q2]) * 104 + l + 64] = f2hbits(P1[q2] * invs);
            }
        }
    }

    // ---- gating part 1 (x16 still intact): cg[h] = xi @ LW_top
    f32x4 cg0 = {0.f, 0.f, 0.f, 0.f}, cg1 = {0.f, 0.f, 0.f, 0.f};
    {
        const int d = wid * 16 + la;
        int arow = r0 + la; if (arow > 99) arow = 99;
#pragma unroll
        for (int h = 0; h < 2; h++) {
            const ushort_t* lwbase = LWT + ((size_t)(gz * 2 + h) * cD + d) * 256;
            f32x4 c = {0.f, 0.f, 0.f, 0.f};
#pragma unroll
            for (int kc = 0; kc < 4; kc++) {
                f16x8 a = ldf(&x16[arow * 136 + kc * 32 + lg * 8]);
                uint4 u = *(const uint4*)(lwbase + kc * 32 + lg * 8);
                f16x8 bb; __builtin_memcpy(&bb, &u, 16);
                c = mm(a, bb, c);
            }
            if (h) cg1 = c; else cg0 = c;
        }
    }
    __syncthreads();

    // ---- xT build from GLOBAL x (L2-hot), b128 writes, into dead x16 region
    for (int job = tid; job < 13 * 128; job += 512) {
        int d2 = job & 127, jc = job >> 7;
        f16x8 v;
#pragma unroll
        for (int t = 0; t < 8; t++) {
            int j = jc * 8 + t;
            float f = (j < cN) ? x[((size_t)b * cN + j) * cD + d2] : 0.f;
            v[t] = (__fp16)f;
        }
        uint4 u; __builtin_memcpy(&u, &v, 16);
        *(uint4*)(&xT[d2 * 104 + jc * 8]) = u;
    }
    __syncthreads();

    // ---- PV + gating part 2, per h ----
    float res[4] = {0.f, 0.f, 0.f, 0.f};
    const int dt = wid;
    const int d = dt * 16 + la;
    for (int h = 0; h < 2; h++) {
        if (h) __syncthreads();
        {
            f32x4 c = {0.f, 0.f, 0.f, 0.f};
#pragma unroll
            for (int kc = 0; kc < 3; kc++) {
                f16x8 a  = ldf(&sc[(h * 16 + la) * 104 + kc * 32 + lg * 8]);
                f16x8 bb = ldf(&xT[(dt * 16 + la) * 104 + kc * 32 + lg * 8]);
                c = mm(a, bb, c);
            }
#pragma unroll
            for (int r = 0; r < 4; r++) {
                int i = lg * 4 + r;
                float acc = c[r];
#pragma unroll
                for (int j = 96; j < 100; j++)
                    acc += h2f(sc[(h * 16 + i) * 104 + j]) * h2f(xT[d * 104 + j]);
                if (i < cG) out16[i * 136 + d] = f2hbits(acc);
            }
        }
        __syncthreads();
        {
            f32x4 c = h ? cg1 : cg0;
            const ushort_t* lwbase = LWT + ((size_t)(gz * 2 + h) * cD + d) * 256 + 128;
#pragma unroll
            for (int kc = 0; kc < 4; kc++) {
                f16x8 a = ldf(&out16[la * 136 + kc * 32 + lg * 8]);
                uint4 u = *(const uint4*)(lwbase + kc * 32 + lg * 8);
                f16x8 bb; __builtin_memcpy(&bb, &u, 16);
                c = mm(a, bb, c);
            }
            float lb = LB[h * cD + d];
#pragma unroll
            for (int r = 0; r < 4; r++) {
                int i = lg * 4 + r;
                float g = sigm(c[r] + lb);
                float o = h2f(out16[i * 136 + d]);
                float xi = h2f(xT[d * 104 + r0 + i]);
                res[r] += g * o + (1.f - g) * xi;
            }
        }
    }
#pragma unroll
    for (int r = 0; r < 4; r++) {
        int i = lg * 4 + r;
        if (i < cG) out[((size_t)b * cN + r0 + i) * cD + d] = res[r];
    }
}

// ---------------- kernel 3: fused tail (one block per b, 512 threads) ----------------
__global__ __launch_bounds__(512) void k_tail(
    const float* __restrict__ S, const float* __restrict__ T,
    const int* __restrict__ iidx, const float* __restrict__ g2w,
    const float* __restrict__ G1b, const float* __restrict__ W2,
    const ushort_t* __restrict__ W0T, const ushort_t* __restrict__ W1gT,
    const ushort_t* __restrict__ W1bT, const ushort_t* __restrict__ G1T,
    const float* __restrict__ posW1, float* __restrict__ outp)
{
    const int b = blockIdx.x;
    const int tid = threadIdx.x, wid = tid >> 6, l = tid & 63;
    const int la = l & 15, lg = l >> 4;
    const float scale = 0.088388347648318447f;   // 1/sqrt(128)

    __shared__ __align__(16) ushort_t s16[100 * 136];   // s, then snew, then nh
    __shared__ __align__(16) ushort_t t16[100 * 136];   // t, then hid
    __shared__ float a_sh[cN];
    __shared__ float part[4][cD];
    __shared__ float hs_s[cD];
    __shared__ float hsg_s[cD];
    __shared__ float beta_s[cN];
    __shared__ int   idx_s[cN];

    for (int idx = tid; idx < 100 * 64; idx += 512) {
        int n = idx >> 6, d2 = idx & 63;
        const float* sp = S + ((size_t)b * cN + n) * cD + 2 * d2;
        const float* tp = T + ((size_t)b * cN + n) * cD + 2 * d2;
        *(unsigned*)&s16[n * 136 + 2 * d2] = pkh2(sp[0], sp[1]);
        *(unsigned*)&t16[n * 136 + 2 * d2] = pkh2(tp[0], tp[1]);
    }
    if (tid < cN) idx_s[tid] = iidx[b * cN + tid];
    __syncthreads();

    if (wid < 7) {
        int arow = wid * 16 + la; if (arow > 99) arow = 99;
        float asum[4] = {0.f, 0.f, 0.f, 0.f};
        for (int nt = 0; nt < 8; nt++) {
            f32x4 cs = {0.f, 0.f, 0.f, 0.f}, ct = {0.f, 0.f, 0.f, 0.f};
            const ushort_t* b0 = W0T + (size_t)(nt * 16 + la) * cD;
            const ushort_t* b1 = W1gT + (size_t)(nt * 16 + la) * cD;
#pragma unroll
            for (int kc = 0; kc < 4; kc++) {
                f16x8 as = ldf(&s16[arow * 136 + kc * 32 + lg * 8]);
                f16x8 at = ldf(&t16[arow * 136 + kc * 32 + lg * 8]);
                uint4 u0 = *(const uint4*)(b0 + kc * 32 + lg * 8);
                uint4 u1 = *(const uint4*)(b1 + kc * 32 + lg * 8);
                f16x8 w0v, w1v; __builtin_memcpy(&w0v, &u0, 16); __builtin_memcpy(&w1v, &u1, 16);
                cs = mm(as, w0v, cs);
                ct = mm(at, w1v, ct);
            }
#pragma unroll
            for (int r = 0; r < 4; r++) asum[r] += cs[r] * ct[r];
        }
#pragma unroll
        for (int o = 8; o; o >>= 1) {
#pragma unroll
            for (int r = 0; r < 4; r++) asum[r] += __shfl_xor(asum[r], o, 64);
        }
        if (la == 0) {
#pragma unroll
            for (int r = 0; r < 4; r++) {
                int n = wid * 16 + lg * 4 + r;
                if (n < cN) a_sh[n] = asum[r] * scale;
            }
        }
    }
    __syncthreads();

    for (int idx = tid; idx < 100 * 64; idx += 512) {
        int n = idx >> 6, d2 = idx & 63;
        unsigned su = *(unsigned*)&s16[n * 136 + 2 * d2];
        unsigned tu = *(unsigned*)&t16[n * 136 + 2 * d2];
        float a = a_sh[n];
        float s0 = h2f((ushort_t)(su & 0xffffu)), s1 = h2f((ushort_t)(su >> 16));
        float t0 = h2f((ushort_t)(tu & 0xffffu)), t1 = h2f((ushort_t)(tu >> 16));
        *(unsigned*)&s16[n * 136 + 2 * d2] = pkh2(s0 + a * (t0 - s0), s1 + a * (t1 - s1));
    }
    __syncthreads();

    for (int idx = tid; idx < 100 * 64; idx += 512) {
        int n = idx >> 6, d2 = idx & 63;
        int rsrc = idx_s[n];
        *(unsigned*)&t16[n * 136 + 2 * d2] = *(unsigned*)&s16[rsrc * 136 + 2 * d2];
    }
    __syncthreads();

    {
        int g = tid >> 7, d = tid & 127;
        float sum = 0.f;
        for (int n = g * 25; n < g * 25 + 25; n++) sum += h2f(t16[n * 136 + d]);
        part[g][d] = sum;
    }
    __syncthreads();
    if (tid < cD) hs_s[tid] = (part[0][tid] + part[1][tid] + part[2][tid] + part[3][tid]) * (1.f / (100.f + 1e-7f));
    __syncthreads();
    if (tid < cD) {
        float acc = 0.f;
        for (int c = 0; c < cD; c++) acc += hs_s[c] * g2w[c * cD + tid];
        hsg_s[tid] = acc;
    }
    __syncthreads();

    if (wid < 7) {
        int arow = wid * 16 + la; if (arow > 99) arow = 99;
        for (int nt = 0; nt < 8; nt++) {
            f32x4 c = {0.f, 0.f, 0.f, 0.f};
            const ushort_t* bb = W1bT + (size_t)(nt * 16 + la) * cD;
#pragma unroll
            for (int kc = 0; kc < 4; kc++) {
                f16x8 a = ldf(&t16[arow * 136 + kc * 32 + lg * 8]);
                uint4 u = *(const uint4*)(bb + kc * 32 + lg * 8);
                f16x8 wv; __builtin_memcpy(&wv, &u, 16);
                c = mm(a, wv, c);
            }
            int d = nt * 16 + la;
#pragma unroll
            for (int r = 0; r < 4; r++) {
                int n = wid * 16 + lg * 4 + r;
                if (n < cN) s16[n * 136 + d] = f2hbits(tanhf(c[r] + posW1[n * cD + d]));
            }
        }
    }
    __syncthreads();

    if (wid < 7) {
        int arow = wid * 16 + la; if (arow > 99) arow = 99;
        float bsum[4] = {0.f, 0.f, 0.f, 0.f};
        for (int nt = 0; nt < 8; nt++) {
            f32x4 c = {0.f, 0.f, 0.f, 0.f};
            const ushort_t* bb = G1T + (size_t)(nt * 16 + la) * cD;
#pragma unroll
            for (int kc = 0; kc < 4; kc++) {
                f16x8 a = ldf(&s16[arow * 136 + kc * 32 + lg * 8]);
                uint4 u = *(const uint4*)(bb + kc * 32 + lg * 8);
                f16x8 wv; __builtin_memcpy(&wv, &u, 16);
                c = mm(a, wv, c);
            }
            int d = nt * 16 + la;
            float add = G1b[d] + hsg_s[d];
            float w2v = W2[d];
#pragma unroll
            for (int r = 0; r < 4; r++) bsum[r] += sigm(c[r] + add) * w2v;
        }
#pragma unroll
        for (int o = 8; o; o >>= 1) {
#pragma unroll
            for (int r = 0; r < 4; r++) bsum[r] += __shfl_xor(bsum[r], o, 64);
        }
        if (la == 0) {
#pragma unroll
            for (int r = 0; r < 4; r++) {
                int n = wid * 16 + lg * 4 + r;
                if (n < cN) beta_s[n] = bsum[r];
            }
        }
    }
    __syncthreads();

    {
        int g = tid >> 7, d = tid & 127;
        float sum = 0.f;
        for (int n = g * 25; n < g * 25 + 25; n++) sum += beta_s[n] * h2f(t16[n * 136 + d]);
        part[g][d] = sum;
    }
    __syncthreads();
    if (tid < cD) outp[b * cD + tid] = part[0][tid] + part[1][tid] + part[2][tid] + part[3][tid];
}

extern "C" void kernel_launch(void* const* d_in, const int* in_sizes, int n_in,
                              void* d_out, int out_size, void* d_ws, size_t ws_size,
                              hipStream_t stream) {
    const float* gnn   = (const float*)d_in[0];
    const float* drop  = (const float*)d_in[1];
    const float* proto = (const float*)d_in[2];
    const float* pos   = (const float*)d_in[3];
    const float* laL_a = (const float*)d_in[4];
    const float* laL_w = (const float*)d_in[5];
    const float* laL_b = (const float*)d_in[6];
    const float* ssL_w = (const float*)d_in[7];
    const float* ssL_b = (const float*)d_in[8];
    const float* laG_a = (const float*)d_in[9];
    const float* laG_w = (const float*)d_in[10];
    const float* laG_b = (const float*)d_in[11];
    const float* ssG_w = (const float*)d_in[12];
    const float* ssG_b = (const float*)d_in[13];
    const float* gem_w = (const float*)d_in[14];
    const float* fn_w  = (const float*)d_in[15];
    const float* fn_b  = (const float*)d_in[16];
    const float* w_1   = (const float*)d_in[17];
    const float* w_2   = (const float*)d_in[18];
    const float* glu1w = (const float*)d_in[19];
    const float* glu1b = (const float*)d_in[20];
    const float* glu2w = (const float*)d_in[21];
    const int*   adj   = (const int*)d_in[22];
    const int*   iidx  = (const int*)d_in[23];
    const void*  m0    = d_in[24];
    float* out = (float*)d_out;

    const size_t BND = (size_t)cB * cN * cD;
    float* w = (float*)d_ws;
    float* bufA = w;               // gi
    float* bufB = bufA + BND;      // pi
    float* locS = bufB + BND;
    float* gloS = locS + BND;
    float* aL   = gloS + BND;
    float* aG   = aL + (size_t)cB * cN;
    float* avgdot = aG + (size_t)cB * cN;
    ushort_t* LWT  = (ushort_t*)(avgdot + cB);
    ushort_t* W1bT = LWT + (size_t)4 * cD * 256;
    ushort_t* G1T  = W1bT + (size_t)cD * cD;
    ushort_t* W0T  = G1T + (size_t)cD * cD;
    ushort_t* W1gT = W0T + (size_t)cD * cD;
    float* posW1   = (float*)(W1gT + (size_t)cD * cD);

    k_cvtw<<<dim3(9, 8), dim3(256), 0, stream>>>(laL_w, laG_w, w_1, glu1w, gem_w, pos,
                                                 LWT, W1bT, G1T, W0T, W1gT, posW1);
    k_prep_a<<<dim3(cB), dim3(256), 0, stream>>>(gnn, m0, fn_w, avgdot);
    k_prep_b<<<dim3(cB, 13), dim3(512), 0, stream>>>(gnn, drop, proto, m0, avgdot,
                                                     fn_w, fn_b, ssL_w, ssL_b, ssG_w, ssG_b,
                                                     bufA, bufB, aL, aG);
    k_gnn<<<dim3(cNCH * cB * 2), dim3(512), 0, stream>>>(
        bufA, bufB, adj, aL, aG, laL_a, laG_a, LWT, laL_b, laG_b, locS, gloS);
    k_tail<<<dim3(cB), dim3(512), 0, stream>>>(locS, gloS, iidx, glu2w, glu1b, w_2,
                                               W0T, W1gT, W1bT, G1T, posW1, out);
}

// Round 18
// 288.336 us; speedup vs baseline: 1.3985x; 1.0379x over previous
//
#include <hip/hip_runtime.h>
#include <math.h>

// DenoiseEncoder forward, MI355X. B=256,N=100,D=128,H=2.
// v14 = v13 (round-17 confirmed 299us) with N_ITER_RUN 12 -> 10.
// Error analysis: rel p-error ~ 4.6*2^-k/z (alpha-independent); k=10 -> ~0.5%,
// absmax headroom 17.2 vs current 4.0.
constexpr int cB = 256, cN = 100, cD = 128, cH = 2, cG = 10, cNCH = cN / cG;
constexpr int N_ITER_RUN = 10;

typedef __fp16 h2 __attribute__((ext_vector_type(2)));
typedef __fp16 f16x8 __attribute__((ext_vector_type(8)));
typedef float f32x4 __attribute__((ext_vector_type(4)));
typedef unsigned short ushort_t;
typedef unsigned char uchar_t;

// ---------------- helpers ----------------
__device__ __forceinline__ float wsum(float v) {
#pragma unroll
    for (int o = 32; o; o >>= 1) v += __shfl_xor(v, o, 64);
    return v;
}
__device__ __forceinline__ float sigm(float x) { return 1.f / (1.f + __expf(-x)); }
__device__ __forceinline__ float ex2(float x) {
#if __has_builtin(__builtin_amdgcn_exp2f)
    return __builtin_amdgcn_exp2f(x);
#else
    return exp2f(x);
#endif
}
__device__ __forceinline__ float lg2(float x) {
#if __has_builtin(__builtin_amdgcn_logf)
    return __builtin_amdgcn_logf(x);       // v_log_f32; lg2(0) = -inf
#else
    return __log2f(x);
#endif
}
__device__ __forceinline__ unsigned pkh2(float a, float b) {
#if __has_builtin(__builtin_amdgcn_cvt_pkrtz)
    h2 r = __builtin_amdgcn_cvt_pkrtz(a, b);
#else
    h2 r; r.x = (__fp16)a; r.y = (__fp16)b;
#endif
    unsigned u; __builtin_memcpy(&u, &r, 4); return u;
}
__device__ __forceinline__ ushort_t f2hbits(float v) {
    __fp16 h = (__fp16)v;
    ushort_t u; __builtin_memcpy(&u, &h, 2); return u;
}
__device__ __forceinline__ float h2f(ushort_t u) {
    __fp16 h; __builtin_memcpy(&h, &u, 2); return (float)h;
}
__device__ __forceinline__ f16x8 ldf(const ushort_t* p) {   // 16B-aligned load
    uint4 u = *(const uint4*)p;
    f16x8 a; __builtin_memcpy(&a, &u, 16); return a;
}
__device__ __forceinline__ f32x4 mm(f16x8 a, f16x8 b, f32x4 c) {
    return __builtin_amdgcn_mfma_f32_16x16x32_f16(a, b, c, 0, 0, 0);
}

// ---------------- kernel 0: weight converts + posW1 (grid (9,8)) ----------------
__global__ __launch_bounds__(256) void k_cvtw(
    const float* __restrict__ LWL, const float* __restrict__ LWG,
    const float* __restrict__ W1, const float* __restrict__ G1w,
    const float* __restrict__ GW, const float* __restrict__ pos,
    ushort_t* __restrict__ LWT, ushort_t* __restrict__ W1bT, ushort_t* __restrict__ G1T,
    ushort_t* __restrict__ W0T, ushort_t* __restrict__ W1gT, float* __restrict__ posW1)
{
    const int bz = blockIdx.x;
    if (bz < 4) {
        const int gz = bz >> 1, h = bz & 1;
        const int cseg = blockIdx.y * 32;
        const float* src = (gz ? LWG : LWL) + (size_t)h * 2 * cD * cD;
        for (int idx = threadIdx.x; idx < 32 * cD; idx += 256) {
            int c = cseg + (idx >> 7), d = idx & 127;
            LWT[((size_t)bz * cD + d) * 256 + c] = f2hbits(src[c * cD + d]);
        }
    } else if (bz < 8) {
        const float* src = (bz == 4) ? (W1 + cD * cD) : (bz == 5) ? G1w
                         : (bz == 6) ? GW : (GW + cD * cD);
        ushort_t* dst = (bz == 4) ? W1bT : (bz == 5) ? G1T : (bz == 6) ? W0T : W1gT;
        const int cseg = blockIdx.y * 16;
        for (int idx = threadIdx.x; idx < 16 * cD; idx += 256) {
            int c = cseg + (idx >> 7), d = idx & 127;
            dst[(size_t)d * cD + c] = f2hbits(src[c * cD + d]);
        }
    } else {
        int n0 = blockIdx.y * 13;
        int cnt = (n0 + 13 <= cN) ? 13 : (cN - n0);
        for (int idx = threadIdx.x; idx < cnt * cD; idx += 256) {
            int n = n0 + (idx >> 7), d = idx & 127;
            float acc = 0.f;
            for (int c = 0; c < cD; c++) acc += pos[n * cD + c] * W1[c * cD + d];
            posW1[n * cD + d] = acc;
        }
    }
}

// ---------------- kernel 1a: avgdot[b] ----------------
__global__ __launch_bounds__(256) void k_prep_a(
    const float* __restrict__ gnn, const void* __restrict__ m0,
    const float* __restrict__ fnw, float* __restrict__ avgdot)
{
    const int b = blockIdx.x, tid = threadIdx.x;
    const int w = tid >> 6, l = tid & 63;
    const int d0 = l, d1 = l + 64;
    __shared__ int fmt_s;
    __shared__ float mrow[cN];
    __shared__ float part[4][cD];
    __shared__ float red2[2];
    if (tid < 64) {
        unsigned u = ((const unsigned*)m0)[tid];
        int c = ((u & 0xffu) != 0) + ((u & 0xff00u) != 0) + ((u & 0xff0000u) != 0) + ((u >> 24) != 0);
        float cf = wsum((float)c);
        if (tid == 0) fmt_s = (cf > 128.f);
    }
    __syncthreads();
    if (tid < cN) {
        int idx = b * cN + tid;
        float m;
        if (fmt_s) m = ((const unsigned char*)m0)[idx] ? 1.f : 0.f;
        else       m = ((const int*)m0)[idx] ? 1.f : 0.f;
        mrow[tid] = m;
    }
    __syncthreads();
    float s0 = 0.f, s1 = 0.f;
    for (int n = w; n < cN; n += 4) {
        size_t o = ((size_t)b * cN + n) * cD;
        float m = mrow[n];
        s0 += gnn[o + d0] * m;
        s1 += gnn[o + d1] * m;
    }
    part[w][d0] = s0; part[w][d1] = s1;
    __syncthreads();
    const float rcnt = 1.f / (100.f + 1e-7f);
    if (tid < cD) {
        float avg = (part[0][tid] + part[1][tid] + part[2][tid] + part[3][tid]) * rcnt;
        float v = wsum(avg * fnw[tid]);
        if ((tid & 63) == 0) red2[tid >> 6] = v;
    }
    __syncthreads();
    if (tid == 0) avgdot[b] = red2[0] + red2[1];
}

// ---------------- kernel 1b: per-(b,n) wave: gi, pi, aL, aG ----------------
__global__ __launch_bounds__(512) void k_prep_b(
    const float* __restrict__ gnn, const float* __restrict__ drop, const float* __restrict__ proto,
    const void* __restrict__ m0, const float* __restrict__ avgdot,
    const float* __restrict__ fnw, const float* __restrict__ fnb,
    const float* __restrict__ ssLw, const float* __restrict__ ssLb,
    const float* __restrict__ ssGw, const float* __restrict__ ssGb,
    float* __restrict__ gi, float* __restrict__ pi,
    float* __restrict__ aL, float* __restrict__ aG)
{
    const int b = blockIdx.x, tid = threadIdx.x;
    const int wid = tid >> 6, l = tid & 63;
    const int n = blockIdx.y * 8 + wid;
    __shared__ int fmt_s;
    if (tid < 64) {
        unsigned u = ((const unsigned*)m0)[tid];
        int c = ((u & 0xffu) != 0) + ((u & 0xff00u) != 0) + ((u & 0xff0000u) != 0) + ((u >> 24) != 0);
        float cf = wsum((float)c);
        if (tid == 0) fmt_s = (cf > 128.f);
    }
    __syncthreads();
    if (n >= cN) return;
    float m;
    {
        int idx = b * cN + n;
        if (fmt_s) m = ((const unsigned char*)m0)[idx] ? 1.f : 0.f;
        else       m = ((const int*)m0)[idx] ? 1.f : 0.f;
    }
    const float dm = 1.f - m;
    const int d0 = l, d1 = l + 64;
    const size_t o = ((size_t)b * cN + n) * cD;
    float dr0 = drop[o + d0] * dm, dr1 = drop[o + d1] * dm;
    float p0 = proto[o + d0] * m,  p1 = proto[o + d1] * m;
    pi[o + d0] = p0; pi[o + d1] = p1;
    float r1 = wsum(dr0 * fnw[cD + d0] + dr1 * fnw[cD + d1]);
    float r2 = wsum(p0 * ssGw[d0] + p1 * ssGw[d1]);
    float alpha = r1 + avgdot[b] + fnb[0];
    float g0 = gnn[o + d0] * m + alpha * dr0;
    float g1 = gnn[o + d1] * m + alpha * dr1;
    gi[o + d0] = g0; gi[o + d1] = g1;
    float r3 = wsum(g0 * ssLw[d0] + g1 * ssLw[d1]);
    if (l == 0) {
        aL[b * cN + n] = 1.f + sigm(r3 + ssLb[0]);
        aG[b * cN + n] = 1.f + sigm(r2 + ssGb[0]);
    }
}

// ---------------- kernel 2: GNN via MFMA. 512 threads, G=10 rows ----------------
// 1D grid 5120 with XCD-affinity decode (wgid%8 == b%8). LDS 39288 B -> 4 blocks/CU.
__global__ __launch_bounds__(512, 8) void k_gnn(
    const float* __restrict__ xL, const float* __restrict__ xG,
    const int* __restrict__ adj,
    const float* __restrict__ alpL, const float* __restrict__ alpG,
    const float* __restrict__ AL, const float* __restrict__ AG,
    const ushort_t* __restrict__ LWT,
    const float* __restrict__ LBL, const float* __restrict__ LBG,
    float* __restrict__ outLp, float* __restrict__ outGp)
{
    const int wg = blockIdx.x;
    const int xcd = wg & 7;
    const int q = wg >> 3;
    const int b = (q / 20) * 8 + xcd;
    const int c20 = q % 20;
    const int gz = c20 & 1;
    const int r0 = (c20 >> 1) * cG;

    const float* __restrict__ x   = gz ? xG : xL;
    const float* __restrict__ alp = gz ? alpG : alpL;
    const float* __restrict__ A   = gz ? AG : AL;
    const float* __restrict__ LB  = gz ? LBG : LBL;
    float* __restrict__ out       = gz ? outGp : outLp;

    const int tid = threadIdx.x, wid = tid >> 6, l = tid & 63;
    const int la = l & 15, lg = l >> 4;

    __shared__ __align__(16) uchar_t lds[39288];
    ushort_t* x16   = (ushort_t*)(lds);           // [100][136]
    ushort_t* xT    = (ushort_t*)(lds);           // [128][104], after gating-p1
    ushort_t* sc    = (ushort_t*)(lds + 27200);   // [2][16][104]
    ushort_t* A16   = (ushort_t*)(lds + 33856);   // [8][128], scores phase only
    ushort_t* out16 = (ushort_t*)(lds + 33856);   // [16][136], PV phase (A16 dead)
    uchar_t*  adjb  = lds + 38208;                // [10][104]
    float*    alps  = (float*)(lds + 39248);

    // ---- S1: stage x16 (paired dwords), A16, adjb, sc zero, alps
    for (int idx = tid; idx < 100 * 64; idx += 512) {
        int j = idx >> 6, d2 = idx & 63;
        const float* xp = x + ((size_t)b * cN + j) * cD + 2 * d2;
        *(unsigned*)&x16[j * 136 + 2 * d2] = pkh2(xp[0], xp[1]);
    }
    {   // 8 rows x 64 dwords
        int row = tid >> 6, d2 = tid & 63;
        const float* ap = A + row * cD + 2 * d2;
        *(unsigned*)&A16[row * 128 + 2 * d2] = pkh2(ap[0], ap[1]);
    }
    for (int idx = tid; idx < cG * cN; idx += 512) {
        int i = idx / cN, j = idx % cN;
        adjb[i * 104 + j] = (uchar_t)adj[((size_t)b * cN + r0 + i) * cN + j];
    }
    for (int idx = tid; idx < 1664; idx += 512) ((unsigned*)sc)[idx] = 0u;
    if (tid < cG) alps[tid] = alp[b * cN + r0 + tid];
    __syncthreads();

    // ---- scores, both h: C[j][(ik)] = sum_d x16[j][d] * (x16[r0+i][d]*A16[h*4+k][d])
    for (int h = 0; h < 2; h++) {
        f16x8 afr[4];
        const int krow = (h * 4 + (la & 3)) * 128;
#pragma unroll
        for (int kc = 0; kc < 4; kc++) afr[kc] = ldf(&A16[krow + kc * 32 + lg * 8]);
        for (int job = wid; job < 21; job += 8) {
            int mt = job / 3, nt = job % 3;
            int arow = mt * 16 + la; if (arow > 99) arow = 99;
            int brow = nt * 16 + la; if (brow > 39) brow = 39;
            int xrow = r0 + (brow >> 2);
            f32x4 c = {0.f, 0.f, 0.f, 0.f};
#pragma unroll
            for (int kc = 0; kc < 4; kc++) {
                f16x8 a  = ldf(&x16[arow * 136 + kc * 32 + lg * 8]);
                f16x8 xb = ldf(&x16[xrow * 136 + kc * 32 + lg * 8]);
                c = mm(a, xb * afr[kc], c);
            }
            int col = nt * 16 + la, i = col >> 2, k = col & 3;
            if (i < cG) {
#pragma unroll
                for (int r = 0; r < 4; r++) {
                    int j = mt * 16 + lg * 4 + r;
                    if (j < cN && (int)adjb[i * 104 + j] == k + 1) {
                        float v = c[r];
                        v = (v >= 0.f) ? v : 0.2f * v;     // leaky
                        sc[(h * 16 + i) * 104 + j] = f2hbits(v);
                    }
                }
            }
        }
    }
    __syncthreads();

    // ---- entmax: waves 0-3 rows {wid, 8+wid, 16+wid}; waves 4-7 rows {wid, 8+wid}
    {
        const bool w3 = (wid < 4);
        const float log2_rn = -6.6438561897747395f;
        float X0[3], X1[3], INV[3], TLO[3], DM[3], FLO[3], TM[3], S[3];
        int RI[3], RH[3];
#pragma unroll
        for (int q2 = 0; q2 < 3; q2++) {
            if (q2 < 2 || w3) {
                int r = (q2 < 2) ? (wid + 8 * q2) : (16 + wid);
                RI[q2] = r >> 1; RH[q2] = r & 1;
                float am1 = alps[RI[q2]] - 1.f;
                INV[q2] = 1.f / am1;
                X0[q2] = h2f(sc[(RH[q2] * 16 + RI[q2]) * 104 + l]) * am1;
                X1[q2] = (l + 64 < cN) ? h2f(sc[(RH[q2] * 16 + RI[q2]) * 104 + l + 64]) * am1 : -INFINITY;
                TM[q2] = ex2(am1 * log2_rn);
            }
        }
        float MX[3];
#pragma unroll
        for (int q2 = 0; q2 < 3; q2++) if (q2 < 2 || w3) MX[q2] = fmaxf(X0[q2], X1[q2]);
#pragma unroll
        for (int o = 32; o; o >>= 1) {
#pragma unroll
            for (int q2 = 0; q2 < 3; q2++) if (q2 < 2 || w3) MX[q2] = fmaxf(MX[q2], __shfl_xor(MX[q2], o, 64));
        }
#pragma unroll
        for (int q2 = 0; q2 < 3; q2++) if (q2 < 2 || w3) { TLO[q2] = MX[q2] - 1.f; DM[q2] = 1.f - TM[q2]; }
#pragma unroll
        for (int q2 = 0; q2 < 3; q2++) if (q2 < 2 || w3) {
            float z0 = fmaxf(X0[q2] - TLO[q2], 0.f);
            float z1 = fmaxf(X1[q2] - TLO[q2], 0.f);
            S[q2] = ex2(INV[q2] * lg2(z0)) + ex2(INV[q2] * lg2(z1));
        }
#pragma unroll
        for (int o = 32; o; o >>= 1) {
#pragma unroll
            for (int q2 = 0; q2 < 3; q2++) if (q2 < 2 || w3) S[q2] += __shfl_xor(S[q2], o, 64);
        }
#pragma unroll
        for (int q2 = 0; q2 < 3; q2++) if (q2 < 2 || w3) FLO[q2] = S[q2] - 1.f;

#pragma unroll 1
        for (int it = 0; it < N_ITER_RUN - 1; ++it) {
#pragma unroll
            for (int q2 = 0; q2 < 3; q2++) if (q2 < 2 || w3) { DM[q2] *= 0.5f; TM[q2] = TLO[q2] + DM[q2]; }
#pragma unroll
            for (int q2 = 0; q2 < 3; q2++) if (q2 < 2 || w3) {
                float z0 = fmaxf(X0[q2] - TM[q2], 0.f);
                float z1 = fmaxf(X1[q2] - TM[q2], 0.f);
                S[q2] = ex2(INV[q2] * lg2(z0)) + ex2(INV[q2] * lg2(z1));
            }
#pragma unroll
            for (int o = 32; o; o >>= 1) {
#pragma unroll
                for (int q2 = 0; q2 < 3; q2++) if (q2 < 2 || w3) S[q2] += __shfl_xor(S[q2], o, 64);
            }
#pragma unroll
            for (int q2 = 0; q2 < 3; q2++) if (q2 < 2 || w3)
                if ((S[q2] - 1.f) * FLO[q2] >= 0.f) TLO[q2] = TM[q2];
        }
        float P0[3], P1[3];
#pragma unroll
        for (int q2 = 0; q2 < 3; q2++) if (q2 < 2 || w3) {
            DM[q2] *= 0.5f; TM[q2] = TLO[q2] + DM[q2];
            float z0 = fmaxf(X0[q2] - TM[q2], 0.f);
            float z1 = fmaxf(X1[q2] - TM[q2], 0.f);
            P0[q2] = ex2(INV[q2] * lg2(z0));
            P1[q2] = ex2(INV[q2] * lg2(z1));
            S[q2] = P0[q2] + P1[q2];
        }
#pragma unroll
        for (int o = 32; o; o >>= 1) {
#pragma unroll
            for (int q2 = 0; q2 < 3; q2++) if (q2 < 2 || w3) S[q2] += __shfl_xor(S[q2], o, 64);
        }
        __syncthreads();
#pragma unroll
        for (int q2 = 0; q2 < 3; q2++) {
            if (q2 < 2 || w3) {
                float invs = 1.f / S[q2];
                sc[(RH[q2] * 16 + RI[q2]) * 104 + l] = f2hbits(P0[q2] * invs);
                if (l + 64 < cN) sc[(RH[q2] * 16 + RI[q2]) * 104 + l + 64] = f2hbits(P1[q2] * invs);
            }
        }
    }

    // ---- gating part 1 (x16 still intact): cg[h] = xi @ LW_top
    f32x4 cg0 = {0.f, 0.f, 0.f, 0.f}, cg1 = {0.f, 0.f, 0.f, 0.f};
    {
        const int d = wid * 16 + la;
        int arow = r0 + la; if (arow > 99) arow = 99;
#pragma unroll
        for (int h = 0; h < 2; h++) {
            const ushort_t* lwbase = LWT + ((size_t)(gz * 2 + h) * cD + d) * 256;
            f32x4 c = {0.f, 0.f, 0.f, 0.f};
#pragma unroll
            for (int kc = 0; kc < 4; kc++) {
                f16x8 a = ldf(&x16[arow * 136 + kc * 32 + lg * 8]);
                uint4 u = *(const uint4*)(lwbase + kc * 32 + lg * 8);
                f16x8 bb; __builtin_memcpy(&bb, &u, 16);
                c = mm(a, bb, c);
            }
            if (h) cg1 = c; else cg0 = c;
        }
    }
    __syncthreads();

    // ---- xT build from GLOBAL x (L2-hot), b128 writes, into dead x16 region
    for (int job = tid; job < 13 * 128; job += 512) {
        int d2 = job & 127, jc = job >> 7;
        f16x8 v;
#pragma unroll
        for (int t = 0; t < 8; t++) {
            int j = jc * 8 + t;
            float f = (j < cN) ? x[((size_t)b * cN + j) * cD + d2] : 0.f;
            v[t] = (__fp16)f;
        }
        uint4 u; __builtin_memcpy(&u, &v, 16);
        *(uint4*)(&xT[d2 * 104 + jc * 8]) = u;
    }
    __syncthreads();

    // ---- PV + gating part 2, per h ----
    float res[4] = {0.f, 0.f, 0.f, 0.f};
    const int dt = wid;
    const int d = dt * 16 + la;
    for (int h = 0; h < 2; h++) {
        if (h) __syncthreads();
        {
            f32x4 c = {0.f, 0.f, 0.f, 0.f};
#pragma unroll
            for (int kc = 0; kc < 3; kc++) {
                f16x8 a  = ldf(&sc[(h * 16 + la) * 104 + kc * 32 + lg * 8]);
                f16x8 bb = ldf(&xT[(dt * 16 + la) * 104 + kc * 32 + lg * 8]);
                c = mm(a, bb, c);
            }
#pragma unroll
            for (int r = 0; r < 4; r++) {
                int i = lg * 4 + r;
                float acc = c[r];
#pragma unroll
                for (int j = 96; j < 100; j++)
                    acc += h2f(sc[(h * 16 + i) * 104 + j]) * h2f(xT[d * 104 + j]);
                if (i < cG) out16[i * 136 + d] = f2hbits(acc);
            }
        }
        __syncthreads();
        {
            f32x4 c = h ? cg1 : cg0;
            const ushort_t* lwbase = LWT + ((size_t)(gz * 2 + h) * cD + d) * 256 + 128;
#pragma unroll
            for (int kc = 0; kc < 4; kc++) {
                f16x8 a = ldf(&out16[la * 136 + kc * 32 + lg * 8]);
                uint4 u = *(const uint4*)(lwbase + kc * 32 + lg * 8);
                f16x8 bb; __builtin_memcpy(&bb, &u, 16);
                c = mm(a, bb, c);
            }
            float lb = LB[h * cD + d];
#pragma unroll
            for (int r = 0; r < 4; r++) {
                int i = lg * 4 + r;
                float g = sigm(c[r] + lb);
                float o = h2f(out16[i * 136 + d]);
                float xi = h2f(xT[d * 104 + r0 + i]);
                res[r] += g * o + (1.f - g) * xi;
            }
        }
    }
#pragma unroll
    for (int r = 0; r < 4; r++) {
        int i = lg * 4 + r;
        if (i < cG) out[((size_t)b * cN + r0 + i) * cD + d] = res[r];
    }
}

// ---------------- kernel 3: fused tail (one block per b, 512 threads) ----------------
__global__ __launch_bounds__(512) void k_tail(
    const float* __restrict__ S, const float* __restrict__ T,
    const int* __restrict__ iidx, const float* __restrict__ g2w,
    const float* __restrict__ G1b, const float* __restrict__ W2,
    const ushort_t* __restrict__ W0T, const ushort_t* __restrict__ W1gT,
    const ushort_t* __restrict__ W1bT, const ushort_t* __restrict__ G1T,
    const float* __restrict__ posW1, float* __restrict__ outp)
{
    const int b = blockIdx.x;
    const int tid = threadIdx.x, wid = tid >> 6, l = tid & 63;
    const int la = l & 15, lg = l >> 4;
    const float scale = 0.088388347648318447f;   // 1/sqrt(128)

    __shared__ __align__(16) ushort_t s16[100 * 136];   // s, then snew, then nh
    __shared__ __align__(16) ushort_t t16[100 * 136];   // t, then hid
    __shared__ float a_sh[cN];
    __shared__ float part[4][cD];
    __shared__ float hs_s[cD];
    __shared__ float hsg_s[cD];
    __shared__ float beta_s[cN];
    __shared__ int   idx_s[cN];

    for (int idx = tid; idx < 100 * 64; idx += 512) {
        int n = idx >> 6, d2 = idx & 63;
        const float* sp = S + ((size_t)b * cN + n) * cD + 2 * d2;
        const float* tp = T + ((size_t)b * cN + n) * cD + 2 * d2;
        *(unsigned*)&s16[n * 136 + 2 * d2] = pkh2(sp[0], sp[1]);
        *(unsigned*)&t16[n * 136 + 2 * d2] = pkh2(tp[0], tp[1]);
    }
    if (tid < cN) idx_s[tid] = iidx[b * cN + tid];
    __syncthreads();

    if (wid < 7) {
        int arow = wid * 16 + la; if (arow > 99) arow = 99;
        float asum[4] = {0.f, 0.f, 0.f, 0.f};
        for (int nt = 0; nt < 8; nt++) {
            f32x4 cs = {0.f, 0.f, 0.f, 0.f}, ct = {0.f, 0.f, 0.f, 0.f};
            const ushort_t* b0 = W0T + (size_t)(nt * 16 + la) * cD;
            const ushort_t* b1 = W1gT + (size_t)(nt * 16 + la) * cD;
#pragma unroll
            for (int kc = 0; kc < 4; kc++) {
                f16x8 as = ldf(&s16[arow * 136 + kc * 32 + lg * 8]);
                f16x8 at = ldf(&t16[arow * 136 + kc * 32 + lg * 8]);
                uint4 u0 = *(const uint4*)(b0 + kc * 32 + lg * 8);
                uint4 u1 = *(const uint4*)(b1 + kc * 32 + lg * 8);
                f16x8 w0v, w1v; __builtin_memcpy(&w0v, &u0, 16); __builtin_memcpy(&w1v, &u1, 16);
                cs = mm(as, w0v, cs);
                ct = mm(at, w1v, ct);
            }
#pragma unroll
            for (int r = 0; r < 4; r++) asum[r] += cs[r] * ct[r];
        }
#pragma unroll
        for (int o = 8; o; o >>= 1) {
#pragma unroll
            for (int r = 0; r < 4; r++) asum[r] += __shfl_xor(asum[r], o, 64);
        }
        if (la == 0) {
#pragma unroll
            for (int r = 0; r < 4; r++) {
                int n = wid * 16 + lg * 4 + r;
                if (n < cN) a_sh[n] = asum[r] * scale;
            }
        }
    }
    __syncthreads();

    for (int idx = tid; idx < 100 * 64; idx += 512) {
        int n = idx >> 6, d2 = idx & 63;
        unsigned su = *(unsigned*)&s16[n * 136 + 2 * d2];
        unsigned tu = *(unsigned*)&t16[n * 136 + 2 * d2];
        float a = a_sh[n];
        float s0 = h2f((ushort_t)(su & 0xffffu)), s1 = h2f((ushort_t)(su >> 16));
        float t0 = h2f((ushort_t)(tu & 0xffffu)), t1 = h2f((ushort_t)(tu >> 16));
        *(unsigned*)&s16[n * 136 + 2 * d2] = pkh2(s0 + a * (t0 - s0), s1 + a * (t1 - s1));
    }
    __syncthreads();

    for (int idx = tid; idx < 100 * 64; idx += 512) {
        int n = idx >> 6, d2 = idx & 63;
        int rsrc = idx_s[n];
        *(unsigned*)&t16[n * 136 + 2 * d2] = *(unsigned*)&s16[rsrc * 136 + 2 * d2];
    }
    __syncthreads();

    {
        int g = tid >> 7, d = tid & 127;
        float sum = 0.f;
        for (int n = g * 25; n < g * 25 + 25; n++) sum += h2f(t16[n * 136 + d]);
        part[g][d] = sum;
    }
    __syncthreads();
    if (tid < cD) hs_s[tid] = (part[0][tid] + part[1][tid] + part[2][tid] + part[3][tid]) * (1.f / (100.f + 1e-7f));
    __syncthreads();
    if (tid < cD) {
        float acc = 0.f;
        for (int c = 0; c < cD; c++) acc += hs_s[c] * g2w[c * cD + tid];
        hsg_s[tid] = acc;
    }
    __syncthreads();

    if (wid < 7) {
        int arow = wid * 16 + la; if (arow > 99) arow = 99;
        for (int nt = 0; nt < 8; nt++) {
            f32x4 c = {0.f, 0.f, 0.f, 0.f};
            const ushort_t* bb = W1bT + (size_t)(nt * 16 + la) * cD;
#pragma unroll
            for (int kc = 0; kc < 4; kc++) {
                f16x8 a = ldf(&t16[arow * 136 + kc * 32 + lg * 8]);
                uint4 u = *(const uint4*)(bb + kc * 32 + lg * 8);
                f16x8 wv; __builtin_memcpy(&wv, &u, 16);
                c = mm(a, wv, c);
            }
            int d = nt * 16 + la;
#pragma unroll
            for (int r = 0; r < 4; r++) {
                int n = wid * 16 + lg * 4 + r;
                if (n < cN) s16[n * 136 + d] = f2hbits(tanhf(c[r] + posW1[n * cD + d]));
            }
        }
    }
    __syncthreads();

    if (wid < 7) {
        int arow = wid * 16 + la; if (arow > 99) arow = 99;
        float bsum[4] = {0.f, 0.f, 0.f, 0.f};
        for (int nt = 0; nt < 8; nt++) {
            f32x4 c = {0.f, 0.f, 0.f, 0.f};
            const ushort_t* bb = G1T + (size_t)(nt * 16 + la) * cD;
#pragma unroll
            for (int kc = 0; kc < 4; kc++) {
                f16x8 a = ldf(&s16[arow * 136 + kc * 32 + lg * 8]);
                uint4 u = *(const uint4*)(bb + kc * 32 + lg * 8);
                f16x8 wv; __builtin_memcpy(&wv, &u, 16);
                c = mm(a, wv, c);
            }
            int d = nt * 16 + la;
            float add = G1b[d] + hsg_s[d];
            float w2v = W2[d];
#pragma unroll
            for (int r = 0; r < 4; r++) bsum[r] += sigm(c[r] + add) * w2v;
        }
#pragma unroll
        for (int o = 8; o; o >>= 1) {
#pragma unroll
            for (int r = 0; r < 4; r++) bsum[r] += __shfl_xor(bsum[r], o, 64);
        }
        if (la == 0) {
#pragma unroll
            for (int r = 0; r < 4; r++) {
                int n = wid * 16 + lg * 4 + r;
                if (n < cN) beta_s[n] = bsum[r];
            }
        }
    }
    __syncthreads();

    {
        int g = tid >> 7, d = tid & 127;
        float sum = 0.f;
        for (int n = g * 25; n < g * 25 + 25; n++) sum += beta_s[n] * h2f(t16[n * 136 + d]);
        part[g][d] = sum;
    }
    __syncthreads();
    if (tid < cD) outp[b * cD + tid] = part[0][tid] + part[1][tid] + part[2][tid] + part[3][tid];
}

extern "C" void kernel_launch(void* const* d_in, const int* in_sizes, int n_in,
                              void* d_out, int out_size, void* d_ws, size_t ws_size,
                              hipStream_t stream) {
    const float* gnn   = (const float*)d_in[0];
    const float* drop  = (const float*)d_in[1];
    const float* proto = (const float*)d_in[2];
    const float* pos   = (const float*)d_in[3];
    const float* laL_a = (const float*)d_in[4];
    const float* laL_w = (const float*)d_in[5];
    const float* laL_b = (const float*)d_in[6];
    const float* ssL_w = (const float*)d_in[7];
    const float* ssL_b = (const float*)d_in[8];
    const float* laG_a = (const float*)d_in[9];
    const float* laG_w = (const float*)d_in[10];
    const float* laG_b = (const float*)d_in[11];
    const float* ssG_w = (const float*)d_in[12];
    const float* ssG_b = (const float*)d_in[13];
    const float* gem_w = (const float*)d_in[14];
    const float* fn_w  = (const float*)d_in[15];
    const float* fn_b  = (const float*)d_in[16];
    const float* w_1   = (const float*)d_in[17];
    const float* w_2   = (const float*)d_in[18];
    const float* glu1w = (const float*)d_in[19];
    const float* glu1b = (const float*)d_in[20];
    const float* glu2w = (const float*)d_in[21];
    const int*   adj   = (const int*)d_in[22];
    const int*   iidx  = (const int*)d_in[23];
    const void*  m0    = d_in[24];
    float* out = (float*)d_out;

    const size_t BND = (size_t)cB * cN * cD;
    float* w = (float*)d_ws;
    float* bufA = w;               // gi
    float* bufB = bufA + BND;      // pi
    float* locS = bufB + BND;
    float* gloS = locS + BND;
    float* aL   = gloS + BND;
    float* aG   = aL + (size_t)cB * cN;
    float* avgdot = aG + (size_t)cB * cN;
    ushort_t* LWT  = (ushort_t*)(avgdot + cB);
    ushort_t* W1bT = LWT + (size_t)4 * cD * 256;
    ushort_t* G1T  = W1bT + (size_t)cD * cD;
    ushort_t* W0T  = G1T + (size_t)cD * cD;
    ushort_t* W1gT = W0T + (size_t)cD * cD;
    float* posW1   = (float*)(W1gT + (size_t)cD * cD);

    k_cvtw<<<dim3(9, 8), dim3(256), 0, stream>>>(laL_w, laG_w, w_1, glu1w, gem_w, pos,
                                                 LWT, W1bT, G1T, W0T, W1gT, posW1);
    k_prep_a<<<dim3(cB), dim3(256), 0, stream>>>(gnn, m0, fn_w, avgdot);
    k_prep_b<<<dim3(cB, 13), dim3(512), 0, stream>>>(gnn, drop, proto, m0, avgdot,
                                                     fn_w, fn_b, ssL_w, ssL_b, ssG_w, ssG_b,
                                                     bufA, bufB, aL, aG);
    k_gnn<<<dim3(cNCH * cB * 2), dim3(512), 0, stream>>>(
        bufA, bufB, adj, aL, aG, laL_a, laG_a, LWT, laL_b, laG_b, locS, gloS);
    k_tail<<<dim3(cB), dim3(512), 0, stream>>>(locS, gloS, iidx, glu2w, glu1b, w_2,
                                               W0T, W1gT, W1bT, G1T, posW1, out);
}

// Round 19
// 280.112 us; speedup vs baseline: 1.4396x; 1.0294x over previous
//
#include <hip/hip_runtime.h>
#include <math.h>

// DenoiseEncoder forward, MI355X. B=256,N=100,D=128,H=2.
// v15 = v14 (round-18, 288us, absmax 4.0) with N_ITER_RUN 10 -> 8.
// Ladder evidence: 24->14->12->10 iters gave absmax 2.0/2.0/4.0/4.0 (tau err
// invisible under f16 floor). k=8 tau err ~0.4%; threshold 17.2.
constexpr int cB = 256, cN = 100, cD = 128, cH = 2, cG = 10, cNCH = cN / cG;
constexpr int N_ITER_RUN = 8;

typedef __fp16 h2 __attribute__((ext_vector_type(2)));
typedef __fp16 f16x8 __attribute__((ext_vector_type(8)));
typedef float f32x4 __attribute__((ext_vector_type(4)));
typedef unsigned short ushort_t;
typedef unsigned char uchar_t;

// ---------------- helpers ----------------
__device__ __forceinline__ float wsum(float v) {
#pragma unroll
    for (int o = 32; o; o >>= 1) v += __shfl_xor(v, o, 64);
    return v;
}
__device__ __forceinline__ float sigm(float x) { return 1.f / (1.f + __expf(-x)); }
__device__ __forceinline__ float ex2(float x) {
#if __has_builtin(__builtin_amdgcn_exp2f)
    return __builtin_amdgcn_exp2f(x);
#else
    return exp2f(x);
#endif
}
__device__ __forceinline__ float lg2(float x) {
#if __has_builtin(__builtin_amdgcn_logf)
    return __builtin_amdgcn_logf(x);       // v_log_f32; lg2(0) = -inf
#else
    return __log2f(x);
#endif
}
__device__ __forceinline__ unsigned pkh2(float a, float b) {
#if __has_builtin(__builtin_amdgcn_cvt_pkrtz)
    h2 r = __builtin_amdgcn_cvt_pkrtz(a, b);
#else
    h2 r; r.x = (__fp16)a; r.y = (__fp16)b;
#endif
    unsigned u; __builtin_memcpy(&u, &r, 4); return u;
}
__device__ __forceinline__ ushort_t f2hbits(float v) {
    __fp16 h = (__fp16)v;
    ushort_t u; __builtin_memcpy(&u, &h, 2); return u;
}
__device__ __forceinline__ float h2f(ushort_t u) {
    __fp16 h; __builtin_memcpy(&h, &u, 2); return (float)h;
}
__device__ __forceinline__ f16x8 ldf(const ushort_t* p) {   // 16B-aligned load
    uint4 u = *(const uint4*)p;
    f16x8 a; __builtin_memcpy(&a, &u, 16); return a;
}
__device__ __forceinline__ f32x4 mm(f16x8 a, f16x8 b, f32x4 c) {
    return __builtin_amdgcn_mfma_f32_16x16x32_f16(a, b, c, 0, 0, 0);
}

// ---------------- kernel 0: weight converts + posW1 (grid (9,8)) ----------------
__global__ __launch_bounds__(256) void k_cvtw(
    const float* __restrict__ LWL, const float* __restrict__ LWG,
    const float* __restrict__ W1, const float* __restrict__ G1w,
    const float* __restrict__ GW, const float* __restrict__ pos,
    ushort_t* __restrict__ LWT, ushort_t* __restrict__ W1bT, ushort_t* __restrict__ G1T,
    ushort_t* __restrict__ W0T, ushort_t* __restrict__ W1gT, float* __restrict__ posW1)
{
    const int bz = blockIdx.x;
    if (bz < 4) {
        const int gz = bz >> 1, h = bz & 1;
        const int cseg = blockIdx.y * 32;
        const float* src = (gz ? LWG : LWL) + (size_t)h * 2 * cD * cD;
        for (int idx = threadIdx.x; idx < 32 * cD; idx += 256) {
            int c = cseg + (idx >> 7), d = idx & 127;
            LWT[((size_t)bz * cD + d) * 256 + c] = f2hbits(src[c * cD + d]);
        }
    } else if (bz < 8) {
        const float* src = (bz == 4) ? (W1 + cD * cD) : (bz == 5) ? G1w
                         : (bz == 6) ? GW : (GW + cD * cD);
        ushort_t* dst = (bz == 4) ? W1bT : (bz == 5) ? G1T : (bz == 6) ? W0T : W1gT;
        const int cseg = blockIdx.y * 16;
        for (int idx = threadIdx.x; idx < 16 * cD; idx += 256) {
            int c = cseg + (idx >> 7), d = idx & 127;
            dst[(size_t)d * cD + c] = f2hbits(src[c * cD + d]);
        }
    } else {
        int n0 = blockIdx.y * 13;
        int cnt = (n0 + 13 <= cN) ? 13 : (cN - n0);
        for (int idx = threadIdx.x; idx < cnt * cD; idx += 256) {
            int n = n0 + (idx >> 7), d = idx & 127;
            float acc = 0.f;
            for (int c = 0; c < cD; c++) acc += pos[n * cD + c] * W1[c * cD + d];
            posW1[n * cD + d] = acc;
        }
    }
}

// ---------------- kernel 1a: avgdot[b] ----------------
__global__ __launch_bounds__(256) void k_prep_a(
    const float* __restrict__ gnn, const void* __restrict__ m0,
    const float* __restrict__ fnw, float* __restrict__ avgdot)
{
    const int b = blockIdx.x, tid = threadIdx.x;
    const int w = tid >> 6, l = tid & 63;
    const int d0 = l, d1 = l + 64;
    __shared__ int fmt_s;
    __shared__ float mrow[cN];
    __shared__ float part[4][cD];
    __shared__ float red2[2];
    if (tid < 64) {
        unsigned u = ((const unsigned*)m0)[tid];
        int c = ((u & 0xffu) != 0) + ((u & 0xff00u) != 0) + ((u & 0xff0000u) != 0) + ((u >> 24) != 0);
        float cf = wsum((float)c);
        if (tid == 0) fmt_s = (cf > 128.f);
    }
    __syncthreads();
    if (tid < cN) {
        int idx = b * cN + tid;
        float m;
        if (fmt_s) m = ((const unsigned char*)m0)[idx] ? 1.f : 0.f;
        else       m = ((const int*)m0)[idx] ? 1.f : 0.f;
        mrow[tid] = m;
    }
    __syncthreads();
    float s0 = 0.f, s1 = 0.f;
    for (int n = w; n < cN; n += 4) {
        size_t o = ((size_t)b * cN + n) * cD;
        float m = mrow[n];
        s0 += gnn[o + d0] * m;
        s1 += gnn[o + d1] * m;
    }
    part[w][d0] = s0; part[w][d1] = s1;
    __syncthreads();
    const float rcnt = 1.f / (100.f + 1e-7f);
    if (tid < cD) {
        float avg = (part[0][tid] + part[1][tid] + part[2][tid] + part[3][tid]) * rcnt;
        float v = wsum(avg * fnw[tid]);
        if ((tid & 63) == 0) red2[tid >> 6] = v;
    }
    __syncthreads();
    if (tid == 0) avgdot[b] = red2[0] + red2[1];
}

// ---------------- kernel 1b: per-(b,n) wave: gi, pi, aL, aG ----------------
__global__ __launch_bounds__(512) void k_prep_b(
    const float* __restrict__ gnn, const float* __restrict__ drop, const float* __restrict__ proto,
    const void* __restrict__ m0, const float* __restrict__ avgdot,
    const float* __restrict__ fnw, const float* __restrict__ fnb,
    const float* __restrict__ ssLw, const float* __restrict__ ssLb,
    const float* __restrict__ ssGw, const float* __restrict__ ssGb,
    float* __restrict__ gi, float* __restrict__ pi,
    float* __restrict__ aL, float* __restrict__ aG)
{
    const int b = blockIdx.x, tid = threadIdx.x;
    const int wid = tid >> 6, l = tid & 63;
    const int n = blockIdx.y * 8 + wid;
    __shared__ int fmt_s;
    if (tid < 64) {
        unsigned u = ((const unsigned*)m0)[tid];
        int c = ((u & 0xffu) != 0) + ((u & 0xff00u) != 0) + ((u & 0xff0000u) != 0) + ((u >> 24) != 0);
        float cf = wsum((float)c);
        if (tid == 0) fmt_s = (cf > 128.f);
    }
    __syncthreads();
    if (n >= cN) return;
    float m;
    {
        int idx = b * cN + n;
        if (fmt_s) m = ((const unsigned char*)m0)[idx] ? 1.f : 0.f;
        else       m = ((const int*)m0)[idx] ? 1.f : 0.f;
    }
    const float dm = 1.f - m;
    const int d0 = l, d1 = l + 64;
    const size_t o = ((size_t)b * cN + n) * cD;
    float dr0 = drop[o + d0] * dm, dr1 = drop[o + d1] * dm;
    float p0 = proto[o + d0] * m,  p1 = proto[o + d1] * m;
    pi[o + d0] = p0; pi[o + d1] = p1;
    float r1 = wsum(dr0 * fnw[cD + d0] + dr1 * fnw[cD + d1]);
    float r2 = wsum(p0 * ssGw[d0] + p1 * ssGw[d1]);
    float alpha = r1 + avgdot[b] + fnb[0];
    float g0 = gnn[o + d0] * m + alpha * dr0;
    float g1 = gnn[o + d1] * m + alpha * dr1;
    gi[o + d0] = g0; gi[o + d1] = g1;
    float r3 = wsum(g0 * ssLw[d0] + g1 * ssLw[d1]);
    if (l == 0) {
        aL[b * cN + n] = 1.f + sigm(r3 + ssLb[0]);
        aG[b * cN + n] = 1.f + sigm(r2 + ssGb[0]);
    }
}

// ---------------- kernel 2: GNN via MFMA. 512 threads, G=10 rows ----------------
// 1D grid 5120 with XCD-affinity decode (wgid%8 == b%8). LDS 39288 B -> 4 blocks/CU.
__global__ __launch_bounds__(512, 8) void k_gnn(
    const float* __restrict__ xL, const float* __restrict__ xG,
    const int* __restrict__ adj,
    const float* __restrict__ alpL, const float* __restrict__ alpG,
    const float* __restrict__ AL, const float* __restrict__ AG,
    const ushort_t* __restrict__ LWT,
    const float* __restrict__ LBL, const float* __restrict__ LBG,
    float* __restrict__ outLp, float* __restrict__ outGp)
{
    const int wg = blockIdx.x;
    const int xcd = wg & 7;
    const int q = wg >> 3;
    const int b = (q / 20) * 8 + xcd;
    const int c20 = q % 20;
    const int gz = c20 & 1;
    const int r0 = (c20 >> 1) * cG;

    const float* __restrict__ x   = gz ? xG : xL;
    const float* __restrict__ alp = gz ? alpG : alpL;
    const float* __restrict__ A   = gz ? AG : AL;
    const float* __restrict__ LB  = gz ? LBG : LBL;
    float* __restrict__ out       = gz ? outGp : outLp;

    const int tid = threadIdx.x, wid = tid >> 6, l = tid & 63;
    const int la = l & 15, lg = l >> 4;

    __shared__ __align__(16) uchar_t lds[39288];
    ushort_t* x16   = (ushort_t*)(lds);           // [100][136]
    ushort_t* xT    = (ushort_t*)(lds);           // [128][104], after gating-p1
    ushort_t* sc    = (ushort_t*)(lds + 27200);   // [2][16][104]
    ushort_t* A16   = (ushort_t*)(lds + 33856);   // [8][128], scores phase only
    ushort_t* out16 = (ushort_t*)(lds + 33856);   // [16][136], PV phase (A16 dead)
    uchar_t*  adjb  = lds + 38208;                // [10][104]
    float*    alps  = (float*)(lds + 39248);

    // ---- S1: stage x16 (paired dwords), A16, adjb, sc zero, alps
    for (int idx = tid; idx < 100 * 64; idx += 512) {
        int j = idx >> 6, d2 = idx & 63;
        const float* xp = x + ((size_t)b * cN + j) * cD + 2 * d2;
        *(unsigned*)&x16[j * 136 + 2 * d2] = pkh2(xp[0], xp[1]);
    }
    {   // 8 rows x 64 dwords
        int row = tid >> 6, d2 = tid & 63;
        const float* ap = A + row * cD + 2 * d2;
        *(unsigned*)&A16[row * 128 + 2 * d2] = pkh2(ap[0], ap[1]);
    }
    for (int idx = tid; idx < cG * cN; idx += 512) {
        int i = idx / cN, j = idx % cN;
        adjb[i * 104 + j] = (uchar_t)adj[((size_t)b * cN + r0 + i) * cN + j];
    }
    for (int idx = tid; idx < 1664; idx += 512) ((unsigned*)sc)[idx] = 0u;
    if (tid < cG) alps[tid] = alp[b * cN + r0 + tid];
    __syncthreads();

    // ---- scores, both h: C[j][(ik)] = sum_d x16[j][d] * (x16[r0+i][d]*A16[h*4+k][d])
    for (int h = 0; h < 2; h++) {
        f16x8 afr[4];
        const int krow = (h * 4 + (la & 3)) * 128;
#pragma unroll
        for (int kc = 0; kc < 4; kc++) afr[kc] = ldf(&A16[krow + kc * 32 + lg * 8]);
        for (int job = wid; job < 21; job += 8) {
            int mt = job / 3, nt = job % 3;
            int arow = mt * 16 + la; if (arow > 99) arow = 99;
            int brow = nt * 16 + la; if (brow > 39) brow = 39;
            int xrow = r0 + (brow >> 2);
            f32x4 c = {0.f, 0.f, 0.f, 0.f};
#pragma unroll
            for (int kc = 0; kc < 4; kc++) {
                f16x8 a  = ldf(&x16[arow * 136 + kc * 32 + lg * 8]);
                f16x8 xb = ldf(&x16[xrow * 136 + kc * 32 + lg * 8]);
                c = mm(a, xb * afr[kc], c);
            }
            int col = nt * 16 + la, i = col >> 2, k = col & 3;
            if (i < cG) {
#pragma unroll
                for (int r = 0; r < 4; r++) {
                    int j = mt * 16 + lg * 4 + r;
                    if (j < cN && (int)adjb[i * 104 + j] == k + 1) {
                        float v = c[r];
                        v = (v >= 0.f) ? v : 0.2f * v;     // leaky
                        sc[(h * 16 + i) * 104 + j] = f2hbits(v);
                    }
                }
            }
        }
    }
    __syncthreads();

    // ---- entmax: waves 0-3 rows {wid, 8+wid, 16+wid}; waves 4-7 rows {wid, 8+wid}
    {
        const bool w3 = (wid < 4);
        const float log2_rn = -6.6438561897747395f;
        float X0[3], X1[3], INV[3], TLO[3], DM[3], FLO[3], TM[3], S[3];
        int RI[3], RH[3];
#pragma unroll
        for (int q2 = 0; q2 < 3; q2++) {
            if (q2 < 2 || w3) {
                int r = (q2 < 2) ? (wid + 8 * q2) : (16 + wid);
                RI[q2] = r >> 1; RH[q2] = r & 1;
                float am1 = alps[RI[q2]] - 1.f;
                INV[q2] = 1.f / am1;
                X0[q2] = h2f(sc[(RH[q2] * 16 + RI[q2]) * 104 + l]) * am1;
                X1[q2] = (l + 64 < cN) ? h2f(sc[(RH[q2] * 16 + RI[q2]) * 104 + l + 64]) * am1 : -INFINITY;
                TM[q2] = ex2(am1 * log2_rn);
            }
        }
        float MX[3];
#pragma unroll
        for (int q2 = 0; q2 < 3; q2++) if (q2 < 2 || w3) MX[q2] = fmaxf(X0[q2], X1[q2]);
#pragma unroll
        for (int o = 32; o; o >>= 1) {
#pragma unroll
            for (int q2 = 0; q2 < 3; q2++) if (q2 < 2 || w3) MX[q2] = fmaxf(MX[q2], __shfl_xor(MX[q2], o, 64));
        }
#pragma unroll
        for (int q2 = 0; q2 < 3; q2++) if (q2 < 2 || w3) { TLO[q2] = MX[q2] - 1.f; DM[q2] = 1.f - TM[q2]; }
#pragma unroll
        for (int q2 = 0; q2 < 3; q2++) if (q2 < 2 || w3) {
            float z0 = fmaxf(X0[q2] - TLO[q2], 0.f);
            float z1 = fmaxf(X1[q2] - TLO[q2], 0.f);
            S[q2] = ex2(INV[q2] * lg2(z0)) + ex2(INV[q2] * lg2(z1));
        }
#pragma unroll
        for (int o = 32; o; o >>= 1) {
#pragma unroll
            for (int q2 = 0; q2 < 3; q2++) if (q2 < 2 || w3) S[q2] += __shfl_xor(S[q2], o, 64);
        }
#pragma unroll
        for (int q2 = 0; q2 < 3; q2++) if (q2 < 2 || w3) FLO[q2] = S[q2] - 1.f;

#pragma unroll 1
        for (int it = 0; it < N_ITER_RUN - 1; ++it) {
#pragma unroll
            for (int q2 = 0; q2 < 3; q2++) if (q2 < 2 || w3) { DM[q2] *= 0.5f; TM[q2] = TLO[q2] + DM[q2]; }
#pragma unroll
            for (int q2 = 0; q2 < 3; q2++) if (q2 < 2 || w3) {
                float z0 = fmaxf(X0[q2] - TM[q2], 0.f);
                float z1 = fmaxf(X1[q2] - TM[q2], 0.f);
                S[q2] = ex2(INV[q2] * lg2(z0)) + ex2(INV[q2] * lg2(z1));
            }
#pragma unroll
            for (int o = 32; o; o >>= 1) {
#pragma unroll
                for (int q2 = 0; q2 < 3; q2++) if (q2 < 2 || w3) S[q2] += __shfl_xor(S[q2], o, 64);
            }
#pragma unroll
            for (int q2 = 0; q2 < 3; q2++) if (q2 < 2 || w3)
                if ((S[q2] - 1.f) * FLO[q2] >= 0.f) TLO[q2] = TM[q2];
        }
        float P0[3], P1[3];
#pragma unroll
        for (int q2 = 0; q2 < 3; q2++) if (q2 < 2 || w3) {
            DM[q2] *= 0.5f; TM[q2] = TLO[q2] + DM[q2];
            float z0 = fmaxf(X0[q2] - TM[q2], 0.f);
            float z1 = fmaxf(X1[q2] - TM[q2], 0.f);
            P0[q2] = ex2(INV[q2] * lg2(z0));
            P1[q2] = ex2(INV[q2] * lg2(z1));
            S[q2] = P0[q2] + P1[q2];
        }
#pragma unroll
        for (int o = 32; o; o >>= 1) {
#pragma unroll
            for (int q2 = 0; q2 < 3; q2++) if (q2 < 2 || w3) S[q2] += __shfl_xor(S[q2], o, 64);
        }
        __syncthreads();
#pragma unroll
        for (int q2 = 0; q2 < 3; q2++) {
            if (q2 < 2 || w3) {
                float invs = 1.f / S[q2];
                sc[(RH[q2] * 16 + RI[q2]) * 104 + l] = f2hbits(P0[q2] * invs);
                if (l + 64 < cN) sc[(RH[q2] * 16 + RI[q2]) * 104 + l + 64] = f2hbits(P1[q2] * invs);
            }
        }
    }

    // ---- gating part 1 (x16 still intact): cg[h] = xi @ LW_top
    f32x4 cg0 = {0.f, 0.f, 0.f, 0.f}, cg1 = {0.f, 0.f, 0.f, 0.f};
    {
        const int d = wid * 16 + la;
        int arow = r0 + la; if (arow > 99) arow = 99;
#pragma unroll
        for (int h = 0; h < 2; h++) {
            const ushort_t* lwbase = LWT + ((size_t)(gz * 2 + h) * cD + d) * 256;
            f32x4 c = {0.f, 0.f, 0.f, 0.f};
#pragma unroll
            for (int kc = 0; kc < 4; kc++) {
                f16x8 a = ldf(&x16[arow * 136 + kc * 32 + lg * 8]);
                uint4 u = *(const uint4*)(lwbase + kc * 32 + lg * 8);
                f16x8 bb; __builtin_memcpy(&bb, &u, 16);
                c = mm(a, bb, c);
            }
            if (h) cg1 = c; else cg0 = c;
        }
    }
    __syncthreads();

    // ---- xT build from GLOBAL x (L2-hot), b128 writes, into dead x16 region
    for (int job = tid; job < 13 * 128; job += 512) {
        int d2 = job & 127, jc = job >> 7;
        f16x8 v;
#pragma unroll
        for (int t = 0; t < 8; t++) {
            int j = jc * 8 + t;
            float f = (j < cN) ? x[((size_t)b * cN + j) * cD + d2] : 0.f;
            v[t] = (__fp16)f;
        }
        uint4 u; __builtin_memcpy(&u, &v, 16);
        *(uint4*)(&xT[d2 * 104 + jc * 8]) = u;
    }
    __syncthreads();

    // ---- PV + gating part 2, per h ----
    float res[4] = {0.f, 0.f, 0.f, 0.f};
    const int dt = wid;
    const int d = dt * 16 + la;
    for (int h = 0; h < 2; h++) {
        if (h) __syncthreads();
        {
            f32x4 c = {0.f, 0.f, 0.f, 0.f};
#pragma unroll
            for (int kc = 0; kc < 3; kc++) {
                f16x8 a  = ldf(&sc[(h * 16 + la) * 104 + kc * 32 + lg * 8]);
                f16x8 bb = ldf(&xT[(dt * 16 + la) * 104 + kc * 32 + lg * 8]);
                c = mm(a, bb, c);
            }
#pragma unroll
            for (int r = 0; r < 4; r++) {
                int i = lg * 4 + r;
                float acc = c[r];
#pragma unroll
                for (int j = 96; j < 100; j++)
                    acc += h2f(sc[(h * 16 + i) * 104 + j]) * h2f(xT[d * 104 + j]);
                if (i < cG) out16[i * 136 + d] = f2hbits(acc);
            }
        }
        __syncthreads();
        {
            f32x4 c = h ? cg1 : cg0;
            const ushort_t* lwbase = LWT + ((size_t)(gz * 2 + h) * cD + d) * 256 + 128;
#pragma unroll
            for (int kc = 0; kc < 4; kc++) {
                f16x8 a = ldf(&out16[la * 136 + kc * 32 + lg * 8]);
                uint4 u = *(const uint4*)(lwbase + kc * 32 + lg * 8);
                f16x8 bb; __builtin_memcpy(&bb, &u, 16);
                c = mm(a, bb, c);
            }
            float lb = LB[h * cD + d];
#pragma unroll
            for (int r = 0; r < 4; r++) {
                int i = lg * 4 + r;
                float g = sigm(c[r] + lb);
                float o = h2f(out16[i * 136 + d]);
                float xi = h2f(xT[d * 104 + r0 + i]);
                res[r] += g * o + (1.f - g) * xi;
            }
        }
    }
#pragma unroll
    for (int r = 0; r < 4; r++) {
        int i = lg * 4 + r;
        if (i < cG) out[((size_t)b * cN + r0 + i) * cD + d] = res[r];
    }
}

// ---------------- kernel 3: fused tail (one block per b, 512 threads) ----------------
__global__ __launch_bounds__(512) void k_tail(
    const float* __restrict__ S, const float* __restrict__ T,
    const int* __restrict__ iidx, const float* __restrict__ g2w,
    const float* __restrict__ G1b, const float* __restrict__ W2,
    const ushort_t* __restrict__ W0T, const ushort_t* __restrict__ W1gT,
    const ushort_t* __restrict__ W1bT, const ushort_t* __restrict__ G1T,
    const float* __restrict__ posW1, float* __restrict__ outp)
{
    const int b = blockIdx.x;
    const int tid = threadIdx.x, wid = tid >> 6, l = tid & 63;
    const int la = l & 15, lg = l >> 4;
    const float scale = 0.088388347648318447f;   // 1/sqrt(128)

    __shared__ __align__(16) ushort_t s16[100 * 136];   // s, then snew, then nh
    __shared__ __align__(16) ushort_t t16[100 * 136];   // t, then hid
    __shared__ float a_sh[cN];
    __shared__ float part[4][cD];
    __shared__ float hs_s[cD];
    __shared__ float hsg_s[cD];
    __shared__ float beta_s[cN];
    __shared__ int   idx_s[cN];

    for (int idx = tid; idx < 100 * 64; idx += 512) {
        int n = idx >> 6, d2 = idx & 63;
        const float* sp = S + ((size_t)b * cN + n) * cD + 2 * d2;
        const float* tp = T + ((size_t)b * cN + n) * cD + 2 * d2;
        *(unsigned*)&s16[n * 136 + 2 * d2] = pkh2(sp[0], sp[1]);
        *(unsigned*)&t16[n * 136 + 2 * d2] = pkh2(tp[0], tp[1]);
    }
    if (tid < cN) idx_s[tid] = iidx[b * cN + tid];
    __syncthreads();

    if (wid < 7) {
        int arow = wid * 16 + la; if (arow > 99) arow = 99;
        float asum[4] = {0.f, 0.f, 0.f, 0.f};
        for (int nt = 0; nt < 8; nt++) {
            f32x4 cs = {0.f, 0.f, 0.f, 0.f}, ct = {0.f, 0.f, 0.f, 0.f};
            const ushort_t* b0 = W0T + (size_t)(nt * 16 + la) * cD;
            const ushort_t* b1 = W1gT + (size_t)(nt * 16 + la) * cD;
#pragma unroll
            for (int kc = 0; kc < 4; kc++) {
                f16x8 as = ldf(&s16[arow * 136 + kc * 32 + lg * 8]);
                f16x8 at = ldf(&t16[arow * 136 + kc * 32 + lg * 8]);
                uint4 u0 = *(const uint4*)(b0 + kc * 32 + lg * 8);
                uint4 u1 = *(const uint4*)(b1 + kc * 32 + lg * 8);
                f16x8 w0v, w1v; __builtin_memcpy(&w0v, &u0, 16); __builtin_memcpy(&w1v, &u1, 16);
                cs = mm(as, w0v, cs);
                ct = mm(at, w1v, ct);
            }
#pragma unroll
            for (int r = 0; r < 4; r++) asum[r] += cs[r] * ct[r];
        }
#pragma unroll
        for (int o = 8; o; o >>= 1) {
#pragma unroll
            for (int r = 0; r < 4; r++) asum[r] += __shfl_xor(asum[r], o, 64);
        }
        if (la == 0) {
#pragma unroll
            for (int r = 0; r < 4; r++) {
                int n = wid * 16 + lg * 4 + r;
                if (n < cN) a_sh[n] = asum[r] * scale;
            }
        }
    }
    __syncthreads();

    for (int idx = tid; idx < 100 * 64; idx += 512) {
        int n = idx >> 6, d2 = idx & 63;
        unsigned su = *(unsigned*)&s16[n * 136 + 2 * d2];
        unsigned tu = *(unsigned*)&t16[n * 136 + 2 * d2];
        float a = a_sh[n];
        float s0 = h2f((ushort_t)(su & 0xffffu)), s1 = h2f((ushort_t)(su >> 16));
        float t0 = h2f((ushort_t)(tu & 0xffffu)), t1 = h2f((ushort_t)(tu >> 16));
        *(unsigned*)&s16[n * 136 + 2 * d2] = pkh2(s0 + a * (t0 - s0), s1 + a * (t1 - s1));
    }
    __syncthreads();

    for (int idx = tid; idx < 100 * 64; idx += 512) {
        int n = idx >> 6, d2 = idx & 63;
        int rsrc = idx_s[n];
        *(unsigned*)&t16[n * 136 + 2 * d2] = *(unsigned*)&s16[rsrc * 136 + 2 * d2];
    }
    __syncthreads();

    {
        int g = tid >> 7, d = tid & 127;
        float sum = 0.f;
        for (int n = g * 25; n < g * 25 + 25; n++) sum += h2f(t16[n * 136 + d]);
        part[g][d] = sum;
    }
    __syncthreads();
    if (tid < cD) hs_s[tid] = (part[0][tid] + part[1][tid] + part[2][tid] + part[3][tid]) * (1.f / (100.f + 1e-7f));
    __syncthreads();
    if (tid < cD) {
        float acc = 0.f;
        for (int c = 0; c < cD; c++) acc += hs_s[c] * g2w[c * cD + tid];
        hsg_s[tid] = acc;
    }
    __syncthreads();

    if (wid < 7) {
        int arow = wid * 16 + la; if (arow > 99) arow = 99;
        for (int nt = 0; nt < 8; nt++) {
            f32x4 c = {0.f, 0.f, 0.f, 0.f};
            const ushort_t* bb = W1bT + (size_t)(nt * 16 + la) * cD;
#pragma unroll
            for (int kc = 0; kc < 4; kc++) {
                f16x8 a = ldf(&t16[arow * 136 + kc * 32 + lg * 8]);
                uint4 u = *(const uint4*)(bb + kc * 32 + lg * 8);
                f16x8 wv; __builtin_memcpy(&wv, &u, 16);
                c = mm(a, wv, c);
            }
            int d = nt * 16 + la;
#pragma unroll
            for (int r = 0; r < 4; r++) {
                int n = wid * 16 + lg * 4 + r;
                if (n < cN) s16[n * 136 + d] = f2hbits(tanhf(c[r] + posW1[n * cD + d]));
            }
        }
    }
    __syncthreads();

    if (wid < 7) {
        int arow = wid * 16 + la; if (arow > 99) arow = 99;
        float bsum[4] = {0.f, 0.f, 0.f, 0.f};
        for (int nt = 0; nt < 8; nt++) {
            f32x4 c = {0.f, 0.f, 0.f, 0.f};
            const ushort_t* bb = G1T + (size_t)(nt * 16 + la) * cD;
#pragma unroll
            for (int kc = 0; kc < 4; kc++) {
                f16x8 a = ldf(&s16[arow * 136 + kc * 32 + lg * 8]);
                uint4 u = *(const uint4*)(bb + kc * 32 + lg * 8);
                f16x8 wv; __builtin_memcpy(&wv, &u, 16);
                c = mm(a, wv, c);
            }
            int d = nt * 16 + la;
            float add = G1b[d] + hsg_s[d];
            float w2v = W2[d];
#pragma unroll
            for (int r = 0; r < 4; r++) bsum[r] += sigm(c[r] + add) * w2v;
        }
#pragma unroll
        for (int o = 8; o; o >>= 1) {
#pragma unroll
            for (int r = 0; r < 4; r++) bsum[r] += __shfl_xor(bsum[r], o, 64);
        }
        if (la == 0) {
#pragma unroll
            for (int r = 0; r < 4; r++) {
                int n = wid * 16 + lg * 4 + r;
                if (n < cN) beta_s[n] = bsum[r];
            }
        }
    }
    __syncthreads();

    {
        int g = tid >> 7, d = tid & 127;
        float sum = 0.f;
        for (int n = g * 25; n < g * 25 + 25; n++) sum += beta_s[n] * h2f(t16[n * 136 + d]);
        part[g][d] = sum;
    }
    __syncthreads();
    if (tid < cD) outp[b * cD + tid] = part[0][tid] + part[1][tid] + part[2][tid] + part[3][tid];
}

extern "C" void kernel_launch(void* const* d_in, const int* in_sizes, int n_in,
                              void* d_out, int out_size, void* d_ws, size_t ws_size,
                              hipStream_t stream) {
    const float* gnn   = (const float*)d_in[0];
    const float* drop  = (const float*)d_in[1];
    const float* proto = (const float*)d_in[2];
    const float* pos   = (const float*)d_in[3];
    const float* laL_a = (const float*)d_in[4];
    const float* laL_w = (const float*)d_in[5];
    const float* laL_b = (const float*)d_in[6];
    const float* ssL_w = (const float*)d_in[7];
    const float* ssL_b = (const float*)d_in[8];
    const float* laG_a = (const float*)d_in[9];
    const float* laG_w = (const float*)d_in[10];
    const float* laG_b = (const float*)d_in[11];
    const float* ssG_w = (const float*)d_in[12];
    const float* ssG_b = (const float*)d_in[13];
    const float* gem_w = (const float*)d_in[14];
    const float* fn_w  = (const float*)d_in[15];
    const float* fn_b  = (const float*)d_in[16];
    const float* w_1   = (const float*)d_in[17];
    const float* w_2   = (const float*)d_in[18];
    const float* glu1w = (const float*)d_in[19];
    const float* glu1b = (const float*)d_in[20];
    const float* glu2w = (const float*)d_in[21];
    const int*   adj   = (const int*)d_in[22];
    const int*   iidx  = (const int*)d_in[23];
    const void*  m0    = d_in[24];
    float* out = (float*)d_out;

    const size_t BND = (size_t)cB * cN * cD;
    float* w = (float*)d_ws;
    float* bufA = w;               // gi
    float* bufB = bufA + BND;      // pi
    float* locS = bufB + BND;
    float* gloS = locS + BND;
    float* aL   = gloS + BND;
    float* aG   = aL + (size_t)cB * cN;
    float* avgdot = aG + (size_t)cB * cN;
    ushort_t* LWT  = (ushort_t*)(avgdot + cB);
    ushort_t* W1bT = LWT + (size_t)4 * cD * 256;
    ushort_t* G1T  = W1bT + (size_t)cD * cD;
    ushort_t* W0T  = G1T + (size_t)cD * cD;
    ushort_t* W1gT = W0T + (size_t)cD * cD;
    float* posW1   = (float*)(W1gT + (size_t)cD * cD);

    k_cvtw<<<dim3(9, 8), dim3(256), 0, stream>>>(laL_w, laG_w, w_1, glu1w, gem_w, pos,
                                                 LWT, W1bT, G1T, W0T, W1gT, posW1);
    k_prep_a<<<dim3(cB), dim3(256), 0, stream>>>(gnn, m0, fn_w, avgdot);
    k_prep_b<<<dim3(cB, 13), dim3(512), 0, stream>>>(gnn, drop, proto, m0, avgdot,
                                                     fn_w, fn_b, ssL_w, ssL_b, ssG_w, ssG_b,
                                                     bufA, bufB, aL, aG);
    k_gnn<<<dim3(cNCH * cB * 2), dim3(512), 0, stream>>>(
        bufA, bufB, adj, aL, aG, laL_a, laG_a, LWT, laL_b, laG_b, locS, gloS);
    k_tail<<<dim3(cB), dim3(512), 0, stream>>>(locS, gloS, iidx, glu2w, glu1b, w_2,
                                               W0T, W1gT, W1bT, G1T, posW1, out);
}

// Round 20
// 271.036 us; speedup vs baseline: 1.4878x; 1.0335x over previous
//
#include <hip/hip_runtime.h>
#include <math.h>

// DenoiseEncoder forward, MI355X. B=256,N=100,D=128,H=2.
// v16 = v15 (round-19, 280us, absmax 4.0) with N_ITER_RUN 8 -> 6.
// Ladder: 24/14/12/10/8 iters -> absmax 2/2/4/4/4 (tau err below f16 floor).
// k=6 tau err ~1.6%; expected absmax 6-12 vs threshold 17.2.
constexpr int cB = 256, cN = 100, cD = 128, cH = 2, cG = 10, cNCH = cN / cG;
constexpr int N_ITER_RUN = 6;

typedef __fp16 h2 __attribute__((ext_vector_type(2)));
typedef __fp16 f16x8 __attribute__((ext_vector_type(8)));
typedef float f32x4 __attribute__((ext_vector_type(4)));
typedef unsigned short ushort_t;
typedef unsigned char uchar_t;

// ---------------- helpers ----------------
__device__ __forceinline__ float wsum(float v) {
#pragma unroll
    for (int o = 32; o; o >>= 1) v += __shfl_xor(v, o, 64);
    return v;
}
__device__ __forceinline__ float sigm(float x) { return 1.f / (1.f + __expf(-x)); }
__device__ __forceinline__ float ex2(float x) {
#if __has_builtin(__builtin_amdgcn_exp2f)
    return __builtin_amdgcn_exp2f(x);
#else
    return exp2f(x);
#endif
}
__device__ __forceinline__ float lg2(float x) {
#if __has_builtin(__builtin_amdgcn_logf)
    return __builtin_amdgcn_logf(x);       // v_log_f32; lg2(0) = -inf
#else
    return __log2f(x);
#endif
}
__device__ __forceinline__ unsigned pkh2(float a, float b) {
#if __has_builtin(__builtin_amdgcn_cvt_pkrtz)
    h2 r = __builtin_amdgcn_cvt_pkrtz(a, b);
#else
    h2 r; r.x = (__fp16)a; r.y = (__fp16)b;
#endif
    unsigned u; __builtin_memcpy(&u, &r, 4); return u;
}
__device__ __forceinline__ ushort_t f2hbits(float v) {
    __fp16 h = (__fp16)v;
    ushort_t u; __builtin_memcpy(&u, &h, 2); return u;
}
__device__ __forceinline__ float h2f(ushort_t u) {
    __fp16 h; __builtin_memcpy(&h, &u, 2); return (float)h;
}
__device__ __forceinline__ f16x8 ldf(const ushort_t* p) {   // 16B-aligned load
    uint4 u = *(const uint4*)p;
    f16x8 a; __builtin_memcpy(&a, &u, 16); return a;
}
__device__ __forceinline__ f32x4 mm(f16x8 a, f16x8 b, f32x4 c) {
    return __builtin_amdgcn_mfma_f32_16x16x32_f16(a, b, c, 0, 0, 0);
}

// ---------------- kernel 0: weight converts + posW1 (grid (9,8)) ----------------
__global__ __launch_bounds__(256) void k_cvtw(
    const float* __restrict__ LWL, const float* __restrict__ LWG,
    const float* __restrict__ W1, const float* __restrict__ G1w,
    const float* __restrict__ GW, const float* __restrict__ pos,
    ushort_t* __restrict__ LWT, ushort_t* __restrict__ W1bT, ushort_t* __restrict__ G1T,
    ushort_t* __restrict__ W0T, ushort_t* __restrict__ W1gT, float* __restrict__ posW1)
{
    const int bz = blockIdx.x;
    if (bz < 4) {
        const int gz = bz >> 1, h = bz & 1;
        const int cseg = blockIdx.y * 32;
        const float* src = (gz ? LWG : LWL) + (size_t)h * 2 * cD * cD;
        for (int idx = threadIdx.x; idx < 32 * cD; idx += 256) {
            int c = cseg + (idx >> 7), d = idx & 127;
            LWT[((size_t)bz * cD + d) * 256 + c] = f2hbits(src[c * cD + d]);
        }
    } else if (bz < 8) {
        const float* src = (bz == 4) ? (W1 + cD * cD) : (bz == 5) ? G1w
                         : (bz == 6) ? GW : (GW + cD * cD);
        ushort_t* dst = (bz == 4) ? W1bT : (bz == 5) ? G1T : (bz == 6) ? W0T : W1gT;
        const int cseg = blockIdx.y * 16;
        for (int idx = threadIdx.x; idx < 16 * cD; idx += 256) {
            int c = cseg + (idx >> 7), d = idx & 127;
            dst[(size_t)d * cD + c] = f2hbits(src[c * cD + d]);
        }
    } else {
        int n0 = blockIdx.y * 13;
        int cnt = (n0 + 13 <= cN) ? 13 : (cN - n0);
        for (int idx = threadIdx.x; idx < cnt * cD; idx += 256) {
            int n = n0 + (idx >> 7), d = idx & 127;
            float acc = 0.f;
            for (int c = 0; c < cD; c++) acc += pos[n * cD + c] * W1[c * cD + d];
            posW1[n * cD + d] = acc;
        }
    }
}

// ---------------- kernel 1a: avgdot[b] ----------------
__global__ __launch_bounds__(256) void k_prep_a(
    const float* __restrict__ gnn, const void* __restrict__ m0,
    const float* __restrict__ fnw, float* __restrict__ avgdot)
{
    const int b = blockIdx.x, tid = threadIdx.x;
    const int w = tid >> 6, l = tid & 63;
    const int d0 = l, d1 = l + 64;
    __shared__ int fmt_s;
    __shared__ float mrow[cN];
    __shared__ float part[4][cD];
    __shared__ float red2[2];
    if (tid < 64) {
        unsigned u = ((const unsigned*)m0)[tid];
        int c = ((u & 0xffu) != 0) + ((u & 0xff00u) != 0) + ((u & 0xff0000u) != 0) + ((u >> 24) != 0);
        float cf = wsum((float)c);
        if (tid == 0) fmt_s = (cf > 128.f);
    }
    __syncthreads();
    if (tid < cN) {
        int idx = b * cN + tid;
        float m;
        if (fmt_s) m = ((const unsigned char*)m0)[idx] ? 1.f : 0.f;
        else       m = ((const int*)m0)[idx] ? 1.f : 0.f;
        mrow[tid] = m;
    }
    __syncthreads();
    float s0 = 0.f, s1 = 0.f;
    for (int n = w; n < cN; n += 4) {
        size_t o = ((size_t)b * cN + n) * cD;
        float m = mrow[n];
        s0 += gnn[o + d0] * m;
        s1 += gnn[o + d1] * m;
    }
    part[w][d0] = s0; part[w][d1] = s1;
    __syncthreads();
    const float rcnt = 1.f / (100.f + 1e-7f);
    if (tid < cD) {
        float avg = (part[0][tid] + part[1][tid] + part[2][tid] + part[3][tid]) * rcnt;
        float v = wsum(avg * fnw[tid]);
        if ((tid & 63) == 0) red2[tid >> 6] = v;
    }
    __syncthreads();
    if (tid == 0) avgdot[b] = red2[0] + red2[1];
}

// ---------------- kernel 1b: per-(b,n) wave: gi, pi, aL, aG ----------------
__global__ __launch_bounds__(512) void k_prep_b(
    const float* __restrict__ gnn, const float* __restrict__ drop, const float* __restrict__ proto,
    const void* __restrict__ m0, const float* __restrict__ avgdot,
    const float* __restrict__ fnw, const float* __restrict__ fnb,
    const float* __restrict__ ssLw, const float* __restrict__ ssLb,
    const float* __restrict__ ssGw, const float* __restrict__ ssGb,
    float* __restrict__ gi, float* __restrict__ pi,
    float* __restrict__ aL, float* __restrict__ aG)
{
    const int b = blockIdx.x, tid = threadIdx.x;
    const int wid = tid >> 6, l = tid & 63;
    const int n = blockIdx.y * 8 + wid;
    __shared__ int fmt_s;
    if (tid < 64) {
        unsigned u = ((const unsigned*)m0)[tid];
        int c = ((u & 0xffu) != 0) + ((u & 0xff00u) != 0) + ((u & 0xff0000u) != 0) + ((u >> 24) != 0);
        float cf = wsum((float)c);
        if (tid == 0) fmt_s = (cf > 128.f);
    }
    __syncthreads();
    if (n >= cN) return;
    float m;
    {
        int idx = b * cN + n;
        if (fmt_s) m = ((const unsigned char*)m0)[idx] ? 1.f : 0.f;
        else       m = ((const int*)m0)[idx] ? 1.f : 0.f;
    }
    const float dm = 1.f - m;
    const int d0 = l, d1 = l + 64;
    const size_t o = ((size_t)b * cN + n) * cD;
    float dr0 = drop[o + d0] * dm, dr1 = drop[o + d1] * dm;
    float p0 = proto[o + d0] * m,  p1 = proto[o + d1] * m;
    pi[o + d0] = p0; pi[o + d1] = p1;
    float r1 = wsum(dr0 * fnw[cD + d0] + dr1 * fnw[cD + d1]);
    float r2 = wsum(p0 * ssGw[d0] + p1 * ssGw[d1]);
    float alpha = r1 + avgdot[b] + fnb[0];
    float g0 = gnn[o + d0] * m + alpha * dr0;
    float g1 = gnn[o + d1] * m + alpha * dr1;
    gi[o + d0] = g0; gi[o + d1] = g1;
    float r3 = wsum(g0 * ssLw[d0] + g1 * ssLw[d1]);
    if (l == 0) {
        aL[b * cN + n] = 1.f + sigm(r3 + ssLb[0]);
        aG[b * cN + n] = 1.f + sigm(r2 + ssGb[0]);
    }
}

// ---------------- kernel 2: GNN via MFMA. 512 threads, G=10 rows ----------------
// 1D grid 5120 with XCD-affinity decode (wgid%8 == b%8). LDS 39288 B -> 4 blocks/CU.
__global__ __launch_bounds__(512, 8) void k_gnn(
    const float* __restrict__ xL, const float* __restrict__ xG,
    const int* __restrict__ adj,
    const float* __restrict__ alpL, const float* __restrict__ alpG,
    const float* __restrict__ AL, const float* __restrict__ AG,
    const ushort_t* __restrict__ LWT,
    const float* __restrict__ LBL, const float* __restrict__ LBG,
    float* __restrict__ outLp, float* __restrict__ outGp)
{
    const int wg = blockIdx.x;
    const int xcd = wg & 7;
    const int q = wg >> 3;
    const int b = (q / 20) * 8 + xcd;
    const int c20 = q % 20;
    const int gz = c20 & 1;
    const int r0 = (c20 >> 1) * cG;

    const float* __restrict__ x   = gz ? xG : xL;
    const float* __restrict__ alp = gz ? alpG : alpL;
    const float* __restrict__ A   = gz ? AG : AL;
    const float* __restrict__ LB  = gz ? LBG : LBL;
    float* __restrict__ out       = gz ? outGp : outLp;

    const int tid = threadIdx.x, wid = tid >> 6, l = tid & 63;
    const int la = l & 15, lg = l >> 4;

    __shared__ __align__(16) uchar_t lds[39288];
    ushort_t* x16   = (ushort_t*)(lds);           // [100][136]
    ushort_t* xT    = (ushort_t*)(lds);           // [128][104], after gating-p1
    ushort_t* sc    = (ushort_t*)(lds + 27200);   // [2][16][104]
    ushort_t* A16   = (ushort_t*)(lds + 33856);   // [8][128], scores phase only
    ushort_t* out16 = (ushort_t*)(lds + 33856);   // [16][136], PV phase (A16 dead)
    uchar_t*  adjb  = lds + 38208;                // [10][104]
    float*    alps  = (float*)(lds + 39248);

    // ---- S1: stage x16 (paired dwords), A16, adjb, sc zero, alps
    for (int idx = tid; idx < 100 * 64; idx += 512) {
        int j = idx >> 6, d2 = idx & 63;
        const float* xp = x + ((size_t)b * cN + j) * cD + 2 * d2;
        *(unsigned*)&x16[j * 136 + 2 * d2] = pkh2(xp[0], xp[1]);
    }
    {   // 8 rows x 64 dwords
        int row = tid >> 6, d2 = tid & 63;
        const float* ap = A + row * cD + 2 * d2;
        *(unsigned*)&A16[row * 128 + 2 * d2] = pkh2(ap[0], ap[1]);
    }
    for (int idx = tid; idx < cG * cN; idx += 512) {
        int i = idx / cN, j = idx % cN;
        adjb[i * 104 + j] = (uchar_t)adj[((size_t)b * cN + r0 + i) * cN + j];
    }
    for (int idx = tid; idx < 1664; idx += 512) ((unsigned*)sc)[idx] = 0u;
    if (tid < cG) alps[tid] = alp[b * cN + r0 + tid];
    __syncthreads();

    // ---- scores, both h: C[j][(ik)] = sum_d x16[j][d] * (x16[r0+i][d]*A16[h*4+k][d])
    for (int h = 0; h < 2; h++) {
        f16x8 afr[4];
        const int krow = (h * 4 + (la & 3)) * 128;
#pragma unroll
        for (int kc = 0; kc < 4; kc++) afr[kc] = ldf(&A16[krow + kc * 32 + lg * 8]);
        for (int job = wid; job < 21; job += 8) {
            int mt = job / 3, nt = job % 3;
            int arow = mt * 16 + la; if (arow > 99) arow = 99;
            int brow = nt * 16 + la; if (brow > 39) brow = 39;
            int xrow = r0 + (brow >> 2);
            f32x4 c = {0.f, 0.f, 0.f, 0.f};
#pragma unroll
            for (int kc = 0; kc < 4; kc++) {
                f16x8 a  = ldf(&x16[arow * 136 + kc * 32 + lg * 8]);
                f16x8 xb = ldf(&x16[xrow * 136 + kc * 32 + lg * 8]);
                c = mm(a, xb * afr[kc], c);
            }
            int col = nt * 16 + la, i = col >> 2, k = col & 3;
            if (i < cG) {
#pragma unroll
                for (int r = 0; r < 4; r++) {
                    int j = mt * 16 + lg * 4 + r;
                    if (j < cN && (int)adjb[i * 104 + j] == k + 1) {
                        float v = c[r];
                        v = (v >= 0.f) ? v : 0.2f * v;     // leaky
                        sc[(h * 16 + i) * 104 + j] = f2hbits(v);
                    }
                }
            }
        }
    }
    __syncthreads();

    // ---- entmax: waves 0-3 rows {wid, 8+wid, 16+wid}; waves 4-7 rows {wid, 8+wid}
    {
        const bool w3 = (wid < 4);
        const float log2_rn = -6.6438561897747395f;
        float X0[3], X1[3], INV[3], TLO[3], DM[3], FLO[3], TM[3], S[3];
        int RI[3], RH[3];
#pragma unroll
        for (int q2 = 0; q2 < 3; q2++) {
            if (q2 < 2 || w3) {
                int r = (q2 < 2) ? (wid + 8 * q2) : (16 + wid);
                RI[q2] = r >> 1; RH[q2] = r & 1;
                float am1 = alps[RI[q2]] - 1.f;
                INV[q2] = 1.f / am1;
                X0[q2] = h2f(sc[(RH[q2] * 16 + RI[q2]) * 104 + l]) * am1;
                X1[q2] = (l + 64 < cN) ? h2f(sc[(RH[q2] * 16 + RI[q2]) * 104 + l + 64]) * am1 : -INFINITY;
                TM[q2] = ex2(am1 * log2_rn);
            }
        }
        float MX[3];
#pragma unroll
        for (int q2 = 0; q2 < 3; q2++) if (q2 < 2 || w3) MX[q2] = fmaxf(X0[q2], X1[q2]);
#pragma unroll
        for (int o = 32; o; o >>= 1) {
#pragma unroll
            for (int q2 = 0; q2 < 3; q2++) if (q2 < 2 || w3) MX[q2] = fmaxf(MX[q2], __shfl_xor(MX[q2], o, 64));
        }
#pragma unroll
        for (int q2 = 0; q2 < 3; q2++) if (q2 < 2 || w3) { TLO[q2] = MX[q2] - 1.f; DM[q2] = 1.f - TM[q2]; }
#pragma unroll
        for (int q2 = 0; q2 < 3; q2++) if (q2 < 2 || w3) {
            float z0 = fmaxf(X0[q2] - TLO[q2], 0.f);
            float z1 = fmaxf(X1[q2] - TLO[q2], 0.f);
            S[q2] = ex2(INV[q2] * lg2(z0)) + ex2(INV[q2] * lg2(z1));
        }
#pragma unroll
        for (int o = 32; o; o >>= 1) {
#pragma unroll
            for (int q2 = 0; q2 < 3; q2++) if (q2 < 2 || w3) S[q2] += __shfl_xor(S[q2], o, 64);
        }
#pragma unroll
        for (int q2 = 0; q2 < 3; q2++) if (q2 < 2 || w3) FLO[q2] = S[q2] - 1.f;

#pragma unroll 1
        for (int it = 0; it < N_ITER_RUN - 1; ++it) {
#pragma unroll
            for (int q2 = 0; q2 < 3; q2++) if (q2 < 2 || w3) { DM[q2] *= 0.5f; TM[q2] = TLO[q2] + DM[q2]; }
#pragma unroll
            for (int q2 = 0; q2 < 3; q2++) if (q2 < 2 || w3) {
                float z0 = fmaxf(X0[q2] - TM[q2], 0.f);
                float z1 = fmaxf(X1[q2] - TM[q2], 0.f);
                S[q2] = ex2(INV[q2] * lg2(z0)) + ex2(INV[q2] * lg2(z1));
            }
#pragma unroll
            for (int o = 32; o; o >>= 1) {
#pragma unroll
                for (int q2 = 0; q2 < 3; q2++) if (q2 < 2 || w3) S[q2] += __shfl_xor(S[q2], o, 64);
            }
#pragma unroll
            for (int q2 = 0; q2 < 3; q2++) if (q2 < 2 || w3)
                if ((S[q2] - 1.f) * FLO[q2] >= 0.f) TLO[q2] = TM[q2];
        }
        float P0[3], P1[3];
#pragma unroll
        for (int q2 = 0; q2 < 3; q2++) if (q2 < 2 || w3) {
            DM[q2] *= 0.5f; TM[q2] = TLO[q2] + DM[q2];
            float z0 = fmaxf(X0[q2] - TM[q2], 0.f);
            float z1 = fmaxf(X1[q2] - TM[q2], 0.f);
            P0[q2] = ex2(INV[q2] * lg2(z0));
            P1[q2] = ex2(INV[q2] * lg2(z1));
            S[q2] = P0[q2] + P1[q2];
        }
#pragma unroll
        for (int o = 32; o; o >>= 1) {
#pragma unroll
            for (int q2 = 0; q2 < 3; q2++) if (q2 < 2 || w3) S[q2] += __shfl_xor(S[q2], o, 64);
        }
        __syncthreads();
#pragma unroll
        for (int q2 = 0; q2 < 3; q2++) {
            if (q2 < 2 || w3) {
                float invs = 1.f / S[q2];
                sc[(RH[q2] * 16 + RI[q2]) * 104 + l] = f2hbits(P0[q2] * invs);
                if (l + 64 < cN) sc[(RH[q2] * 16 + RI[q2]) * 104 + l + 64] = f2hbits(P1[q2] * invs);
            }
        }
    }

    // ---- gating part 1 (x16 still intact): cg[h] = xi @ LW_top
    f32x4 cg0 = {0.f, 0.f, 0.f, 0.f}, cg1 = {0.f, 0.f, 0.f, 0.f};
    {
        const int d = wid * 16 + la;
        int arow = r0 + la; if (arow > 99) arow = 99;
#pragma unroll
        for (int h = 0; h < 2; h++) {
            const ushort_t* lwbase = LWT + ((size_t)(gz * 2 + h) * cD + d) * 256;
            f32x4 c = {0.f, 0.f, 0.f, 0.f};
#pragma unroll
            for (int kc = 0; kc < 4; kc++) {
                f16x8 a = ldf(&x16[arow * 136 + kc * 32 + lg * 8]);
                uint4 u = *(const uint4*)(lwbase + kc * 32 + lg * 8);
                f16x8 bb; __builtin_memcpy(&bb, &u, 16);
                c = mm(a, bb, c);
            }
            if (h) cg1 = c; else cg0 = c;
        }
    }
    __syncthreads();

    // ---- xT build from GLOBAL x (L2-hot), b128 writes, into dead x16 region
    for (int job = tid; job < 13 * 128; job += 512) {
        int d2 = job & 127, jc = job >> 7;
        f16x8 v;
#pragma unroll
        for (int t = 0; t < 8; t++) {
            int j = jc * 8 + t;
            float f = (j < cN) ? x[((size_t)b * cN + j) * cD + d2] : 0.f;
            v[t] = (__fp16)f;
        }
        uint4 u; __builtin_memcpy(&u, &v, 16);
        *(uint4*)(&xT[d2 * 104 + jc * 8]) = u;
    }
    __syncthreads();

    // ---- PV + gating part 2, per h ----
    float res[4] = {0.f, 0.f, 0.f, 0.f};
    const int dt = wid;
    const int d = dt * 16 + la;
    for (int h = 0; h < 2; h++) {
        if (h) __syncthreads();
        {
            f32x4 c = {0.f, 0.f, 0.f, 0.f};
#pragma unroll
            for (int kc = 0; kc < 3; kc++) {
                f16x8 a  = ldf(&sc[(h * 16 + la) * 104 + kc * 32 + lg * 8]);
                f16x8 bb = ldf(&xT[(dt * 16 + la) * 104 + kc * 32 + lg * 8]);
                c = mm(a, bb, c);
            }
#pragma unroll
            for (int r = 0; r < 4; r++) {
                int i = lg * 4 + r;
                float acc = c[r];
#pragma unroll
                for (int j = 96; j < 100; j++)
                    acc += h2f(sc[(h * 16 + i) * 104 + j]) * h2f(xT[d * 104 + j]);
                if (i < cG) out16[i * 136 + d] = f2hbits(acc);
            }
        }
        __syncthreads();
        {
            f32x4 c = h ? cg1 : cg0;
            const ushort_t* lwbase = LWT + ((size_t)(gz * 2 + h) * cD + d) * 256 + 128;
#pragma unroll
            for (int kc = 0; kc < 4; kc++) {
                f16x8 a = ldf(&out16[la * 136 + kc * 32 + lg * 8]);
                uint4 u = *(const uint4*)(lwbase + kc * 32 + lg * 8);
                f16x8 bb; __builtin_memcpy(&bb, &u, 16);
                c = mm(a, bb, c);
            }
            float lb = LB[h * cD + d];
#pragma unroll
            for (int r = 0; r < 4; r++) {
                int i = lg * 4 + r;
                float g = sigm(c[r] + lb);
                float o = h2f(out16[i * 136 + d]);
                float xi = h2f(xT[d * 104 + r0 + i]);
                res[r] += g * o + (1.f - g) * xi;
            }
        }
    }
#pragma unroll
    for (int r = 0; r < 4; r++) {
        int i = lg * 4 + r;
        if (i < cG) out[((size_t)b * cN + r0 + i) * cD + d] = res[r];
    }
}

// ---------------- kernel 3: fused tail (one block per b, 512 threads) ----------------
__global__ __launch_bounds__(512) void k_tail(
    const float* __restrict__ S, const float* __restrict__ T,
    const int* __restrict__ iidx, const float* __restrict__ g2w,
    const float* __restrict__ G1b, const float* __restrict__ W2,
    const ushort_t* __restrict__ W0T, const ushort_t* __restrict__ W1gT,
    const ushort_t* __restrict__ W1bT, const ushort_t* __restrict__ G1T,
    const float* __restrict__ posW1, float* __restrict__ outp)
{
    const int b = blockIdx.x;
    const int tid = threadIdx.x, wid = tid >> 6, l = tid & 63;
    const int la = l & 15, lg = l >> 4;
    const float scale = 0.088388347648318447f;   // 1/sqrt(128)

    __shared__ __align__(16) ushort_t s16[100 * 136];   // s, then snew, then nh
    __shared__ __align__(16) ushort_t t16[100 * 136];   // t, then hid
    __shared__ float a_sh[cN];
    __shared__ float part[4][cD];
    __shared__ float hs_s[cD];
    __shared__ float hsg_s[cD];
    __shared__ float beta_s[cN];
    __shared__ int   idx_s[cN];

    for (int idx = tid; idx < 100 * 64; idx += 512) {
        int n = idx >> 6, d2 = idx & 63;
        const float* sp = S + ((size_t)b * cN + n) * cD + 2 * d2;
        const float* tp = T + ((size_t)b * cN + n) * cD + 2 * d2;
        *(unsigned*)&s16[n * 136 + 2 * d2] = pkh2(sp[0], sp[1]);
        *(unsigned*)&t16[n * 136 + 2 * d2] = pkh2(tp[0], tp[1]);
    }
    if (tid < cN) idx_s[tid] = iidx[b * cN + tid];
    __syncthreads();

    if (wid < 7) {
        int arow = wid * 16 + la; if (arow > 99) arow = 99;
        float asum[4] = {0.f, 0.f, 0.f, 0.f};
        for (int nt = 0; nt < 8; nt++) {
            f32x4 cs = {0.f, 0.f, 0.f, 0.f}, ct = {0.f, 0.f, 0.f, 0.f};
            const ushort_t* b0 = W0T + (size_t)(nt * 16 + la) * cD;
            const ushort_t* b1 = W1gT + (size_t)(nt * 16 + la) * cD;
#pragma unroll
            for (int kc = 0; kc < 4; kc++) {
                f16x8 as = ldf(&s16[arow * 136 + kc * 32 + lg * 8]);
                f16x8 at = ldf(&t16[arow * 136 + kc * 32 + lg * 8]);
                uint4 u0 = *(const uint4*)(b0 + kc * 32 + lg * 8);
                uint4 u1 = *(const uint4*)(b1 + kc * 32 + lg * 8);
                f16x8 w0v, w1v; __builtin_memcpy(&w0v, &u0, 16); __builtin_memcpy(&w1v, &u1, 16);
                cs = mm(as, w0v, cs);
                ct = mm(at, w1v, ct);
            }
#pragma unroll
            for (int r = 0; r < 4; r++) asum[r] += cs[r] * ct[r];
        }
#pragma unroll
        for (int o = 8; o; o >>= 1) {
#pragma unroll
            for (int r = 0; r < 4; r++) asum[r] += __shfl_xor(asum[r], o, 64);
        }
        if (la == 0) {
#pragma unroll
            for (int r = 0; r < 4; r++) {
                int n = wid * 16 + lg * 4 + r;
                if (n < cN) a_sh[n] = asum[r] * scale;
            }
        }
    }
    __syncthreads();

    for (int idx = tid; idx < 100 * 64; idx += 512) {
        int n = idx >> 6, d2 = idx & 63;
        unsigned su = *(unsigned*)&s16[n * 136 + 2 * d2];
        unsigned tu = *(unsigned*)&t16[n * 136 + 2 * d2];
        float a = a_sh[n];
        float s0 = h2f((ushort_t)(su & 0xffffu)), s1 = h2f((ushort_t)(su >> 16));
        float t0 = h2f((ushort_t)(tu & 0xffffu)), t1 = h2f((ushort_t)(tu >> 16));
        *(unsigned*)&s16[n * 136 + 2 * d2] = pkh2(s0 + a * (t0 - s0), s1 + a * (t1 - s1));
    }
    __syncthreads();

    for (int idx = tid; idx < 100 * 64; idx += 512) {
        int n = idx >> 6, d2 = idx & 63;
        int rsrc = idx_s[n];
        *(unsigned*)&t16[n * 136 + 2 * d2] = *(unsigned*)&s16[rsrc * 136 + 2 * d2];
    }
    __syncthreads();

    {
        int g = tid >> 7, d = tid & 127;
        float sum = 0.f;
        for (int n = g * 25; n < g * 25 + 25; n++) sum += h2f(t16[n * 136 + d]);
        part[g][d] = sum;
    }
    __syncthreads();
    if (tid < cD) hs_s[tid] = (part[0][tid] + part[1][tid] + part[2][tid] + part[3][tid]) * (1.f / (100.f + 1e-7f));
    __syncthreads();
    if (tid < cD) {
        float acc = 0.f;
        for (int c = 0; c < cD; c++) acc += hs_s[c] * g2w[c * cD + tid];
        hsg_s[tid] = acc;
    }
    __syncthreads();

    if (wid < 7) {
        int arow = wid * 16 + la; if (arow > 99) arow = 99;
        for (int nt = 0; nt < 8; nt++) {
            f32x4 c = {0.f, 0.f, 0.f, 0.f};
            const ushort_t* bb = W1bT + (size_t)(nt * 16 + la) * cD;
#pragma unroll
            for (int kc = 0; kc < 4; kc++) {
                f16x8 a = ldf(&t16[arow * 136 + kc * 32 + lg * 8]);
                uint4 u = *(const uint4*)(bb + kc * 32 + lg * 8);
                f16x8 wv; __builtin_memcpy(&wv, &u, 16);
                c = mm(a, wv, c);
            }
            int d = nt * 16 + la;
#pragma unroll
            for (int r = 0; r < 4; r++) {
                int n = wid * 16 + lg * 4 + r;
                if (n < cN) s16[n * 136 + d] = f2hbits(tanhf(c[r] + posW1[n * cD + d]));
            }
        }
    }
    __syncthreads();

    if (wid < 7) {
        int arow = wid * 16 + la; if (arow > 99) arow = 99;
        float bsum[4] = {0.f, 0.f, 0.f, 0.f};
        for (int nt = 0; nt < 8; nt++) {
            f32x4 c = {0.f, 0.f, 0.f, 0.f};
            const ushort_t* bb = G1T + (size_t)(nt * 16 + la) * cD;
#pragma unroll
            for (int kc = 0; kc < 4; kc++) {
                f16x8 a = ldf(&s16[arow * 136 + kc * 32 + lg * 8]);
                uint4 u = *(const uint4*)(bb + kc * 32 + lg * 8);
                f16x8 wv; __builtin_memcpy(&wv, &u, 16);
                c = mm(a, wv, c);
            }
            int d = nt * 16 + la;
            float add = G1b[d] + hsg_s[d];
            float w2v = W2[d];
#pragma unroll
            for (int r = 0; r < 4; r++) bsum[r] += sigm(c[r] + add) * w2v;
        }
#pragma unroll
        for (int o = 8; o; o >>= 1) {
#pragma unroll
            for (int r = 0; r < 4; r++) bsum[r] += __shfl_xor(bsum[r], o, 64);
        }
        if (la == 0) {
#pragma unroll
            for (int r = 0; r < 4; r++) {
                int n = wid * 16 + lg * 4 + r;
                if (n < cN) beta_s[n] = bsum[r];
            }
        }
    }
    __syncthreads();

    {
        int g = tid >> 7, d = tid & 127;
        float sum = 0.f;
        for (int n = g * 25; n < g * 25 + 25; n++) sum += beta_s[n] * h2f(t16[n * 136 + d]);
        part[g][d] = sum;
    }
    __syncthreads();
    if (tid < cD) outp[b * cD + tid] = part[0][tid] + part[1][tid] + part[2][tid] + part[3][tid];
}

extern "C" void kernel_launch(void* const* d_in, const int* in_sizes, int n_in,
                              void* d_out, int out_size, void* d_ws, size_t ws_size,
                              hipStream_t stream) {
    const float* gnn   = (const float*)d_in[0];
    const float* drop  = (const float*)d_in[1];
    const float* proto = (const float*)d_in[2];
    const float* pos   = (const float*)d_in[3];
    const float* laL_a = (const float*)d_in[4];
    const float* laL_w = (const float*)d_in[5];
    const float* laL_b = (const float*)d_in[6];
    const float* ssL_w = (const float*)d_in[7];
    const float* ssL_b = (const float*)d_in[8];
    const float* laG_a = (const float*)d_in[9];
    const float* laG_w = (const float*)d_in[10];
    const float* laG_b = (const float*)d_in[11];
    const float* ssG_w = (const float*)d_in[12];
    const float* ssG_b = (const float*)d_in[13];
    const float* gem_w = (const float*)d_in[14];
    const float* fn_w  = (const float*)d_in[15];
    const float* fn_b  = (const float*)d_in[16];
    const float* w_1   = (const float*)d_in[17];
    const float* w_2   = (const float*)d_in[18];
    const float* glu1w = (const float*)d_in[19];
    const float* glu1b = (const float*)d_in[20];
    const float* glu2w = (const float*)d_in[21];
    const int*   adj   = (const int*)d_in[22];
    const int*   iidx  = (const int*)d_in[23];
    const void*  m0    = d_in[24];
    float* out = (float*)d_out;

    const size_t BND = (size_t)cB * cN * cD;
    float* w = (float*)d_ws;
    float* bufA = w;               // gi
    float* bufB = bufA + BND;      // pi
    float* locS = bufB + BND;
    float* gloS = locS + BND;
    float* aL   = gloS + BND;
    float* aG   = aL + (size_t)cB * cN;
    float* avgdot = aG + (size_t)cB * cN;
    ushort_t* LWT  = (ushort_t*)(avgdot + cB);
    ushort_t* W1bT = LWT + (size_t)4 * cD * 256;
    ushort_t* G1T  = W1bT + (size_t)cD * cD;
    ushort_t* W0T  = G1T + (size_t)cD * cD;
    ushort_t* W1gT = W0T + (size_t)cD * cD;
    float* posW1   = (float*)(W1gT + (size_t)cD * cD);

    k_cvtw<<<dim3(9, 8), dim3(256), 0, stream>>>(laL_w, laG_w, w_1, glu1w, gem_w, pos,
                                                 LWT, W1bT, G1T, W0T, W1gT, posW1);
    k_prep_a<<<dim3(cB), dim3(256), 0, stream>>>(gnn, m0, fn_w, avgdot);
    k_prep_b<<<dim3(cB, 13), dim3(512), 0, stream>>>(gnn, drop, proto, m0, avgdot,
                                                     fn_w, fn_b, ssL_w, ssL_b, ssG_w, ssG_b,
                                                     bufA, bufB, aL, aG);
    k_gnn<<<dim3(cNCH * cB * 2), dim3(512), 0, stream>>>(
        bufA, bufB, adj, aL, aG, laL_a, laG_a, LWT, laL_b, laG_b, locS, gloS);
    k_tail<<<dim3(cB), dim3(512), 0, stream>>>(locS, gloS, iidx, glu2w, glu1b, w_2,
                                               W0T, W1gT, W1bT, G1T, posW1, out);
}

// Round 21
// 266.361 us; speedup vs baseline: 1.5139x; 1.0175x over previous
//
#include <hip/hip_runtime.h>
#include <math.h>

// DenoiseEncoder forward, MI355X. B=256,N=100,D=128,H=2.
// v17 = v16 (round-20, 271us, absmax 4.0) with N_ITER_RUN 6 -> 5 (terminal ladder step).
// Ladder: 24/14/12/10/8/6 iters -> absmax 2/2/4/4/4/4 (f16 floor dominates).
constexpr int cB = 256, cN = 100, cD = 128, cH = 2, cG = 10, cNCH = cN / cG;
constexpr int N_ITER_RUN = 5;

typedef __fp16 h2 __attribute__((ext_vector_type(2)));
typedef __fp16 f16x8 __attribute__((ext_vector_type(8)));
typedef float f32x4 __attribute__((ext_vector_type(4)));
typedef unsigned short ushort_t;
typedef unsigned char uchar_t;

// ---------------- helpers ----------------
__device__ __forceinline__ float wsum(float v) {
#pragma unroll
    for (int o = 32; o; o >>= 1) v += __shfl_xor(v, o, 64);
    return v;
}
__device__ __forceinline__ float sigm(float x) { return 1.f / (1.f + __expf(-x)); }
__device__ __forceinline__ float ex2(float x) {
#if __has_builtin(__builtin_amdgcn_exp2f)
    return __builtin_amdgcn_exp2f(x);
#else
    return exp2f(x);
#endif
}
__device__ __forceinline__ float lg2(float x) {
#if __has_builtin(__builtin_amdgcn_logf)
    return __builtin_amdgcn_logf(x);       // v_log_f32; lg2(0) = -inf
#else
    return __log2f(x);
#endif
}
__device__ __forceinline__ unsigned pkh2(float a, float b) {
#if __has_builtin(__builtin_amdgcn_cvt_pkrtz)
    h2 r = __builtin_amdgcn_cvt_pkrtz(a, b);
#else
    h2 r; r.x = (__fp16)a; r.y = (__fp16)b;
#endif
    unsigned u; __builtin_memcpy(&u, &r, 4); return u;
}
__device__ __forceinline__ ushort_t f2hbits(float v) {
    __fp16 h = (__fp16)v;
    ushort_t u; __builtin_memcpy(&u, &h, 2); return u;
}
__device__ __forceinline__ float h2f(ushort_t u) {
    __fp16 h; __builtin_memcpy(&h, &u, 2); return (float)h;
}
__device__ __forceinline__ f16x8 ldf(const ushort_t* p) {   // 16B-aligned load
    uint4 u = *(const uint4*)p;
    f16x8 a; __builtin_memcpy(&a, &u, 16); return a;
}
__device__ __forceinline__ f32x4 mm(f16x8 a, f16x8 b, f32x4 c) {
    return __builtin_amdgcn_mfma_f32_16x16x32_f16(a, b, c, 0, 0, 0);
}

// ---------------- kernel 0: weight converts + posW1 (grid (9,8)) ----------------
__global__ __launch_bounds__(256) void k_cvtw(
    const float* __restrict__ LWL, const float* __restrict__ LWG,
    const float* __restrict__ W1, const float* __restrict__ G1w,
    const float* __restrict__ GW, const float* __restrict__ pos,
    ushort_t* __restrict__ LWT, ushort_t* __restrict__ W1bT, ushort_t* __restrict__ G1T,
    ushort_t* __restrict__ W0T, ushort_t* __restrict__ W1gT, float* __restrict__ posW1)
{
    const int bz = blockIdx.x;
    if (bz < 4) {
        const int gz = bz >> 1, h = bz & 1;
        const int cseg = blockIdx.y * 32;
        const float* src = (gz ? LWG : LWL) + (size_t)h * 2 * cD * cD;
        for (int idx = threadIdx.x; idx < 32 * cD; idx += 256) {
            int c = cseg + (idx >> 7), d = idx & 127;
            LWT[((size_t)bz * cD + d) * 256 + c] = f2hbits(src[c * cD + d]);
        }
    } else if (bz < 8) {
        const float* src = (bz == 4) ? (W1 + cD * cD) : (bz == 5) ? G1w
                         : (bz == 6) ? GW : (GW + cD * cD);
        ushort_t* dst = (bz == 4) ? W1bT : (bz == 5) ? G1T : (bz == 6) ? W0T : W1gT;
        const int cseg = blockIdx.y * 16;
        for (int idx = threadIdx.x; idx < 16 * cD; idx += 256) {
            int c = cseg + (idx >> 7), d = idx & 127;
            dst[(size_t)d * cD + c] = f2hbits(src[c * cD + d]);
        }
    } else {
        int n0 = blockIdx.y * 13;
        int cnt = (n0 + 13 <= cN) ? 13 : (cN - n0);
        for (int idx = threadIdx.x; idx < cnt * cD; idx += 256) {
            int n = n0 + (idx >> 7), d = idx & 127;
            float acc = 0.f;
            for (int c = 0; c < cD; c++) acc += pos[n * cD + c] * W1[c * cD + d];
            posW1[n * cD + d] = acc;
        }
    }
}

// ---------------- kernel 1a: avgdot[b] ----------------
__global__ __launch_bounds__(256) void k_prep_a(
    const float* __restrict__ gnn, const void* __restrict__ m0,
    const float* __restrict__ fnw, float* __restrict__ avgdot)
{
    const int b = blockIdx.x, tid = threadIdx.x;
    const int w = tid >> 6, l = tid & 63;
    const int d0 = l, d1 = l + 64;
    __shared__ int fmt_s;
    __shared__ float mrow[cN];
    __shared__ float part[4][cD];
    __shared__ float red2[2];
    if (tid < 64) {
        unsigned u = ((const unsigned*)m0)[tid];
        int c = ((u & 0xffu) != 0) + ((u & 0xff00u) != 0) + ((u & 0xff0000u) != 0) + ((u >> 24) != 0);
        float cf = wsum((float)c);
        if (tid == 0) fmt_s = (cf > 128.f);
    }
    __syncthreads();
    if (tid < cN) {
        int idx = b * cN + tid;
        float m;
        if (fmt_s) m = ((const unsigned char*)m0)[idx] ? 1.f : 0.f;
        else       m = ((const int*)m0)[idx] ? 1.f : 0.f;
        mrow[tid] = m;
    }
    __syncthreads();
    float s0 = 0.f, s1 = 0.f;
    for (int n = w; n < cN; n += 4) {
        size_t o = ((size_t)b * cN + n) * cD;
        float m = mrow[n];
        s0 += gnn[o + d0] * m;
        s1 += gnn[o + d1] * m;
    }
    part[w][d0] = s0; part[w][d1] = s1;
    __syncthreads();
    const float rcnt = 1.f / (100.f + 1e-7f);
    if (tid < cD) {
        float avg = (part[0][tid] + part[1][tid] + part[2][tid] + part[3][tid]) * rcnt;
        float v = wsum(avg * fnw[tid]);
        if ((tid & 63) == 0) red2[tid >> 6] = v;
    }
    __syncthreads();
    if (tid == 0) avgdot[b] = red2[0] + red2[1];
}

// ---------------- kernel 1b: per-(b,n) wave: gi, pi, aL, aG ----------------
__global__ __launch_bounds__(512) void k_prep_b(
    const float* __restrict__ gnn, const float* __restrict__ drop, const float* __restrict__ proto,
    const void* __restrict__ m0, const float* __restrict__ avgdot,
    const float* __restrict__ fnw, const float* __restrict__ fnb,
    const float* __restrict__ ssLw, const float* __restrict__ ssLb,
    const float* __restrict__ ssGw, const float* __restrict__ ssGb,
    float* __restrict__ gi, float* __restrict__ pi,
    float* __restrict__ aL, float* __restrict__ aG)
{
    const int b = blockIdx.x, tid = threadIdx.x;
    const int wid = tid >> 6, l = tid & 63;
    const int n = blockIdx.y * 8 + wid;
    __shared__ int fmt_s;
    if (tid < 64) {
        unsigned u = ((const unsigned*)m0)[tid];
        int c = ((u & 0xffu) != 0) + ((u & 0xff00u) != 0) + ((u & 0xff0000u) != 0) + ((u >> 24) != 0);
        float cf = wsum((float)c);
        if (tid == 0) fmt_s = (cf > 128.f);
    }
    __syncthreads();
    if (n >= cN) return;
    float m;
    {
        int idx = b * cN + n;
        if (fmt_s) m = ((const unsigned char*)m0)[idx] ? 1.f : 0.f;
        else       m = ((const int*)m0)[idx] ? 1.f : 0.f;
    }
    const float dm = 1.f - m;
    const int d0 = l, d1 = l + 64;
    const size_t o = ((size_t)b * cN + n) * cD;
    float dr0 = drop[o + d0] * dm, dr1 = drop[o + d1] * dm;
    float p0 = proto[o + d0] * m,  p1 = proto[o + d1] * m;
    pi[o + d0] = p0; pi[o + d1] = p1;
    float r1 = wsum(dr0 * fnw[cD + d0] + dr1 * fnw[cD + d1]);
    float r2 = wsum(p0 * ssGw[d0] + p1 * ssGw[d1]);
    float alpha = r1 + avgdot[b] + fnb[0];
    float g0 = gnn[o + d0] * m + alpha * dr0;
    float g1 = gnn[o + d1] * m + alpha * dr1;
    gi[o + d0] = g0; gi[o + d1] = g1;
    float r3 = wsum(g0 * ssLw[d0] + g1 * ssLw[d1]);
    if (l == 0) {
        aL[b * cN + n] = 1.f + sigm(r3 + ssLb[0]);
        aG[b * cN + n] = 1.f + sigm(r2 + ssGb[0]);
    }
}

// ---------------- kernel 2: GNN via MFMA. 512 threads, G=10 rows ----------------
// 1D grid 5120 with XCD-affinity decode (wgid%8 == b%8). LDS 39288 B -> 4 blocks/CU.
__global__ __launch_bounds__(512, 8) void k_gnn(
    const float* __restrict__ xL, const float* __restrict__ xG,
    const int* __restrict__ adj,
    const float* __restrict__ alpL, const float* __restrict__ alpG,
    const float* __restrict__ AL, const float* __restrict__ AG,
    const ushort_t* __restrict__ LWT,
    const float* __restrict__ LBL, const float* __restrict__ LBG,
    float* __restrict__ outLp, float* __restrict__ outGp)
{
    const int wg = blockIdx.x;
    const int xcd = wg & 7;
    const int q = wg >> 3;
    const int b = (q / 20) * 8 + xcd;
    const int c20 = q % 20;
    const int gz = c20 & 1;
    const int r0 = (c20 >> 1) * cG;

    const float* __restrict__ x   = gz ? xG : xL;
    const float* __restrict__ alp = gz ? alpG : alpL;
    const float* __restrict__ A   = gz ? AG : AL;
    const float* __restrict__ LB  = gz ? LBG : LBL;
    float* __restrict__ out       = gz ? outGp : outLp;

    const int tid = threadIdx.x, wid = tid >> 6, l = tid & 63;
    const int la = l & 15, lg = l >> 4;

    __shared__ __align__(16) uchar_t lds[39288];
    ushort_t* x16   = (ushort_t*)(lds);           // [100][136]
    ushort_t* xT    = (ushort_t*)(lds);           // [128][104], after gating-p1
    ushort_t* sc    = (ushort_t*)(lds + 27200);   // [2][16][104]
    ushort_t* A16   = (ushort_t*)(lds + 33856);   // [8][128], scores phase only
    ushort_t* out16 = (ushort_t*)(lds + 33856);   // [16][136], PV phase (A16 dead)
    uchar_t*  adjb  = lds + 38208;                // [10][104]
    float*    alps  = (float*)(lds + 39248);

    // ---- S1: stage x16 (paired dwords), A16, adjb, sc zero, alps
    for (int idx = tid; idx < 100 * 64; idx += 512) {
        int j = idx >> 6, d2 = idx & 63;
        const float* xp = x + ((size_t)b * cN + j) * cD + 2 * d2;
        *(unsigned*)&x16[j * 136 + 2 * d2] = pkh2(xp[0], xp[1]);
    }
    {   // 8 rows x 64 dwords
        int row = tid >> 6, d2 = tid & 63;
        const float* ap = A + row * cD + 2 * d2;
        *(unsigned*)&A16[row * 128 + 2 * d2] = pkh2(ap[0], ap[1]);
    }
    for (int idx = tid; idx < cG * cN; idx += 512) {
        int i = idx / cN, j = idx % cN;
        adjb[i * 104 + j] = (uchar_t)adj[((size_t)b * cN + r0 + i) * cN + j];
    }
    for (int idx = tid; idx < 1664; idx += 512) ((unsigned*)sc)[idx] = 0u;
    if (tid < cG) alps[tid] = alp[b * cN + r0 + tid];
    __syncthreads();

    // ---- scores, both h: C[j][(ik)] = sum_d x16[j][d] * (x16[r0+i][d]*A16[h*4+k][d])
    for (int h = 0; h < 2; h++) {
        f16x8 afr[4];
        const int krow = (h * 4 + (la & 3)) * 128;
#pragma unroll
        for (int kc = 0; kc < 4; kc++) afr[kc] = ldf(&A16[krow + kc * 32 + lg * 8]);
        for (int job = wid; job < 21; job += 8) {
            int mt = job / 3, nt = job % 3;
            int arow = mt * 16 + la; if (arow > 99) arow = 99;
            int brow = nt * 16 + la; if (brow > 39) brow = 39;
            int xrow = r0 + (brow >> 2);
            f32x4 c = {0.f, 0.f, 0.f, 0.f};
#pragma unroll
            for (int kc = 0; kc < 4; kc++) {
                f16x8 a  = ldf(&x16[arow * 136 + kc * 32 + lg * 8]);
                f16x8 xb = ldf(&x16[xrow * 136 + kc * 32 + lg * 8]);
                c = mm(a, xb * afr[kc], c);
            }
            int col = nt * 16 + la, i = col >> 2, k = col & 3;
            if (i < cG) {
#pragma unroll
                for (int r = 0; r < 4; r++) {
                    int j = mt * 16 + lg * 4 + r;
                    if (j < cN && (int)adjb[i * 104 + j] == k + 1) {
                        float v = c[r];
                        v = (v >= 0.f) ? v : 0.2f * v;     // leaky
                        sc[(h * 16 + i) * 104 + j] = f2hbits(v);
                    }
                }
            }
        }
    }
    __syncthreads();

    // ---- entmax: waves 0-3 rows {wid, 8+wid, 16+wid}; waves 4-7 rows {wid, 8+wid}
    {
        const bool w3 = (wid < 4);
        const float log2_rn = -6.6438561897747395f;
        float X0[3], X1[3], INV[3], TLO[3], DM[3], FLO[3], TM[3], S[3];
        int RI[3], RH[3];
#pragma unroll
        for (int q2 = 0; q2 < 3; q2++) {
            if (q2 < 2 || w3) {
                int r = (q2 < 2) ? (wid + 8 * q2) : (16 + wid);
                RI[q2] = r >> 1; RH[q2] = r & 1;
                float am1 = alps[RI[q2]] - 1.f;
                INV[q2] = 1.f / am1;
                X0[q2] = h2f(sc[(RH[q2] * 16 + RI[q2]) * 104 + l]) * am1;
                X1[q2] = (l + 64 < cN) ? h2f(sc[(RH[q2] * 16 + RI[q2]) * 104 + l + 64]) * am1 : -INFINITY;
                TM[q2] = ex2(am1 * log2_rn);
            }
        }
        float MX[3];
#pragma unroll
        for (int q2 = 0; q2 < 3; q2++) if (q2 < 2 || w3) MX[q2] = fmaxf(X0[q2], X1[q2]);
#pragma unroll
        for (int o = 32; o; o >>= 1) {
#pragma unroll
            for (int q2 = 0; q2 < 3; q2++) if (q2 < 2 || w3) MX[q2] = fmaxf(MX[q2], __shfl_xor(MX[q2], o, 64));
        }
#pragma unroll
        for (int q2 = 0; q2 < 3; q2++) if (q2 < 2 || w3) { TLO[q2] = MX[q2] - 1.f; DM[q2] = 1.f - TM[q2]; }
#pragma unroll
        for (int q2 = 0; q2 < 3; q2++) if (q2 < 2 || w3) {
            float z0 = fmaxf(X0[q2] - TLO[q2], 0.f);
            float z1 = fmaxf(X1[q2] - TLO[q2], 0.f);
            S[q2] = ex2(INV[q2] * lg2(z0)) + ex2(INV[q2] * lg2(z1));
        }
#pragma unroll
        for (int o = 32; o; o >>= 1) {
#pragma unroll
            for (int q2 = 0; q2 < 3; q2++) if (q2 < 2 || w3) S[q2] += __shfl_xor(S[q2], o, 64);
        }
#pragma unroll
        for (int q2 = 0; q2 < 3; q2++) if (q2 < 2 || w3) FLO[q2] = S[q2] - 1.f;

#pragma unroll 1
        for (int it = 0; it < N_ITER_RUN - 1; ++it) {
#pragma unroll
            for (int q2 = 0; q2 < 3; q2++) if (q2 < 2 || w3) { DM[q2] *= 0.5f; TM[q2] = TLO[q2] + DM[q2]; }
#pragma unroll
            for (int q2 = 0; q2 < 3; q2++) if (q2 < 2 || w3) {
                float z0 = fmaxf(X0[q2] - TM[q2], 0.f);
                float z1 = fmaxf(X1[q2] - TM[q2], 0.f);
                S[q2] = ex2(INV[q2] * lg2(z0)) + ex2(INV[q2] * lg2(z1));
            }
#pragma unroll
            for (int o = 32; o; o >>= 1) {
#pragma unroll
                for (int q2 = 0; q2 < 3; q2++) if (q2 < 2 || w3) S[q2] += __shfl_xor(S[q2], o, 64);
            }
#pragma unroll
            for (int q2 = 0; q2 < 3; q2++) if (q2 < 2 || w3)
                if ((S[q2] - 1.f) * FLO[q2] >= 0.f) TLO[q2] = TM[q2];
        }
        float P0[3], P1[3];
#pragma unroll
        for (int q2 = 0; q2 < 3; q2++) if (q2 < 2 || w3) {
            DM[q2] *= 0.5f; TM[q2] = TLO[q2] + DM[q2];
            float z0 = fmaxf(X0[q2] - TM[q2], 0.f);
            float z1 = fmaxf(X1[q2] - TM[q2], 0.f);
            P0[q2] = ex2(INV[q2] * lg2(z0));
            P1[q2] = ex2(INV[q2] * lg2(z1));
            S[q2] = P0[q2] + P1[q2];
        }
#pragma unroll
        for (int o = 32; o; o >>= 1) {
#pragma unroll
            for (int q2 = 0; q2 < 3; q2++) if (q2 < 2 || w3) S[q2] += __shfl_xor(S[q2], o, 64);
        }
        __syncthreads();
#pragma unroll
        for (int q2 = 0; q2 < 3; q2++) {
            if (q2 < 2 || w3) {
                float invs = 1.f / S[q2];
                sc[(RH[q2] * 16 + RI[q2]) * 104 + l] = f2hbits(P0[q2] * invs);
                if (l + 64 < cN) sc[(RH[q2] * 16 + RI[q2]) * 104 + l + 64] = f2hbits(P1[q2] * invs);
            }
        }
    }

    // ---- gating part 1 (x16 still intact): cg[h] = xi @ LW_top
    f32x4 cg0 = {0.f, 0.f, 0.f, 0.f}, cg1 = {0.f, 0.f, 0.f, 0.f};
    {
        const int d = wid * 16 + la;
        int arow = r0 + la; if (arow > 99) arow = 99;
#pragma unroll
        for (int h = 0; h < 2; h++) {
            const ushort_t* lwbase = LWT + ((size_t)(gz * 2 + h) * cD + d) * 256;
            f32x4 c = {0.f, 0.f, 0.f, 0.f};
#pragma unroll
            for (int kc = 0; kc < 4; kc++) {
                f16x8 a = ldf(&x16[arow * 136 + kc * 32 + lg * 8]);
                uint4 u = *(const uint4*)(lwbase + kc * 32 + lg * 8);
                f16x8 bb; __builtin_memcpy(&bb, &u, 16);
                c = mm(a, bb, c);
            }
            if (h) cg1 = c; else cg0 = c;
        }
    }
    __syncthreads();

    // ---- xT build from GLOBAL x (L2-hot), b128 writes, into dead x16 region
    for (int job = tid; job < 13 * 128; job += 512) {
        int d2 = job & 127, jc = job >> 7;
        f16x8 v;
#pragma unroll
        for (int t = 0; t < 8; t++) {
            int j = jc * 8 + t;
            float f = (j < cN) ? x[((size_t)b * cN + j) * cD + d2] : 0.f;
            v[t] = (__fp16)f;
        }
        uint4 u; __builtin_memcpy(&u, &v, 16);
        *(uint4*)(&xT[d2 * 104 + jc * 8]) = u;
    }
    __syncthreads();

    // ---- PV + gating part 2, per h ----
    float res[4] = {0.f, 0.f, 0.f, 0.f};
    const int dt = wid;
    const int d = dt * 16 + la;
    for (int h = 0; h < 2; h++) {
        if (h) __syncthreads();
        {
            f32x4 c = {0.f, 0.f, 0.f, 0.f};
#pragma unroll
            for (int kc = 0; kc < 3; kc++) {
                f16x8 a  = ldf(&sc[(h * 16 + la) * 104 + kc * 32 + lg * 8]);
                f16x8 bb = ldf(&xT[(dt * 16 + la) * 104 + kc * 32 + lg * 8]);
                c = mm(a, bb, c);
            }
#pragma unroll
            for (int r = 0; r < 4; r++) {
                int i = lg * 4 + r;
                float acc = c[r];
#pragma unroll
                for (int j = 96; j < 100; j++)
                    acc += h2f(sc[(h * 16 + i) * 104 + j]) * h2f(xT[d * 104 + j]);
                if (i < cG) out16[i * 136 + d] = f2hbits(acc);
            }
        }
        __syncthreads();
        {
            f32x4 c = h ? cg1 : cg0;
            const ushort_t* lwbase = LWT + ((size_t)(gz * 2 + h) * cD + d) * 256 + 128;
#pragma unroll
            for (int kc = 0; kc < 4; kc++) {
                f16x8 a = ldf(&out16[la * 136 + kc * 32 + lg * 8]);
                uint4 u = *(const uint4*)(lwbase + kc * 32 + lg * 8);
                f16x8 bb; __builtin_memcpy(&bb, &u, 16);
                c = mm(a, bb, c);
            }
            float lb = LB[h * cD + d];
#pragma unroll
            for (int r = 0; r < 4; r++) {
                int i = lg * 4 + r;
                float g = sigm(c[r] + lb);
                float o = h2f(out16[i * 136 + d]);
                float xi = h2f(xT[d * 104 + r0 + i]);
                res[r] += g * o + (1.f - g) * xi;
            }
        }
    }
#pragma unroll
    for (int r = 0; r < 4; r++) {
        int i = lg * 4 + r;
        if (i < cG) out[((size_t)b * cN + r0 + i) * cD + d] = res[r];
    }
}

// ---------------- kernel 3: fused tail (one block per b, 512 threads) ----------------
__global__ __launch_bounds__(512) void k_tail(
    const float* __restrict__ S, const float* __restrict__ T,
    const int* __restrict__ iidx, const float* __restrict__ g2w,
    const float* __restrict__ G1b, const float* __restrict__ W2,
    const ushort_t* __restrict__ W0T, const ushort_t* __restrict__ W1gT,
    const ushort_t* __restrict__ W1bT, const ushort_t* __restrict__ G1T,
    const float* __restrict__ posW1, float* __restrict__ outp)
{
    const int b = blockIdx.x;
    const int tid = threadIdx.x, wid = tid >> 6, l = tid & 63;
    const int la = l & 15, lg = l >> 4;
    const float scale = 0.088388347648318447f;   // 1/sqrt(128)

    __shared__ __align__(16) ushort_t s16[100 * 136];   // s, then snew, then nh
    __shared__ __align__(16) ushort_t t16[100 * 136];   // t, then hid
    __shared__ float a_sh[cN];
    __shared__ float part[4][cD];
    __shared__ float hs_s[cD];
    __shared__ float hsg_s[cD];
    __shared__ float beta_s[cN];
    __shared__ int   idx_s[cN];

    for (int idx = tid; idx < 100 * 64; idx += 512) {
        int n = idx >> 6, d2 = idx & 63;
        const float* sp = S + ((size_t)b * cN + n) * cD + 2 * d2;
        const float* tp = T + ((size_t)b * cN + n) * cD + 2 * d2;
        *(unsigned*)&s16[n * 136 + 2 * d2] = pkh2(sp[0], sp[1]);
        *(unsigned*)&t16[n * 136 + 2 * d2] = pkh2(tp[0], tp[1]);
    }
    if (tid < cN) idx_s[tid] = iidx[b * cN + tid];
    __syncthreads();

    if (wid < 7) {
        int arow = wid * 16 + la; if (arow > 99) arow = 99;
        float asum[4] = {0.f, 0.f, 0.f, 0.f};
        for (int nt = 0; nt < 8; nt++) {
            f32x4 cs = {0.f, 0.f, 0.f, 0.f}, ct = {0.f, 0.f, 0.f, 0.f};
            const ushort_t* b0 = W0T + (size_t)(nt * 16 + la) * cD;
            const ushort_t* b1 = W1gT + (size_t)(nt * 16 + la) * cD;
#pragma unroll
            for (int kc = 0; kc < 4; kc++) {
                f16x8 as = ldf(&s16[arow * 136 + kc * 32 + lg * 8]);
                f16x8 at = ldf(&t16[arow * 136 + kc * 32 + lg * 8]);
                uint4 u0 = *(const uint4*)(b0 + kc * 32 + lg * 8);
                uint4 u1 = *(const uint4*)(b1 + kc * 32 + lg * 8);
                f16x8 w0v, w1v; __builtin_memcpy(&w0v, &u0, 16); __builtin_memcpy(&w1v, &u1, 16);
                cs = mm(as, w0v, cs);
                ct = mm(at, w1v, ct);
            }
#pragma unroll
            for (int r = 0; r < 4; r++) asum[r] += cs[r] * ct[r];
        }
#pragma unroll
        for (int o = 8; o; o >>= 1) {
#pragma unroll
            for (int r = 0; r < 4; r++) asum[r] += __shfl_xor(asum[r], o, 64);
        }
        if (la == 0) {
#pragma unroll
            for (int r = 0; r < 4; r++) {
                int n = wid * 16 + lg * 4 + r;
                if (n < cN) a_sh[n] = asum[r] * scale;
            }
        }
    }
    __syncthreads();

    for (int idx = tid; idx < 100 * 64; idx += 512) {
        int n = idx >> 6, d2 = idx & 63;
        unsigned su = *(unsigned*)&s16[n * 136 + 2 * d2];
        unsigned tu = *(unsigned*)&t16[n * 136 + 2 * d2];
        float a = a_sh[n];
        float s0 = h2f((ushort_t)(su & 0xffffu)), s1 = h2f((ushort_t)(su >> 16));
        float t0 = h2f((ushort_t)(tu & 0xffffu)), t1 = h2f((ushort_t)(tu >> 16));
        *(unsigned*)&s16[n * 136 + 2 * d2] = pkh2(s0 + a * (t0 - s0), s1 + a * (t1 - s1));
    }
    __syncthreads();

    for (int idx = tid; idx < 100 * 64; idx += 512) {
        int n = idx >> 6, d2 = idx & 63;
        int rsrc = idx_s[n];
        *(unsigned*)&t16[n * 136 + 2 * d2] = *(unsigned*)&s16[rsrc * 136 + 2 * d2];
    }
    __syncthreads();

    {
        int g = tid >> 7, d = tid & 127;
        float sum = 0.f;
        for (int n = g * 25; n < g * 25 + 25; n++) sum += h2f(t16[n * 136 + d]);
        part[g][d] = sum;
    }
    __syncthreads();
    if (tid < cD) hs_s[tid] = (part[0][tid] + part[1][tid] + part[2][tid] + part[3][tid]) * (1.f / (100.f + 1e-7f));
    __syncthreads();
    if (tid < cD) {
        float acc = 0.f;
        for (int c = 0; c < cD; c++) acc += hs_s[c] * g2w[c * cD + tid];
        hsg_s[tid] = acc;
    }
    __syncthreads();

    if (wid < 7) {
        int arow = wid * 16 + la; if (arow > 99) arow = 99;
        for (int nt = 0; nt < 8; nt++) {
            f32x4 c = {0.f, 0.f, 0.f, 0.f};
            const ushort_t* bb = W1bT + (size_t)(nt * 16 + la) * cD;
#pragma unroll
            for (int kc = 0; kc < 4; kc++) {
                f16x8 a = ldf(&t16[arow * 136 + kc * 32 + lg * 8]);
                uint4 u = *(const uint4*)(bb + kc * 32 + lg * 8);
                f16x8 wv; __builtin_memcpy(&wv, &u, 16);
                c = mm(a, wv, c);
            }
            int d = nt * 16 + la;
#pragma unroll
            for (int r = 0; r < 4; r++) {
                int n = wid * 16 + lg * 4 + r;
                if (n < cN) s16[n * 136 + d] = f2hbits(tanhf(c[r] + posW1[n * cD + d]));
            }
        }
    }
    __syncthreads();

    if (wid < 7) {
        int arow = wid * 16 + la; if (arow > 99) arow = 99;
        float bsum[4] = {0.f, 0.f, 0.f, 0.f};
        for (int nt = 0; nt < 8; nt++) {
            f32x4 c = {0.f, 0.f, 0.f, 0.f};
            const ushort_t* bb = G1T + (size_t)(nt * 16 + la) * cD;
#pragma unroll
            for (int kc = 0; kc < 4; kc++) {
                f16x8 a = ldf(&s16[arow * 136 + kc * 32 + lg * 8]);
                uint4 u = *(const uint4*)(bb + kc * 32 + lg * 8);
                f16x8 wv; __builtin_memcpy(&wv, &u, 16);
                c = mm(a, wv, c);
            }
            int d = nt * 16 + la;
            float add = G1b[d] + hsg_s[d];
            float w2v = W2[d];
#pragma unroll
            for (int r = 0; r < 4; r++) bsum[r] += sigm(c[r] + add) * w2v;
        }
#pragma unroll
        for (int o = 8; o; o >>= 1) {
#pragma unroll
            for (int r = 0; r < 4; r++) bsum[r] += __shfl_xor(bsum[r], o, 64);
        }
        if (la == 0) {
#pragma unroll
            for (int r = 0; r < 4; r++) {
                int n = wid * 16 + lg * 4 + r;
                if (n < cN) beta_s[n] = bsum[r];
            }
        }
    }
    __syncthreads();

    {
        int g = tid >> 7, d = tid & 127;
        float sum = 0.f;
        for (int n = g * 25; n < g * 25 + 25; n++) sum += beta_s[n] * h2f(t16[n * 136 + d]);
        part[g][d] = sum;
    }
    __syncthreads();
    if (tid < cD) outp[b * cD + tid] = part[0][tid] + part[1][tid] + part[2][tid] + part[3][tid];
}

extern "C" void kernel_launch(void* const* d_in, const int* in_sizes, int n_in,
                              void* d_out, int out_size, void* d_ws, size_t ws_size,
                              hipStream_t stream) {
    const float* gnn   = (const float*)d_in[0];
    const float* drop  = (const float*)d_in[1];
    const float* proto = (const float*)d_in[2];
    const float* pos   = (const float*)d_in[3];
    const float* laL_a = (const float*)d_in[4];
    const float* laL_w = (const float*)d_in[5];
    const float* laL_b = (const float*)d_in[6];
    const float* ssL_w = (const float*)d_in[7];
    const float* ssL_b = (const float*)d_in[8];
    const float* laG_a = (const float*)d_in[9];
    const float* laG_w = (const float*)d_in[10];
    const float* laG_b = (const float*)d_in[11];
    const float* ssG_w = (const float*)d_in[12];
    const float* ssG_b = (const float*)d_in[13];
    const float* gem_w = (const float*)d_in[14];
    const float* fn_w  = (const float*)d_in[15];
    const float* fn_b  = (const float*)d_in[16];
    const float* w_1   = (const float*)d_in[17];
    const float* w_2   = (const float*)d_in[18];
    const float* glu1w = (const float*)d_in[19];
    const float* glu1b = (const float*)d_in[20];
    const float* glu2w = (const float*)d_in[21];
    const int*   adj   = (const int*)d_in[22];
    const int*   iidx  = (const int*)d_in[23];
    const void*  m0    = d_in[24];
    float* out = (float*)d_out;

    const size_t BND = (size_t)cB * cN * cD;
    float* w = (float*)d_ws;
    float* bufA = w;               // gi
    float* bufB = bufA + BND;      // pi
    float* locS = bufB + BND;
    float* gloS = locS + BND;
    float* aL   = gloS + BND;
    float* aG   = aL + (size_t)cB * cN;
    float* avgdot = aG + (size_t)cB * cN;
    ushort_t* LWT  = (ushort_t*)(avgdot + cB);
    ushort_t* W1bT = LWT + (size_t)4 * cD * 256;
    ushort_t* G1T  = W1bT + (size_t)cD * cD;
    ushort_t* W0T  = G1T + (size_t)cD * cD;
    ushort_t* W1gT = W0T + (size_t)cD * cD;
    float* posW1   = (float*)(W1gT + (size_t)cD * cD);

    k_cvtw<<<dim3(9, 8), dim3(256), 0, stream>>>(laL_w, laG_w, w_1, glu1w, gem_w, pos,
                                                 LWT, W1bT, G1T, W0T, W1gT, posW1);
    k_prep_a<<<dim3(cB), dim3(256), 0, stream>>>(gnn, m0, fn_w, avgdot);
    k_prep_b<<<dim3(cB, 13), dim3(512), 0, stream>>>(gnn, drop, proto, m0, avgdot,
                                                     fn_w, fn_b, ssL_w, ssL_b, ssG_w, ssG_b,
                                                     bufA, bufB, aL, aG);
    k_gnn<<<dim3(cNCH * cB * 2), dim3(512), 0, stream>>>(
        bufA, bufB, adj, aL, aG, laL_a, laG_a, LWT, laL_b, laG_b, locS, gloS);
    k_tail<<<dim3(cB), dim3(512), 0, stream>>>(locS, gloS, iidx, glu2w, glu1b, w_2,
                                               W0T, W1gT, W1bT, G1T, posW1, out);
}